// Round 4
// baseline (1818.732 us; speedup 1.0000x reference)
//
#include <hip/hip_runtime.h>
#include <math.h>

#define TPB 256

static const int B_ALL = 4;
static const int CH    = 64;    // input channels
static const int CH2   = 128;   // conv channels
static const int HIN   = 256, WIN = 256;
static const int HH    = 255;   // cropped height
static const int WF    = 129;   // rfft bins along W
static const int HWF   = HH * WF;  // 32895
#define GN_EPS 1e-5f

// ---------------- fallback: zero the output (defined behavior if ws too small) --------
__global__ __launch_bounds__(TPB) void k_zero(float* __restrict__ out, int n) {
  int i = blockIdx.x * TPB + threadIdx.x;
  if (i < n) out[i] = 0.f;
}

// ---------------- DFT coefficient tables (double-precision trig) ----------------
__global__ __launch_bounds__(TPB) void k_tables(float* __restrict__ Tc1, float* __restrict__ Ts1,
                                                float* __restrict__ C255, float* __restrict__ S255,
                                                float* __restrict__ Tci, float* __restrict__ Tsi) {
  int i = blockIdx.x * TPB + threadIdx.x;
  const double PI2 = 6.283185307179586476925286766559;
  if (i < 256 * WF) {                       // forward W-DFT: [w=256][k=129]
    int w = i / WF, k = i - w * WF;
    double ang = PI2 * (double)((w * k) & 255) / 256.0;
    Tc1[i] = (float)cos(ang);
    Ts1[i] = (float)sin(ang);
  }
  if (i < 255 * 255) {                      // H-DFT matrix (symmetric): [h][h']
    int h = i / 255, hp = i - h * 255;
    double ang = PI2 * (double)((h * hp) % 255) / 255.0;
    C255[i] = (float)cos(ang);
    S255[i] = (float)sin(ang);
  }
  if (i < WF * 256) {                       // inverse W-DFT w/ Hermitian fold: [k=129][w'=256]
    int k = i / 256, w = i - k * 256;
    double coef = (k == 0 || k == 128) ? 1.0 : 2.0;
    double ang = PI2 * (double)((k * w) & 255) / 256.0;
    Tci[i] = (float)(coef * cos(ang) / 256.0);
    Tsi[i] = (float)(coef * sin(ang) / 256.0);
  }
}

// ---------------- K1: forward W-DFT  (x[M][256] -> Fr,Fi[M][129]) ----------------
__global__ __launch_bounds__(TPB) void k_dftw_fwd(const float* __restrict__ x,
                                                  const float* __restrict__ Tc,
                                                  const float* __restrict__ Ts,
                                                  float* __restrict__ Fr,
                                                  float* __restrict__ Fi) {
  __shared__ float At[32][68];
  __shared__ float Bc[32][68], Bs[32][68];
  const int tid = threadIdx.x;
  const int tx = tid & 15, ty = tid >> 4;
  const int m0 = blockIdx.x * 64;
  const int n0 = blockIdx.y * 64;
  float ar[4][4] = {{0.f}}, ai[4][4] = {{0.f}};
  for (int k0 = 0; k0 < 256; k0 += 32) {
    for (int f = tid; f < 512; f += TPB) {   // A tile, transposed into LDS
      int i = f >> 3, j4 = f & 7;
      float4 v = *(const float4*)(x + (size_t)(m0 + i) * WIN + k0 + j4 * 4);
      At[j4 * 4 + 0][i] = v.x;
      At[j4 * 4 + 1][i] = v.y;
      At[j4 * 4 + 2][i] = v.z;
      At[j4 * 4 + 3][i] = v.w;
    }
    for (int f = tid; f < 2048; f += TPB) {  // B tiles (cos,sin)
      int kk = f >> 6, j = f & 63;
      int col = n0 + j;
      float c = 0.f, s = 0.f;
      if (col < WF) { c = Tc[(k0 + kk) * WF + col]; s = Ts[(k0 + kk) * WF + col]; }
      Bc[kk][j] = c; Bs[kk][j] = s;
    }
    __syncthreads();
#pragma unroll 8
    for (int kk = 0; kk < 32; ++kk) {
      float4 a4 = *(const float4*)&At[kk][ty * 4];
      float4 c4 = *(const float4*)&Bc[kk][tx * 4];
      float4 s4 = *(const float4*)&Bs[kk][tx * 4];
      float av[4] = {a4.x, a4.y, a4.z, a4.w};
      float cv[4] = {c4.x, c4.y, c4.z, c4.w};
      float sv[4] = {s4.x, s4.y, s4.z, s4.w};
#pragma unroll
      for (int ii = 0; ii < 4; ++ii)
#pragma unroll
        for (int jj = 0; jj < 4; ++jj) {
          ar[ii][jj] += av[ii] * cv[jj];
          ai[ii][jj] += av[ii] * sv[jj];
        }
    }
    __syncthreads();
  }
#pragma unroll
  for (int ii = 0; ii < 4; ++ii) {
    int m = m0 + ty * 4 + ii;
#pragma unroll
    for (int jj = 0; jj < 4; ++jj) {
      int n = n0 + tx * 4 + jj;
      if (n < WF) {
        Fr[(size_t)m * WF + n] = ar[ii][jj];
        Fi[(size_t)m * WF + n] = -ai[ii][jj];   // forward: Fi = -sum x*sin
      }
    }
  }
}

// ------- K2: forward H-DFT  G[h'][k] = sum_h C[h][h']Fr + S[h][h']Fi ;  Gi = C*Fi - S*Fr -------
__global__ __launch_bounds__(TPB) void k_dfth_fwd(const float* __restrict__ Fr,
                                                  const float* __restrict__ Fi,
                                                  const float* __restrict__ C,
                                                  const float* __restrict__ S,
                                                  float* __restrict__ G,
                                                  int hoff) {
  __shared__ float Ct[32][68], St[32][68], Br[32][68], Bi[32][68];
  const int tid = threadIdx.x;
  const int tx = tid & 15, ty = tid >> 4;
  const int bc = blockIdx.z;
  const int b = bc >> 6, c = bc & 63;
  const float* fr = Fr + (size_t)bc * HIN * WF + (size_t)hoff * WF;
  const float* fi = Fi + (size_t)bc * HIN * WF + (size_t)hoff * WF;
  float* gr = G + (size_t)(b * CH2 + c) * HWF;
  float* gi = G + (size_t)(b * CH2 + CH + c) * HWF;
  const int m0 = blockIdx.y * 64;
  const int n0 = blockIdx.x * 64;
  float accr[4][4] = {{0.f}}, acci[4][4] = {{0.f}};
  for (int k0 = 0; k0 < HH; k0 += 32) {
    const int klim = min(32, HH - k0);
    for (int f = tid; f < 2048; f += TPB) {
      int kk = f >> 6, i = f & 63;
      float cv = 0.f, sv = 0.f;
      if (kk < klim && (m0 + i) < HH) {
        cv = C[(k0 + kk) * HH + m0 + i];
        sv = S[(k0 + kk) * HH + m0 + i];
      }
      Ct[kk][i] = cv; St[kk][i] = sv;
    }
    for (int f = tid; f < 2048; f += TPB) {
      int kk = f >> 6, j = f & 63;
      float rv = 0.f, iv = 0.f;
      if (kk < klim && (n0 + j) < WF) {
        rv = fr[(size_t)(k0 + kk) * WF + n0 + j];
        iv = fi[(size_t)(k0 + kk) * WF + n0 + j];
      }
      Br[kk][j] = rv; Bi[kk][j] = iv;
    }
    __syncthreads();
#pragma unroll 4
    for (int kk = 0; kk < 32; ++kk) {
      float4 c4 = *(const float4*)&Ct[kk][ty * 4];
      float4 s4 = *(const float4*)&St[kk][ty * 4];
      float4 r4 = *(const float4*)&Br[kk][tx * 4];
      float4 i4 = *(const float4*)&Bi[kk][tx * 4];
      float cv[4] = {c4.x, c4.y, c4.z, c4.w};
      float sv[4] = {s4.x, s4.y, s4.z, s4.w};
      float rv[4] = {r4.x, r4.y, r4.z, r4.w};
      float iv[4] = {i4.x, i4.y, i4.z, i4.w};
#pragma unroll
      for (int ii = 0; ii < 4; ++ii)
#pragma unroll
        for (int jj = 0; jj < 4; ++jj) {
          accr[ii][jj] += cv[ii] * rv[jj] + sv[ii] * iv[jj];
          acci[ii][jj] += cv[ii] * iv[jj] - sv[ii] * rv[jj];
        }
    }
    __syncthreads();
  }
#pragma unroll
  for (int ii = 0; ii < 4; ++ii) {
    int m = m0 + ty * 4 + ii;
    if (m < HH) {
#pragma unroll
      for (int jj = 0; jj < 4; ++jj) {
        int n = n0 + tx * 4 + jj;
        if (n < WF) {
          gr[(size_t)m * WF + n] = accr[ii][jj];
          gi[(size_t)m * WF + n] = acci[ii][jj];
        }
      }
    }
  }
}

// ---------------- K3: 1x1 conv  Y[o][s] = sum_c W[o][c] G[c][s] + bias[o] ----------------
__global__ __launch_bounds__(TPB) void k_conv(const float* __restrict__ G,
                                              const float* __restrict__ W,
                                              const float* __restrict__ bias,
                                              float* __restrict__ Y) {
  __shared__ float Wt[32][68], Gt[32][68];
  const int tid = threadIdx.x;
  const int tx = tid & 15, ty = tid >> 4;
  const int b = blockIdx.z;
  const int o0 = blockIdx.y * 64;
  const int s0 = blockIdx.x * 64;
  const float* gb = G + (size_t)b * CH2 * HWF;
  float acc[4][4] = {{0.f}};
  for (int c0 = 0; c0 < CH2; c0 += 32) {
    for (int f = tid; f < 2048; f += TPB) {
      int i = f >> 5, kk = f & 31;
      Wt[kk][i] = W[(o0 + i) * CH2 + c0 + kk];
    }
    for (int f = tid; f < 2048; f += TPB) {
      int kk = f >> 6, j = f & 63;
      float v = 0.f;
      if (s0 + j < HWF) v = gb[(size_t)(c0 + kk) * HWF + s0 + j];
      Gt[kk][j] = v;
    }
    __syncthreads();
#pragma unroll 8
    for (int kk = 0; kk < 32; ++kk) {
      float4 a4 = *(const float4*)&Wt[kk][ty * 4];
      float4 b4 = *(const float4*)&Gt[kk][tx * 4];
      float av[4] = {a4.x, a4.y, a4.z, a4.w};
      float bv[4] = {b4.x, b4.y, b4.z, b4.w};
#pragma unroll
      for (int ii = 0; ii < 4; ++ii)
#pragma unroll
        for (int jj = 0; jj < 4; ++jj) acc[ii][jj] += av[ii] * bv[jj];
    }
    __syncthreads();
  }
#pragma unroll
  for (int ii = 0; ii < 4; ++ii) {
    int o = o0 + ty * 4 + ii;
    float bvv = bias[o];
#pragma unroll
    for (int jj = 0; jj < 4; ++jj) {
      int s = s0 + tx * 4 + jj;
      if (s < HWF) Y[((size_t)b * CH2 + o) * HWF + s] = acc[ii][jj] + bvv;
    }
  }
}

// ---------------- K4: GroupNorm stats (deterministic two-stage) ----------------
__global__ __launch_bounds__(TPB) void k_gn_part(const float* __restrict__ Y,
                                                 float* __restrict__ part) {
  const int tid = threadIdx.x;
  const int bgj = blockIdx.x;            // channel index
  const float* p = Y + (size_t)bgj * HWF;
  float s = 0.f, ss = 0.f;
  for (int i = tid; i < HWF; i += TPB) {
    float v = p[i];
    s += v; ss += v * v;
  }
  __shared__ float rs[TPB], rq[TPB];
  rs[tid] = s; rq[tid] = ss;
  __syncthreads();
  for (int st = TPB / 2; st > 0; st >>= 1) {
    if (tid < st) { rs[tid] += rs[tid + st]; rq[tid] += rq[tid + st]; }
    __syncthreads();
  }
  if (tid == 0) { part[bgj * 2] = rs[0]; part[bgj * 2 + 1] = rq[0]; }
}

__global__ void k_gn_stats(const float* __restrict__ part,
                           float* __restrict__ stats, int nbg) {
  int bg = blockIdx.x * blockDim.x + threadIdx.x;
  if (bg < nbg) {
    float s = 0.f, ss = 0.f;
    for (int j = 0; j < 8; ++j) {
      s += part[(bg * 8 + j) * 2];
      ss += part[(bg * 8 + j) * 2 + 1];
    }
    const float inv = 1.f / (8.f * (float)HWF);
    float mean = s * inv;
    float var = ss * inv - mean * mean;
    stats[bg * 2] = mean;
    stats[bg * 2 + 1] = rsqrtf(var + GN_EPS);
  }
}

// ------- K6: GN+ReLU fused + inverse H-DFT (only the 128 surviving rows) -------
__global__ __launch_bounds__(TPB) void k_dfth_inv(const float* __restrict__ Y,
                                                  const float* __restrict__ C,
                                                  const float* __restrict__ S,
                                                  const float* __restrict__ stats,
                                                  const float* __restrict__ gamma,
                                                  const float* __restrict__ beta,
                                                  float* __restrict__ Hr,
                                                  float* __restrict__ Hi,
                                                  int hsel) {
  __shared__ float Ct[32][68], St[32][68], Br[32][68], Bi[32][68];
  const int tid = threadIdx.x;
  const int tx = tid & 15, ty = tid >> 4;
  const int bc = blockIdx.z;
  const int b = bc >> 6, c = bc & 63;
  const float* yr = Y + (size_t)(b * CH2 + c) * HWF;
  const float* yi = Y + (size_t)(b * CH2 + CH + c) * HWF;
  const int g1 = b * 16 + (c >> 3);
  const int g2 = b * 16 + 8 + (c >> 3);
  const float mu1 = stats[g1 * 2], is1 = stats[g1 * 2 + 1];
  const float mu2 = stats[g2 * 2], is2 = stats[g2 * 2 + 1];
  const float ga1 = gamma[c], be1 = beta[c];
  const float ga2 = gamma[CH + c], be2 = beta[CH + c];
  const int m0 = blockIdx.y * 64;
  const int n0 = blockIdx.x * 64;
  float accr[4][4] = {{0.f}}, acci[4][4] = {{0.f}};
  for (int k0 = 0; k0 < HH; k0 += 32) {
    const int klim = min(32, HH - k0);
    for (int f = tid; f < 2048; f += TPB) {
      int kk = f >> 6, i = f & 63;
      float cv = 0.f, sv = 0.f;
      if (kk < klim) {                  // hsel+m0+i <= 254 always
        cv = C[(k0 + kk) * HH + hsel + m0 + i];
        sv = S[(k0 + kk) * HH + hsel + m0 + i];
      }
      Ct[kk][i] = cv; St[kk][i] = sv;
    }
    for (int f = tid; f < 2048; f += TPB) {
      int kk = f >> 6, j = f & 63;
      float rv = 0.f, iv = 0.f;
      if (kk < klim && (n0 + j) < WF) {
        int idx = (k0 + kk) * WF + n0 + j;
        float a = yr[idx], d = yi[idx];
        rv = fmaxf((a - mu1) * is1 * ga1 + be1, 0.f);
        iv = fmaxf((d - mu2) * is2 * ga2 + be2, 0.f);
      }
      Br[kk][j] = rv; Bi[kk][j] = iv;
    }
    __syncthreads();
#pragma unroll 4
    for (int kk = 0; kk < 32; ++kk) {
      float4 c4 = *(const float4*)&Ct[kk][ty * 4];
      float4 s4 = *(const float4*)&St[kk][ty * 4];
      float4 r4 = *(const float4*)&Br[kk][tx * 4];
      float4 i4 = *(const float4*)&Bi[kk][tx * 4];
      float cv[4] = {c4.x, c4.y, c4.z, c4.w};
      float sv[4] = {s4.x, s4.y, s4.z, s4.w};
      float rv[4] = {r4.x, r4.y, r4.z, r4.w};
      float iv[4] = {i4.x, i4.y, i4.z, i4.w};
#pragma unroll
      for (int ii = 0; ii < 4; ++ii)
#pragma unroll
        for (int jj = 0; jj < 4; ++jj) {
          accr[ii][jj] += cv[ii] * rv[jj] - sv[ii] * iv[jj];
          acci[ii][jj] += cv[ii] * iv[jj] + sv[ii] * rv[jj];
        }
    }
    __syncthreads();
  }
  const float inv = 1.f / 255.f;
#pragma unroll
  for (int ii = 0; ii < 4; ++ii) {
    int m = m0 + ty * 4 + ii;            // 0..127 always valid
#pragma unroll
    for (int jj = 0; jj < 4; ++jj) {
      int n = n0 + tx * 4 + jj;
      if (n < WF) {
        Hr[((size_t)bc * 128 + m) * WF + n] = accr[ii][jj] * inv;
        Hi[((size_t)bc * 128 + m) * WF + n] = acci[ii][jj] * inv;
      }
    }
  }
}

// ------- K7: inverse W-DFT (Hermitian-folded, K=129) + scatter into d_out -------
__global__ __launch_bounds__(TPB) void k_dftw_inv(const float* __restrict__ Hr,
                                                  const float* __restrict__ Hi,
                                                  const float* __restrict__ Tc,
                                                  const float* __restrict__ Ts,
                                                  float* __restrict__ out,
                                                  int roff, int b0) {
  __shared__ float Ar[32][68], Ai[32][68], Bc[32][68], Bs[32][68];
  const int tid = threadIdx.x;
  const int tx = tid & 15, ty = tid >> 4;
  const int m0 = blockIdx.y * 64;
  const int n0 = blockIdx.x * 64;
  float acc[4][4] = {{0.f}};
  for (int k0 = 0; k0 < WF; k0 += 32) {
    const int klim = min(32, WF - k0);
    for (int f = tid; f < 2048; f += TPB) {
      int i = f >> 5, j = f & 31;
      float rv = 0.f, iv = 0.f;
      if (j < klim) {
        size_t idx = (size_t)(m0 + i) * WF + k0 + j;
        rv = Hr[idx]; iv = Hi[idx];
      }
      Ar[j][i] = rv; Ai[j][i] = iv;
    }
    for (int f = tid; f < 2048; f += TPB) {
      int kk = f >> 6, j = f & 63;
      float cv = 0.f, sv = 0.f;
      if (kk < klim) {
        cv = Tc[(k0 + kk) * 256 + n0 + j];
        sv = Ts[(k0 + kk) * 256 + n0 + j];
      }
      Bc[kk][j] = cv; Bs[kk][j] = sv;
    }
    __syncthreads();
#pragma unroll 4
    for (int kk = 0; kk < 32; ++kk) {
      float4 r4 = *(const float4*)&Ar[kk][ty * 4];
      float4 i4 = *(const float4*)&Ai[kk][ty * 4];
      float4 c4 = *(const float4*)&Bc[kk][tx * 4];
      float4 s4 = *(const float4*)&Bs[kk][tx * 4];
      float rv[4] = {r4.x, r4.y, r4.z, r4.w};
      float iv[4] = {i4.x, i4.y, i4.z, i4.w};
      float cv[4] = {c4.x, c4.y, c4.z, c4.w};
      float sv[4] = {s4.x, s4.y, s4.z, s4.w};
#pragma unroll
      for (int ii = 0; ii < 4; ++ii)
#pragma unroll
        for (int jj = 0; jj < 4; ++jj)
          acc[ii][jj] += rv[ii] * cv[jj] - iv[ii] * sv[jj];
    }
    __syncthreads();
  }
#pragma unroll
  for (int ii = 0; ii < 4; ++ii) {
    int r = m0 + ty * 4 + ii;            // (b_local*64 + c)*128 + m
    int bl = r >> 13;
    int rem = r & 8191;
    int cch = rem >> 7;
    int m = rem & 127;
    size_t obase = (((size_t)(b0 + bl) * CH + cch) * HIN + roff + m) * WIN;
#pragma unroll
    for (int jj = 0; jj < 4; ++jj) out[obase + n0 + tx * 4 + jj] = acc[ii][jj];
  }
}

// ---------------- host ----------------
extern "C" void kernel_launch(void* const* d_in, const int* in_sizes, int n_in,
                              void* d_out, int out_size, void* d_ws, size_t ws_size,
                              hipStream_t stream) {
  const float* x       = (const float*)d_in[0];
  const float* conv_w  = (const float*)d_in[1];
  const float* conv_b  = (const float*)d_in[2];
  const float* gn_gamma = (const float*)d_in[3];
  const float* gn_beta  = (const float*)d_in[4];
  float* out = (float*)d_out;
  float* ws  = (float*)d_ws;

  const size_t szTc1  = 256 * WF;
  const size_t szC255 = 255 * 255;
  const size_t szTci  = (size_t)WF * 256;
  const size_t fixed  = 2 * szTc1 + 2 * szC255 + 2 * szTci + 1024 + 128;
  const size_t per    = 2ull * CH * HIN * WF + 2ull * CH2 * HWF;  // floats per batch

  // pick batch-chunk size to fit workspace (203MB nb=4, 103MB nb=2, 52MB nb=1)
  int nb = 0;
  if ((fixed + 4ull * per) * sizeof(float) <= ws_size) nb = 4;
  else if ((fixed + 2ull * per) * sizeof(float) <= ws_size) nb = 2;
  else if ((fixed + 1ull * per) * sizeof(float) <= ws_size) nb = 1;

  if (nb == 0) {
    // workspace too small for any chunking: defined (wrong) output, no OOB writes
    k_zero<<<dim3((out_size + TPB - 1) / TPB), dim3(TPB), 0, stream>>>(out, out_size);
    return;
  }

  float* Tc1  = ws;
  float* Ts1  = Tc1 + szTc1;
  float* C255 = Ts1 + szTc1;
  float* S255 = C255 + szC255;
  float* Tci  = S255 + szC255;
  float* Tsi  = Tci + szTci;
  float* part  = Tsi + szTci;     // up to 4*16*8*2 = 1024 floats
  float* stats = part + 1024;     // up to 128 floats
  float* base  = stats + 128;

  const size_t szF = (size_t)nb * CH * HIN * WF;
  const size_t szG = (size_t)nb * CH2 * HWF;
  float* Fr = base;
  float* Fi = Fr + szF;
  float* G  = Fi + szF;
  float* Yb = G + szG;
  float* Hr = G;                                  // H aliases G (free after conv)
  float* Hi = G + (size_t)nb * CH * 128 * WF;

  k_tables<<<dim3((255 * 255 + TPB - 1) / TPB), dim3(TPB), 0, stream>>>(
      Tc1, Ts1, C255, S255, Tci, Tsi);

  for (int b0 = 0; b0 < B_ALL; b0 += nb) {
    // shared forward W-DFT over all 256 input rows
    k_dftw_fwd<<<dim3(nb * CH * HIN / 64, 3), dim3(TPB), 0, stream>>>(
        x + (size_t)b0 * CH * HIN * WIN, Tc1, Ts1, Fr, Fi);
    for (int fu = 0; fu < 2; ++fu) {
      const int hoff = fu;            // bot: rows 0..254, top: rows 1..255
      const int hsel = fu ? 127 : 0;  // surviving h' window start
      const int roff = fu ? 128 : 0;  // output row offset
      k_dfth_fwd<<<dim3(3, 4, nb * CH), dim3(TPB), 0, stream>>>(Fr, Fi, C255, S255, G, hoff);
      k_conv<<<dim3((HWF + 63) / 64, 2, nb), dim3(TPB), 0, stream>>>(G, conv_w, conv_b, Yb);
      k_gn_part<<<dim3(nb * 16 * 8), dim3(TPB), 0, stream>>>(Yb, part);
      k_gn_stats<<<dim3(1), dim3(64), 0, stream>>>(part, stats, nb * 16);
      k_dfth_inv<<<dim3(3, 2, nb * CH), dim3(TPB), 0, stream>>>(
          Yb, C255, S255, stats, gn_gamma, gn_beta, Hr, Hi, hsel);
      k_dftw_inv<<<dim3(4, nb * CH * 128 / 64), dim3(TPB), 0, stream>>>(
          Hr, Hi, Tci, Tsi, out, roff, b0);
    }
  }
}

// Round 5
// 880.762 us; speedup vs baseline: 2.0650x; 2.0650x over previous
//
#include <hip/hip_runtime.h>
#include <math.h>

#define TPB 256

typedef unsigned short us16;
typedef __bf16 bf16x8 __attribute__((ext_vector_type(8)));
typedef float f32x4 __attribute__((ext_vector_type(4)));

static const int B_ALL = 4;
static const int CH    = 64;    // input channels
static const int CH2   = 128;   // conv channels
static const int HIN   = 256, WIN = 256;
static const int HH    = 255;   // cropped height
static const int WF    = 129;   // rfft bins along W
static const int HWF   = HH * WF;  // 32895
static const int FTROWS = 192;  // padded n-rows per bc in Frt/Fit
#define GN_EPS 1e-5f

__device__ __forceinline__ us16 f2bf(float f) {
  union { float f; unsigned u; } v; v.f = f;
  unsigned r = v.u + 0x7FFFu + ((v.u >> 16) & 1u);
  return (us16)(r >> 16);
}

__device__ __forceinline__ void gload16(const void* g, void* l) {
  __builtin_amdgcn_global_load_lds(
      (const __attribute__((address_space(1))) unsigned int*)g,
      (__attribute__((address_space(3))) unsigned int*)l, 16, 0, 0);
}

// ---------------- fallback: zero the output (defined behavior if ws too small) --------
__global__ __launch_bounds__(TPB) void k_zero(float* __restrict__ out, int n) {
  int i = blockIdx.x * TPB + threadIdx.x;
  if (i < n) out[i] = 0.f;
}

// ---------------- tables: fp32 W-DFT tables + bf16 padded H-DFT tables ----------------
// CbA/SbA layout: [fu][m=256][k=256] bf16; CbA[fu][m][k] = C255[m][k-fu] (0 outside),
// so the bot/top row shift is absorbed into the table and all K-tiles stay 16B-aligned.
__global__ __launch_bounds__(TPB) void k_tables(float* __restrict__ Tc1, float* __restrict__ Ts1,
                                                float* __restrict__ Tci, float* __restrict__ Tsi,
                                                us16* __restrict__ CbA, us16* __restrict__ SbA) {
  int i = blockIdx.x * TPB + threadIdx.x;
  const double PI2 = 6.283185307179586476925286766559;
  if (i < 256 * WF) {                       // forward W-DFT: [w=256][k=129]
    int w = i / WF, k = i - w * WF;
    double ang = PI2 * (double)((w * k) & 255) / 256.0;
    Tc1[i] = (float)cos(ang);
    Ts1[i] = (float)sin(ang);
  }
  if (i < WF * 256) {                       // inverse W-DFT w/ Hermitian fold: [k=129][w'=256]
    int k = i >> 8, w = i & 255;
    double coef = (k == 0 || k == 128) ? 1.0 : 2.0;
    double ang = PI2 * (double)((k * w) & 255) / 256.0;
    Tci[i] = (float)(coef * cos(ang) / 256.0);
    Tsi[i] = (float)(coef * sin(ang) / 256.0);
  }
  if (i < 2 * 256 * 256) {                  // bf16 H-DFT tables
    int fu = i >> 16, r = (i >> 8) & 255, k = i & 255;
    float cv = 0.f, sv = 0.f;
    int kk = k - fu;
    if (r < 255 && kk >= 0 && kk < 255) {
      double ang = PI2 * (double)((r * kk) % 255) / 255.0;
      cv = (float)cos(ang);
      sv = (float)sin(ang);
    }
    CbA[i] = f2bf(cv);
    SbA[i] = f2bf(sv);
  }
}

// ------- K1: forward W-DFT (fp32 compute) -> bf16 TRANSPOSED outputs Frt/Fit[bc][n][h] -------
__global__ __launch_bounds__(TPB) void k_dftw_fwd(const float* __restrict__ x,
                                                  const float* __restrict__ Tc,
                                                  const float* __restrict__ Ts,
                                                  us16* __restrict__ Frt,
                                                  us16* __restrict__ Fit) {
  __shared__ float At[32][68];
  __shared__ float Bc[32][68], Bs[32][68];
  const int tid = threadIdx.x;
  const int tx = tid & 15, ty = tid >> 4;
  const int m0 = blockIdx.x * 64;
  const int n0 = blockIdx.y * 64;
  float ar[4][4] = {{0.f}}, ai[4][4] = {{0.f}};
  for (int k0 = 0; k0 < 256; k0 += 32) {
    for (int f = tid; f < 512; f += TPB) {   // A tile, transposed into LDS
      int i = f >> 3, j4 = f & 7;
      float4 v = *(const float4*)(x + (size_t)(m0 + i) * WIN + k0 + j4 * 4);
      At[j4 * 4 + 0][i] = v.x;
      At[j4 * 4 + 1][i] = v.y;
      At[j4 * 4 + 2][i] = v.z;
      At[j4 * 4 + 3][i] = v.w;
    }
    for (int f = tid; f < 2048; f += TPB) {  // B tiles (cos,sin)
      int kk = f >> 6, j = f & 63;
      int col = n0 + j;
      float c = 0.f, s = 0.f;
      if (col < WF) { c = Tc[(k0 + kk) * WF + col]; s = Ts[(k0 + kk) * WF + col]; }
      Bc[kk][j] = c; Bs[kk][j] = s;
    }
    __syncthreads();
#pragma unroll 8
    for (int kk = 0; kk < 32; ++kk) {
      float4 a4 = *(const float4*)&At[kk][ty * 4];
      float4 c4 = *(const float4*)&Bc[kk][tx * 4];
      float4 s4 = *(const float4*)&Bs[kk][tx * 4];
      float av[4] = {a4.x, a4.y, a4.z, a4.w};
      float cv[4] = {c4.x, c4.y, c4.z, c4.w};
      float sv[4] = {s4.x, s4.y, s4.z, s4.w};
#pragma unroll
      for (int ii = 0; ii < 4; ++ii)
#pragma unroll
        for (int jj = 0; jj < 4; ++jj) {
          ar[ii][jj] += av[ii] * cv[jj];
          ai[ii][jj] += av[ii] * sv[jj];
        }
    }
    __syncthreads();
  }
#pragma unroll
  for (int ii = 0; ii < 4; ++ii) {
    int mrow = m0 + ty * 4 + ii;       // flat (bc,h) row
    int bcl = mrow >> 8, h = mrow & 255;
#pragma unroll
    for (int jj = 0; jj < 4; ++jj) {
      int n = n0 + tx * 4 + jj;
      if (n < WF) {
        size_t idx = ((size_t)bcl * FTROWS + n) * 256 + h;
        Frt[idx] = f2bf(ar[ii][jj]);
        Fit[idx] = f2bf(-ai[ii][jj]);  // forward: Fi = -sum x*sin
      }
    }
  }
}

// ------- K2: forward H-DFT via bf16 MFMA. Zero-VALU staging (global_load_lds x4). -------
// G[m][n] = sum_k CbA[fu][m][k]*Frt[n][k] + SbA[fu][m][k]*Fit[n][k]  (k = absolute h)
// Gi      = sum_k CbA*Fit - SbA*Frt
__global__ __launch_bounds__(TPB) void k_dfth_fwd_mfma(const us16* __restrict__ Frt,
                                                       const us16* __restrict__ Fit,
                                                       const us16* __restrict__ CbA,
                                                       const us16* __restrict__ SbA,
                                                       float* __restrict__ G, int fu) {
  __shared__ __align__(16) us16 AsC[64][32];
  __shared__ __align__(16) us16 AsS[64][32];
  __shared__ __align__(16) us16 BsR[64][32];
  __shared__ __align__(16) us16 BsI[64][32];
  const int tid = threadIdx.x;
  const int w = tid >> 6, lane = tid & 63;
  const int bc = blockIdx.z, b = bc >> 6, c = bc & 63;
  const int m0 = blockIdx.y * 64, n0 = blockIdx.x * 64;
  const int rsel = lane >> 2, csel = lane & 3;
  us16* ldsAC = &AsC[16 * w][0];
  us16* ldsAS = &AsS[16 * w][0];
  us16* ldsBR = &BsR[16 * w][0];
  us16* ldsBI = &BsI[16 * w][0];
  const size_t arow_g = (size_t)(fu * 256 + m0 + 16 * w + rsel);
  const us16* gAC = CbA + (arow_g << 8) + csel * 8;
  const us16* gAS = SbA + (arow_g << 8) + csel * 8;
  const size_t brow_g = (size_t)bc * FTROWS + n0 + 16 * w + rsel;
  const us16* gBR = Frt + (brow_g << 8) + csel * 8;
  const us16* gBI = Fit + (brow_g << 8) + csel * 8;
  f32x4 accr[4] = {}, acci[4] = {};
  const int arow = 16 * w + (lane & 15);
  const int kb = 8 * (lane >> 4);
  for (int k0 = 0; k0 < 256; k0 += 32) {
    gload16(gAC + k0, ldsAC);
    gload16(gAS + k0, ldsAS);
    gload16(gBR + k0, ldsBR);
    gload16(gBI + k0, ldsBI);
    __syncthreads();
    bf16x8 aC = *(const bf16x8*)&AsC[arow][kb];
    bf16x8 aS = *(const bf16x8*)&AsS[arow][kb];
    uint4 su = *(const uint4*)&aS;
    su.x ^= 0x80008000u; su.y ^= 0x80008000u; su.z ^= 0x80008000u; su.w ^= 0x80008000u;
    bf16x8 aSn = *(const bf16x8*)&su;
#pragma unroll
    for (int t = 0; t < 4; ++t) {
      int nr = 16 * t + (lane & 15);
      bf16x8 bR = *(const bf16x8*)&BsR[nr][kb];
      bf16x8 bI = *(const bf16x8*)&BsI[nr][kb];
      accr[t] = __builtin_amdgcn_mfma_f32_16x16x32_bf16(aC, bR, accr[t], 0, 0, 0);
      accr[t] = __builtin_amdgcn_mfma_f32_16x16x32_bf16(aS, bI, accr[t], 0, 0, 0);
      acci[t] = __builtin_amdgcn_mfma_f32_16x16x32_bf16(aC, bI, acci[t], 0, 0, 0);
      acci[t] = __builtin_amdgcn_mfma_f32_16x16x32_bf16(aSn, bR, acci[t], 0, 0, 0);
    }
    __syncthreads();
  }
  float* gr = G + (size_t)(b * CH2 + c) * HWF;
  float* gi = G + (size_t)(b * CH2 + CH + c) * HWF;
  const int mb = m0 + 16 * w + 4 * (lane >> 4);
#pragma unroll
  for (int t = 0; t < 4; ++t) {
    int n = n0 + 16 * t + (lane & 15);
    if (n < WF) {
#pragma unroll
      for (int j = 0; j < 4; ++j) {
        int m = mb + j;
        if (m < HH) {
          gr[(size_t)m * WF + n] = accr[t][j];
          gi[(size_t)m * WF + n] = acci[t][j];
        }
      }
    }
  }
}

// ---------------- K3: 1x1 conv  Y[o][s] = sum_c W[o][c] G[c][s] + bias[o] ----------------
__global__ __launch_bounds__(TPB) void k_conv(const float* __restrict__ G,
                                              const float* __restrict__ W,
                                              const float* __restrict__ bias,
                                              float* __restrict__ Y) {
  __shared__ float Wt[32][68], Gt[32][68];
  const int tid = threadIdx.x;
  const int tx = tid & 15, ty = tid >> 4;
  const int b = blockIdx.z;
  const int o0 = blockIdx.y * 64;
  const int s0 = blockIdx.x * 64;
  const float* gb = G + (size_t)b * CH2 * HWF;
  float acc[4][4] = {{0.f}};
  for (int c0 = 0; c0 < CH2; c0 += 32) {
    for (int f = tid; f < 2048; f += TPB) {
      int i = f >> 5, kk = f & 31;
      Wt[kk][i] = W[(o0 + i) * CH2 + c0 + kk];
    }
    for (int f = tid; f < 2048; f += TPB) {
      int kk = f >> 6, j = f & 63;
      float v = 0.f;
      if (s0 + j < HWF) v = gb[(size_t)(c0 + kk) * HWF + s0 + j];
      Gt[kk][j] = v;
    }
    __syncthreads();
#pragma unroll 8
    for (int kk = 0; kk < 32; ++kk) {
      float4 a4 = *(const float4*)&Wt[kk][ty * 4];
      float4 b4 = *(const float4*)&Gt[kk][tx * 4];
      float av[4] = {a4.x, a4.y, a4.z, a4.w};
      float bv[4] = {b4.x, b4.y, b4.z, b4.w};
#pragma unroll
      for (int ii = 0; ii < 4; ++ii)
#pragma unroll
        for (int jj = 0; jj < 4; ++jj) acc[ii][jj] += av[ii] * bv[jj];
    }
    __syncthreads();
  }
#pragma unroll
  for (int ii = 0; ii < 4; ++ii) {
    int o = o0 + ty * 4 + ii;
    float bvv = bias[o];
#pragma unroll
    for (int jj = 0; jj < 4; ++jj) {
      int s = s0 + tx * 4 + jj;
      if (s < HWF) Y[((size_t)b * CH2 + o) * HWF + s] = acc[ii][jj] + bvv;
    }
  }
}

// ---------------- K4: GroupNorm stats (deterministic two-stage) ----------------
__global__ __launch_bounds__(TPB) void k_gn_part(const float* __restrict__ Y,
                                                 float* __restrict__ part) {
  const int tid = threadIdx.x;
  const int bgj = blockIdx.x;            // channel index
  const float* p = Y + (size_t)bgj * HWF;
  float s = 0.f, ss = 0.f;
  for (int i = tid; i < HWF; i += TPB) {
    float v = p[i];
    s += v; ss += v * v;
  }
  __shared__ float rs[TPB], rq[TPB];
  rs[tid] = s; rq[tid] = ss;
  __syncthreads();
  for (int st = TPB / 2; st > 0; st >>= 1) {
    if (tid < st) { rs[tid] += rs[tid + st]; rq[tid] += rq[tid + st]; }
    __syncthreads();
  }
  if (tid == 0) { part[bgj * 2] = rs[0]; part[bgj * 2 + 1] = rq[0]; }
}

__global__ void k_gn_stats(const float* __restrict__ part,
                           float* __restrict__ stats, int nbg) {
  int bg = blockIdx.x * blockDim.x + threadIdx.x;
  if (bg < nbg) {
    float s = 0.f, ss = 0.f;
    for (int j = 0; j < 8; ++j) {
      s += part[(bg * 8 + j) * 2];
      ss += part[(bg * 8 + j) * 2 + 1];
    }
    const float inv = 1.f / (8.f * (float)HWF);
    float mean = s * inv;
    float var = ss * inv - mean * mean;
    stats[bg * 2] = mean;
    stats[bg * 2 + 1] = rsqrtf(var + GN_EPS);
  }
}

// ------- K6: GN+ReLU fused + inverse H-DFT via bf16 MFMA (128 surviving rows) -------
// accr = sum_k C[k][hsel+m]*relu(gn(yr[k][n])) - S[k][hsel+m]*relu(gn(yi[k][n]))
// acci = sum_k C*yi_n + S*yr_n ; A from CbA[0]/SbA[0] rows hsel+m (symmetric table).
__global__ __launch_bounds__(TPB) void k_dfth_inv_mfma(const float* __restrict__ Y,
                                                       const us16* __restrict__ CbA,
                                                       const us16* __restrict__ SbA,
                                                       const float* __restrict__ stats,
                                                       const float* __restrict__ gamma,
                                                       const float* __restrict__ beta,
                                                       float* __restrict__ Hr,
                                                       float* __restrict__ Hi,
                                                       int hsel) {
  __shared__ __align__(16) us16 AsC[64][32];
  __shared__ __align__(16) us16 AsS[64][32];
  __shared__ __align__(8)  us16 BsR[64][36];   // stride 36 u16 = 72B: write conflicts ~4-way
  __shared__ __align__(8)  us16 BsI[64][36];
  const int tid = threadIdx.x;
  const int w = tid >> 6, lane = tid & 63;
  const int bc = blockIdx.z, b = bc >> 6, c = bc & 63;
  const float* yr = Y + (size_t)(b * CH2 + c) * HWF;
  const float* yi = Y + (size_t)(b * CH2 + CH + c) * HWF;
  const int g1 = b * 16 + (c >> 3);
  const int g2 = g1 + 8;
  const float is1 = stats[g1 * 2 + 1], mu1 = stats[g1 * 2];
  const float is2 = stats[g2 * 2 + 1], mu2 = stats[g2 * 2];
  const float sc1 = gamma[c] * is1,      sh1 = beta[c] - mu1 * sc1;
  const float sc2 = gamma[CH + c] * is2, sh2 = beta[CH + c] - mu2 * sc2;
  const int m0 = blockIdx.y * 64, n0 = blockIdx.x * 64;
  const int rsel = lane >> 2, csel = lane & 3;
  us16* ldsAC = &AsC[16 * w][0];
  us16* ldsAS = &AsS[16 * w][0];
  const size_t arow_g = (size_t)(hsel + m0 + 16 * w + rsel);
  const us16* gAC = CbA + (arow_g << 8) + csel * 8;
  const us16* gAS = SbA + (arow_g << 8) + csel * 8;
  f32x4 accr[4] = {}, acci[4] = {};
  const int arow = 16 * w + (lane & 15);
  const int kb = 8 * (lane >> 4);
  for (int k0 = 0; k0 < 256; k0 += 32) {
    gload16(gAC + k0, ldsAC);
    gload16(gAS + k0, ldsAS);
    for (int ff = tid; ff < 1024; ff += TPB) {   // B staging: GN+ReLU+cvt+transpose
      int kp = ff >> 6, n = ff & 63;             // lanes: consecutive n -> coalesced
      int k1 = k0 + 2 * kp, k2 = k1 + 1;
      int nn = n0 + n;
      float r1 = 0.f, r2 = 0.f, i1 = 0.f, i2 = 0.f;
      if (nn < WF) {
        if (k1 < HH) { r1 = yr[(size_t)k1 * WF + nn] * sc1 + sh1; i1 = yi[(size_t)k1 * WF + nn] * sc2 + sh2; }
        if (k2 < HH) { r2 = yr[(size_t)k2 * WF + nn] * sc1 + sh1; i2 = yi[(size_t)k2 * WF + nn] * sc2 + sh2; }
      }
      r1 = fmaxf(r1, 0.f); r2 = fmaxf(r2, 0.f);
      i1 = fmaxf(i1, 0.f); i2 = fmaxf(i2, 0.f);
      *(unsigned int*)&BsR[n][2 * kp] = (unsigned)f2bf(r1) | ((unsigned)f2bf(r2) << 16);
      *(unsigned int*)&BsI[n][2 * kp] = (unsigned)f2bf(i1) | ((unsigned)f2bf(i2) << 16);
    }
    __syncthreads();
    bf16x8 aC = *(const bf16x8*)&AsC[arow][kb];
    bf16x8 aS = *(const bf16x8*)&AsS[arow][kb];
    uint4 su = *(const uint4*)&aS;
    su.x ^= 0x80008000u; su.y ^= 0x80008000u; su.z ^= 0x80008000u; su.w ^= 0x80008000u;
    bf16x8 aSn = *(const bf16x8*)&su;
#pragma unroll
    for (int t = 0; t < 4; ++t) {
      int nr = 16 * t + (lane & 15);
      uint2 lo = *(const uint2*)&BsR[nr][kb];
      uint2 hi = *(const uint2*)&BsR[nr][kb + 4];
      uint4 q1; q1.x = lo.x; q1.y = lo.y; q1.z = hi.x; q1.w = hi.y;
      bf16x8 bR = *(const bf16x8*)&q1;
      lo = *(const uint2*)&BsI[nr][kb];
      hi = *(const uint2*)&BsI[nr][kb + 4];
      uint4 q2; q2.x = lo.x; q2.y = lo.y; q2.z = hi.x; q2.w = hi.y;
      bf16x8 bI = *(const bf16x8*)&q2;
      accr[t] = __builtin_amdgcn_mfma_f32_16x16x32_bf16(aC, bR, accr[t], 0, 0, 0);
      accr[t] = __builtin_amdgcn_mfma_f32_16x16x32_bf16(aSn, bI, accr[t], 0, 0, 0);
      acci[t] = __builtin_amdgcn_mfma_f32_16x16x32_bf16(aC, bI, acci[t], 0, 0, 0);
      acci[t] = __builtin_amdgcn_mfma_f32_16x16x32_bf16(aS, bR, acci[t], 0, 0, 0);
    }
    __syncthreads();
  }
  const float inv = 1.f / 255.f;
  const int mb = m0 + 16 * w + 4 * (lane >> 4);
#pragma unroll
  for (int t = 0; t < 4; ++t) {
    int n = n0 + 16 * t + (lane & 15);
    if (n < WF) {
#pragma unroll
      for (int j = 0; j < 4; ++j) {
        int m = mb + j;  // always < 128
        Hr[((size_t)bc * 128 + m) * WF + n] = accr[t][j] * inv;
        Hi[((size_t)bc * 128 + m) * WF + n] = acci[t][j] * inv;
      }
    }
  }
}

// ------- K7: inverse W-DFT (Hermitian-folded, K=129) + scatter into d_out -------
__global__ __launch_bounds__(TPB) void k_dftw_inv(const float* __restrict__ Hr,
                                                  const float* __restrict__ Hi,
                                                  const float* __restrict__ Tc,
                                                  const float* __restrict__ Ts,
                                                  float* __restrict__ out,
                                                  int roff, int b0) {
  __shared__ float Ar[32][68], Ai[32][68], Bc[32][68], Bs[32][68];
  const int tid = threadIdx.x;
  const int tx = tid & 15, ty = tid >> 4;
  const int m0 = blockIdx.y * 64;
  const int n0 = blockIdx.x * 64;
  float acc[4][4] = {{0.f}};
  for (int k0 = 0; k0 < WF; k0 += 32) {
    const int klim = min(32, WF - k0);
    for (int f = tid; f < 2048; f += TPB) {
      int i = f >> 5, j = f & 31;
      float rv = 0.f, iv = 0.f;
      if (j < klim) {
        size_t idx = (size_t)(m0 + i) * WF + k0 + j;
        rv = Hr[idx]; iv = Hi[idx];
      }
      Ar[j][i] = rv; Ai[j][i] = iv;
    }
    for (int f = tid; f < 2048; f += TPB) {
      int kk = f >> 6, j = f & 63;
      float cv = 0.f, sv = 0.f;
      if (kk < klim) {
        cv = Tc[(k0 + kk) * 256 + n0 + j];
        sv = Ts[(k0 + kk) * 256 + n0 + j];
      }
      Bc[kk][j] = cv; Bs[kk][j] = sv;
    }
    __syncthreads();
#pragma unroll 4
    for (int kk = 0; kk < 32; ++kk) {
      float4 r4 = *(const float4*)&Ar[kk][ty * 4];
      float4 i4 = *(const float4*)&Ai[kk][ty * 4];
      float4 c4 = *(const float4*)&Bc[kk][tx * 4];
      float4 s4 = *(const float4*)&Bs[kk][tx * 4];
      float rv[4] = {r4.x, r4.y, r4.z, r4.w};
      float iv[4] = {i4.x, i4.y, i4.z, i4.w};
      float cv[4] = {c4.x, c4.y, c4.z, c4.w};
      float sv[4] = {s4.x, s4.y, s4.z, s4.w};
#pragma unroll
      for (int ii = 0; ii < 4; ++ii)
#pragma unroll
        for (int jj = 0; jj < 4; ++jj)
          acc[ii][jj] += rv[ii] * cv[jj] - iv[ii] * sv[jj];
    }
    __syncthreads();
  }
#pragma unroll
  for (int ii = 0; ii < 4; ++ii) {
    int r = m0 + ty * 4 + ii;            // (b_local*64 + c)*128 + m
    int bl = r >> 13;
    int rem = r & 8191;
    int cch = rem >> 7;
    int m = rem & 127;
    size_t obase = (((size_t)(b0 + bl) * CH + cch) * HIN + roff + m) * WIN;
#pragma unroll
    for (int jj = 0; jj < 4; ++jj) out[obase + n0 + tx * 4 + jj] = acc[ii][jj];
  }
}

// ---------------- host ----------------
extern "C" void kernel_launch(void* const* d_in, const int* in_sizes, int n_in,
                              void* d_out, int out_size, void* d_ws, size_t ws_size,
                              hipStream_t stream) {
  const float* x        = (const float*)d_in[0];
  const float* conv_w   = (const float*)d_in[1];
  const float* conv_b   = (const float*)d_in[2];
  const float* gn_gamma = (const float*)d_in[3];
  const float* gn_beta  = (const float*)d_in[4];
  float* out = (float*)d_out;
  float* ws  = (float*)d_ws;

  const size_t szT   = 256 * WF;            // 33024 floats per W-DFT table
  const size_t szBft = 2 * 256 * 256;       // u16 per bf16 H-table (=65536 float slots)
  const size_t fixed = 4 * szT + 2 * (szBft / 2) + 1024 + 128;  // float slots
  // per-batch float slots: Frt+Fit (u16) + G + Yb
  const size_t perF  = (size_t)CH * FTROWS * 256;               // u16 per batch per buffer
  const size_t per   = perF /*Frt*/ / 2 * 2  /*both, in float slots: 2*(perF/2)*/
                       + 2ull * CH2 * HWF;
  // = perF (floats for Frt+Fit) + 2*CH2*HWF
  int nb = 0;
  if ((fixed + 4ull * per + 1024) * sizeof(float) <= ws_size) nb = 4;
  else if ((fixed + 2ull * per + 1024) * sizeof(float) <= ws_size) nb = 2;
  else if ((fixed + 1ull * per + 1024) * sizeof(float) <= ws_size) nb = 1;

  if (nb == 0) {
    k_zero<<<dim3((out_size + TPB - 1) / TPB), dim3(TPB), 0, stream>>>(out, out_size);
    return;
  }

  float* Tc1 = ws;
  float* Ts1 = Tc1 + szT;
  float* Tci = Ts1 + szT;
  float* Tsi = Tci + szT;
  us16*  CbA = (us16*)(Tsi + szT);
  us16*  SbA = CbA + szBft;
  float* part  = (float*)(SbA + szBft);
  float* stats = part + 1024;
  float* base  = stats + 128;

  us16*  Frt = (us16*)base;
  us16*  Fit = Frt + (size_t)nb * perF;
  float* G   = (float*)(Fit + (size_t)nb * perF);
  float* Yb  = G + (size_t)nb * CH2 * HWF;
  float* Hr  = G;                                   // aliases G (free after conv)
  float* Hi  = G + (size_t)nb * CH * 128 * WF;

  k_tables<<<dim3(512), dim3(TPB), 0, stream>>>(Tc1, Ts1, Tci, Tsi, CbA, SbA);

  for (int b0 = 0; b0 < B_ALL; b0 += nb) {
    // shared forward W-DFT over all 256 input rows -> bf16 transposed Frt/Fit
    k_dftw_fwd<<<dim3(nb * CH * HIN / 64, 3), dim3(TPB), 0, stream>>>(
        x + (size_t)b0 * CH * HIN * WIN, Tc1, Ts1, Frt, Fit);
    for (int fu = 0; fu < 2; ++fu) {
      const int hsel = fu ? 127 : 0;  // surviving h' window start
      const int roff = fu ? 128 : 0;  // output row offset
      k_dfth_fwd_mfma<<<dim3(3, 4, nb * CH), dim3(TPB), 0, stream>>>(
          Frt, Fit, CbA, SbA, G, fu);
      k_conv<<<dim3((HWF + 63) / 64, 2, nb), dim3(TPB), 0, stream>>>(G, conv_w, conv_b, Yb);
      k_gn_part<<<dim3(nb * 16 * 8), dim3(TPB), 0, stream>>>(Yb, part);
      k_gn_stats<<<dim3(1), dim3(64), 0, stream>>>(part, stats, nb * 16);
      k_dfth_inv_mfma<<<dim3(3, 2, nb * CH), dim3(TPB), 0, stream>>>(
          Yb, CbA, SbA, stats, gn_gamma, gn_beta, Hr, Hi, hsel);
      k_dftw_inv<<<dim3(4, nb * CH * 128 / 64), dim3(TPB), 0, stream>>>(
          Hr, Hi, Tci, Tsi, out, roff, b0);
    }
  }
}

// Round 6
// 338.315 us; speedup vs baseline: 5.3759x; 2.6034x over previous
//
#include <hip/hip_runtime.h>
#include <math.h>

#define TPB 256

typedef unsigned short us16;
typedef __bf16 bf16x8 __attribute__((ext_vector_type(8)));
typedef float f32x4 __attribute__((ext_vector_type(4)));

static const int B_ALL = 4;
static const int CH   = 64;          // input channels
static const int HIN  = 256, WIN = 256;
static const int HH   = 255;         // cropped height
static const int WF   = 129;         // rfft bins along W
static const int HWF  = HH * WF;     // 32895
static const int HWFP = 32896;       // padded Y channel stride (16B aligned)
static const int NT   = 192;         // padded n rows (3 x 64)
static const int SP   = NT * 256;    // 49152 padded spatial per channel
static const int SPV  = WF * 256;    // 33024 valid spatial
static const int KH   = 160;         // padded K for inverse W-DFT (129 -> 160)
#define GN_EPS 1e-5f

__device__ __forceinline__ us16 f2bf(float f) {
  union { float f; unsigned u; } v; v.f = f;
  unsigned r = v.u + 0x7FFFu + ((v.u >> 16) & 1u);
  return (us16)(r >> 16);
}
__device__ __forceinline__ float bf2f(us16 v) {
  union { unsigned u; float f; } t; t.u = ((unsigned)v) << 16; return t.f;
}
__device__ __forceinline__ void gload16(const void* g, void* l) {
  __builtin_amdgcn_global_load_lds(
      (const __attribute__((address_space(1))) unsigned int*)g,
      (__attribute__((address_space(3))) unsigned int*)l, 16, 0, 0);
}
#define MFMA __builtin_amdgcn_mfma_f32_16x16x32_bf16

// ---------------- fallback: zero output ----------------
__global__ __launch_bounds__(TPB) void k_zero(float* __restrict__ out, int n) {
  int i = blockIdx.x * TPB + threadIdx.x;
  if (i < n) out[i] = 0.f;
}

// ---------------- cast x f32 -> bf16 ----------------
__global__ __launch_bounds__(TPB) void k_xcast(const float* __restrict__ x,
                                               us16* __restrict__ xb, int n4) {
  int i = blockIdx.x * TPB + threadIdx.x;
  if (i < n4) {
    float4 v = ((const float4*)x)[i];
    ushort4 o;
    o.x = f2bf(v.x); o.y = f2bf(v.y); o.z = f2bf(v.z); o.w = f2bf(v.w);
    ((ushort4*)xb)[i] = o;
  }
}

// ---------------- all-bf16 DFT tables + mix weights ----------------
// CbA/SbA [2][256][256]: CbA[fu][r][k] = cos(2pi r(k-fu)/255), 0 outside (H-DFT)
// Tcb/Tsb [192][256]: W-DFT fwd transposed [n][w], zero pad n>=129
// Tci/Tsi [256][160]: W-DFT inverse [w][k] with Hermitian coef and /256, zero pad k>=129
// Wpb = conv_w; Wqb[o][c] = c<64 ? -conv_w[o][64+c] : conv_w[o][c-64]
__global__ __launch_bounds__(TPB) void k_tables(
    us16* __restrict__ CbA, us16* __restrict__ SbA,
    us16* __restrict__ Tcb, us16* __restrict__ Tsb,
    us16* __restrict__ Tci, us16* __restrict__ Tsi,
    us16* __restrict__ Wpb, us16* __restrict__ Wqb,
    const float* __restrict__ conv_w) {
  int i = blockIdx.x * TPB + threadIdx.x;
  const double PI2 = 6.283185307179586476925286766559;
  if (i < 2 * 65536) {
    int fu = i >> 16, r = (i >> 8) & 255, k = i & 255;
    float cv = 0.f, sv = 0.f;
    int kk = k - fu;
    if (r < 255 && kk >= 0 && kk < 255) {
      double ang = PI2 * (double)((r * kk) % 255) / 255.0;
      cv = (float)cos(ang); sv = (float)sin(ang);
    }
    CbA[i] = f2bf(cv); SbA[i] = f2bf(sv);
  }
  if (i < NT * 256) {
    int n = i >> 8, w = i & 255;
    float cv = 0.f, sv = 0.f;
    if (n < WF) {
      double ang = PI2 * (double)((n * w) & 255) / 256.0;
      cv = (float)cos(ang); sv = (float)sin(ang);
    }
    Tcb[i] = f2bf(cv); Tsb[i] = f2bf(sv);
  }
  if (i < 256 * KH) {
    int w = i / KH, k = i - w * KH;
    float cv = 0.f, sv = 0.f;
    if (k < WF) {
      double coef = (k == 0 || k == 128) ? 1.0 : 2.0;
      double ang = PI2 * (double)((k * w) & 255) / 256.0;
      cv = (float)(coef * cos(ang) / 256.0);
      sv = (float)(coef * sin(ang) / 256.0);
    }
    Tci[i] = f2bf(cv); Tsi[i] = f2bf(sv);
  }
  if (i < 128 * 128) {
    int o = i >> 7, c = i & 127;
    Wpb[i] = f2bf(conv_w[i]);
    float q = (c < 64) ? -conv_w[o * 128 + 64 + c] : conv_w[o * 128 + c - 64];
    Wqb[i] = f2bf(q);
  }
}

// ------- K1: forward W-DFT via MFMA -> Frt/Fit[bc][n][h] bf16 -------
// Frt[n][h] = sum_w Tcb[n][w] xb[h][w];  Fit[n][h] = -sum_w Tsb[n][w] xb[h][w]
__global__ __launch_bounds__(TPB) void k_dftw_fwd_mfma(
    const us16* __restrict__ xb, const us16* __restrict__ Tcb,
    const us16* __restrict__ Tsb, us16* __restrict__ Frt, us16* __restrict__ Fit) {
  __shared__ __align__(16) us16 Ac[64][32];
  __shared__ __align__(16) us16 As[64][32];
  __shared__ __align__(16) us16 Bx[64][32];
  const int tid = threadIdx.x, w = tid >> 6, lane = tid & 63;
  const int hb = blockIdx.x;             // 64 flat (bc,h) rows
  const int n0 = blockIdx.y * 64;
  const int rsel = lane >> 2;
  const int csw = (lane & 3) ^ ((lane >> 3) & 3);
  const us16* gAc = Tcb + (size_t)(n0 + 16 * w + rsel) * 256 + csw * 8;
  const us16* gAs = Tsb + (size_t)(n0 + 16 * w + rsel) * 256 + csw * 8;
  const us16* gB  = xb + ((size_t)hb * 64 + 16 * w + rsel) * 256 + csw * 8;
  f32x4 accr[4] = {}, acci[4] = {};
  const int fr = lane & 15;
  const int kb = 8 * ((lane >> 4) ^ ((lane >> 1) & 3));
  for (int k0 = 0; k0 < 256; k0 += 32) {
    gload16(gAc + k0, &Ac[16 * w][0]);
    gload16(gAs + k0, &As[16 * w][0]);
    gload16(gB + k0, &Bx[16 * w][0]);
    __syncthreads();
    bf16x8 aC = *(const bf16x8*)&Ac[16 * w + fr][kb];
    bf16x8 aS = *(const bf16x8*)&As[16 * w + fr][kb];
    uint4 su = *(const uint4*)&aS;
    su.x ^= 0x80008000u; su.y ^= 0x80008000u; su.z ^= 0x80008000u; su.w ^= 0x80008000u;
    bf16x8 aSn = *(const bf16x8*)&su;
#pragma unroll
    for (int t = 0; t < 4; ++t) {
      bf16x8 b = *(const bf16x8*)&Bx[16 * t + fr][kb];
      accr[t] = MFMA(aC, b, accr[t], 0, 0, 0);
      acci[t] = MFMA(aSn, b, acci[t], 0, 0, 0);
    }
    __syncthreads();
  }
  const int bc = hb >> 2, hl = (hb & 3) * 64;
#pragma unroll
  for (int t = 0; t < 4; ++t) {
    int h = hl + 16 * t + fr;
#pragma unroll
    for (int j = 0; j < 4; ++j) {
      int n = n0 + 16 * w + 4 * (lane >> 4) + j;
      if (n < WF) {
        size_t idx = ((size_t)bc * NT + n) * 256 + h;
        Frt[idx] = f2bf(accr[t][j]);
        Fit[idx] = f2bf(acci[t][j]);
      }
    }
  }
}

// ------- K2: channel-mix (conv commuted before H-DFT): P = Wp.[Fr;Fi], Q = Wq.[Fr;Fi] -------
__global__ __launch_bounds__(TPB) void k_mix(
    const us16* __restrict__ Frt, const us16* __restrict__ Fit,
    const us16* __restrict__ Wpb, const us16* __restrict__ Wqb,
    us16* __restrict__ P, us16* __restrict__ Q) {
  __shared__ __align__(16) us16 Ap[64][32];
  __shared__ __align__(16) us16 Aq[64][32];
  __shared__ __align__(8)  us16 Bs[64][36];
  const int tid = threadIdx.x, w = tid >> 6, lane = tid & 63;
  const int sp0 = blockIdx.x * 64, o0 = blockIdx.y * 64, b = blockIdx.z;
  const int rsel = lane >> 2;
  const int csw = (lane & 3) ^ ((lane >> 3) & 3);
  const us16* gAp = Wpb + (size_t)(o0 + 16 * w + rsel) * 128 + csw * 8;
  const us16* gAq = Wqb + (size_t)(o0 + 16 * w + rsel) * 128 + csw * 8;
  f32x4 accp[4] = {}, accq[4] = {};
  const int fr = lane & 15;
  const int kbA = 8 * ((lane >> 4) ^ ((lane >> 1) & 3));
  const int kbB = 8 * (lane >> 4);
  for (int c0 = 0; c0 < 128; c0 += 32) {
    gload16(gAp + c0, &Ap[16 * w][0]);
    gload16(gAq + c0, &Aq[16 * w][0]);
    for (int f = tid; f < 1024; f += TPB) {      // transpose-stage F [c][sp] -> [sp][c]
      int cl = f >> 5, spp = f & 31;
      int c = c0 + cl;
      const us16* src = (c < 64) ? Frt : Fit;
      size_t addr = (size_t)(b * 64 + (c & 63)) * SP + sp0 + 2 * spp;
      unsigned v = *(const unsigned*)(src + addr);
      Bs[2 * spp][cl] = (us16)v;
      Bs[2 * spp + 1][cl] = (us16)(v >> 16);
    }
    __syncthreads();
    bf16x8 aP = *(const bf16x8*)&Ap[16 * w + fr][kbA];
    bf16x8 aQ = *(const bf16x8*)&Aq[16 * w + fr][kbA];
#pragma unroll
    for (int t = 0; t < 4; ++t) {
      uint2 lo = *(const uint2*)&Bs[16 * t + fr][kbB];
      uint2 hi = *(const uint2*)&Bs[16 * t + fr][kbB + 4];
      uint4 qq; qq.x = lo.x; qq.y = lo.y; qq.z = hi.x; qq.w = hi.y;
      bf16x8 bb = *(const bf16x8*)&qq;
      accp[t] = MFMA(aP, bb, accp[t], 0, 0, 0);
      accq[t] = MFMA(aQ, bb, accq[t], 0, 0, 0);
    }
    __syncthreads();
  }
#pragma unroll
  for (int t = 0; t < 4; ++t) {
    int sp = sp0 + 16 * t + fr;
#pragma unroll
    for (int j = 0; j < 4; ++j) {
      int o = o0 + 16 * w + 4 * (lane >> 4) + j;
      size_t idx = (size_t)(b * 128 + o) * SP + sp;
      P[idx] = f2bf(accp[t][j]);
      Q[idx] = f2bf(accq[t][j]);
    }
  }
}

// ------- K3: H-DFT fwd (= conv output): Y[m][n] = sum_h C[fu][m][h] P[n][h] + S[fu][m][h] Q[n][h] + bias -------
__global__ __launch_bounds__(TPB) void k_dfth_fwd2(
    const us16* __restrict__ P, const us16* __restrict__ Q,
    const us16* __restrict__ CbA, const us16* __restrict__ SbA,
    const float* __restrict__ bias, us16* __restrict__ Yb, int fu) {
  __shared__ __align__(16) us16 Ac[4][64][32];
  __shared__ __align__(16) us16 As[4][64][32];
  __shared__ __align__(16) us16 Bp[64][32];
  __shared__ __align__(16) us16 Bq[64][32];
  const int tid = threadIdx.x, w = tid >> 6, lane = tid & 63;
  const int bz = blockIdx.z;
  const int n0 = blockIdx.x * 64;
  const int rsel = lane >> 2;
  const int csw = (lane & 3) ^ ((lane >> 3) & 3);
  const us16* gAc = CbA + (((size_t)fu * 256 + 16 * w + rsel) << 8) + csw * 8;
  const us16* gAs = SbA + (((size_t)fu * 256 + 16 * w + rsel) << 8) + csw * 8;
  const us16* gBp = P + ((size_t)bz * NT + n0 + 16 * w + rsel) * 256 + csw * 8;
  const us16* gBq = Q + ((size_t)bz * NT + n0 + 16 * w + rsel) * 256 + csw * 8;
  f32x4 acc[4][4] = {};
  const int fr = lane & 15;
  const int kb = 8 * ((lane >> 4) ^ ((lane >> 1) & 3));
  for (int k0 = 0; k0 < 256; k0 += 32) {
#pragma unroll
    for (int mt = 0; mt < 4; ++mt) {
      gload16(gAc + (mt << 14) + k0, &Ac[mt][16 * w][0]);
      gload16(gAs + (mt << 14) + k0, &As[mt][16 * w][0]);
    }
    gload16(gBp + k0, &Bp[16 * w][0]);
    gload16(gBq + k0, &Bq[16 * w][0]);
    __syncthreads();
    bf16x8 aC[4], aS[4];
#pragma unroll
    for (int mt = 0; mt < 4; ++mt) {
      aC[mt] = *(const bf16x8*)&Ac[mt][16 * w + fr][kb];
      aS[mt] = *(const bf16x8*)&As[mt][16 * w + fr][kb];
    }
#pragma unroll
    for (int t = 0; t < 4; ++t) {
      bf16x8 bP = *(const bf16x8*)&Bp[16 * t + fr][kb];
      bf16x8 bQ = *(const bf16x8*)&Bq[16 * t + fr][kb];
#pragma unroll
      for (int mt = 0; mt < 4; ++mt) {
        acc[mt][t] = MFMA(aC[mt], bP, acc[mt][t], 0, 0, 0);
        acc[mt][t] = MFMA(aS[mt], bQ, acc[mt][t], 0, 0, 0);
      }
    }
    __syncthreads();
  }
  const float bo = bias[bz & 127];
  us16* yc = Yb + (size_t)bz * HWFP;
#pragma unroll
  for (int t = 0; t < 4; ++t) {
    int n = n0 + 16 * t + fr;
    if (n < WF) {
#pragma unroll
      for (int mt = 0; mt < 4; ++mt) {
#pragma unroll
        for (int j = 0; j < 4; ++j) {
          int m = mt * 64 + 16 * w + 4 * (lane >> 4) + j;
          if (m < HH) yc[m * WF + n] = f2bf(acc[mt][t][j] + bo);
        }
      }
    }
  }
}

// ---------------- K4: GroupNorm stats (bf16 Y, deterministic two-stage) ----------------
__global__ __launch_bounds__(TPB) void k_gn_part(const us16* __restrict__ Yb,
                                                 float* __restrict__ part) {
  const int tid = threadIdx.x;
  const int bgj = blockIdx.x;
  const us16* p = Yb + (size_t)bgj * HWFP;
  float s = 0.f, ss = 0.f;
  int i = tid * 8;
  for (; i + 8 <= HWF; i += TPB * 8) {
    uint4 v = *(const uint4*)(p + i);
    unsigned q[4] = {v.x, v.y, v.z, v.w};
#pragma unroll
    for (int u = 0; u < 4; ++u) {
      float f0 = __uint_as_float(q[u] << 16);
      float f1 = __uint_as_float(q[u] & 0xffff0000u);
      s += f0 + f1; ss += f0 * f0 + f1 * f1;
    }
  }
  for (; i < HWF; ++i) { float f = bf2f(p[i]); s += f; ss += f * f; }
  __shared__ float rs[TPB], rq[TPB];
  rs[tid] = s; rq[tid] = ss;
  __syncthreads();
  for (int st = TPB / 2; st > 0; st >>= 1) {
    if (tid < st) { rs[tid] += rs[tid + st]; rq[tid] += rq[tid + st]; }
    __syncthreads();
  }
  if (tid == 0) { part[bgj * 2] = rs[0]; part[bgj * 2 + 1] = rq[0]; }
}

__global__ void k_gn_stats(const float* __restrict__ part,
                           float* __restrict__ stats, int nbg) {
  int bg = blockIdx.x * blockDim.x + threadIdx.x;
  if (bg < nbg) {
    float s = 0.f, ss = 0.f;
    for (int j = 0; j < 8; ++j) {
      s += part[(bg * 8 + j) * 2];
      ss += part[(bg * 8 + j) * 2 + 1];
    }
    const float inv = 1.f / (8.f * (float)HWF);
    float mean = s * inv;
    float var = ss * inv - mean * mean;
    stats[bg * 2] = mean;
    stats[bg * 2 + 1] = rsqrtf(var + GN_EPS);
  }
}

// ------- K5: GN+ReLU fused + inverse H-DFT -> Hr/Hi bf16 [bc*128+m][160] -------
__global__ __launch_bounds__(TPB) void k_dfth_inv_mfma(
    const us16* __restrict__ Yb, const us16* __restrict__ CbA,
    const us16* __restrict__ SbA, const float* __restrict__ stats,
    const float* __restrict__ gamma, const float* __restrict__ beta,
    us16* __restrict__ Hr, us16* __restrict__ Hi, int hsel) {
  __shared__ __align__(16) us16 Ac[2][64][32];
  __shared__ __align__(16) us16 As[2][64][32];
  __shared__ __align__(8)  us16 BsR[64][36];
  __shared__ __align__(8)  us16 BsI[64][36];
  const int tid = threadIdx.x, w = tid >> 6, lane = tid & 63;
  const int bc = blockIdx.z, b = bc >> 6, c = bc & 63;
  const us16* yr = Yb + (size_t)(b * 128 + c) * HWFP;
  const us16* yi = Yb + (size_t)(b * 128 + 64 + c) * HWFP;
  const int g1 = b * 16 + (c >> 3), g2 = g1 + 8;
  const float sc1 = gamma[c] * stats[g1 * 2 + 1];
  const float sh1 = beta[c] - stats[g1 * 2] * sc1;
  const float sc2 = gamma[64 + c] * stats[g2 * 2 + 1];
  const float sh2 = beta[64 + c] - stats[g2 * 2] * sc2;
  const int n0 = blockIdx.x * 64;
  const int rsel = lane >> 2;
  const int csw = (lane & 3) ^ ((lane >> 3) & 3);
  const us16* gAc = CbA + (((size_t)hsel + 16 * w + rsel) << 8) + csw * 8;
  const us16* gAs = SbA + (((size_t)hsel + 16 * w + rsel) << 8) + csw * 8;
  f32x4 accr[2][4] = {}, acci[2][4] = {};
  const int fr = lane & 15;
  const int kbA = 8 * ((lane >> 4) ^ ((lane >> 1) & 3));
  const int kbB = 8 * (lane >> 4);
  for (int k0 = 0; k0 < 256; k0 += 32) {
#pragma unroll
    for (int mt = 0; mt < 2; ++mt) {
      gload16(gAc + (mt << 14) + k0, &Ac[mt][16 * w][0]);
      gload16(gAs + (mt << 14) + k0, &As[mt][16 * w][0]);
    }
    for (int f = tid; f < 1024; f += TPB) {     // GN+ReLU+cvt+transpose staging
      int kp = f >> 6, n = f & 63;
      int k1 = k0 + 2 * kp, k2 = k1 + 1;
      int nn = n0 + n;
      float r1 = 0.f, r2 = 0.f, i1 = 0.f, i2 = 0.f;
      if (nn < WF) {
        if (k1 < HH) { r1 = bf2f(yr[k1 * WF + nn]) * sc1 + sh1;
                       i1 = bf2f(yi[k1 * WF + nn]) * sc2 + sh2; }
        if (k2 < HH) { r2 = bf2f(yr[k2 * WF + nn]) * sc1 + sh1;
                       i2 = bf2f(yi[k2 * WF + nn]) * sc2 + sh2; }
      }
      r1 = fmaxf(r1, 0.f); r2 = fmaxf(r2, 0.f);
      i1 = fmaxf(i1, 0.f); i2 = fmaxf(i2, 0.f);
      *(unsigned*)&BsR[n][2 * kp] = (unsigned)f2bf(r1) | ((unsigned)f2bf(r2) << 16);
      *(unsigned*)&BsI[n][2 * kp] = (unsigned)f2bf(i1) | ((unsigned)f2bf(i2) << 16);
    }
    __syncthreads();
    bf16x8 aC[2], aS[2], aSn[2];
#pragma unroll
    for (int mt = 0; mt < 2; ++mt) {
      aC[mt] = *(const bf16x8*)&Ac[mt][16 * w + fr][kbA];
      aS[mt] = *(const bf16x8*)&As[mt][16 * w + fr][kbA];
      uint4 su = *(const uint4*)&aS[mt];
      su.x ^= 0x80008000u; su.y ^= 0x80008000u; su.z ^= 0x80008000u; su.w ^= 0x80008000u;
      aSn[mt] = *(const bf16x8*)&su;
    }
#pragma unroll
    for (int t = 0; t < 4; ++t) {
      uint2 lo = *(const uint2*)&BsR[16 * t + fr][kbB];
      uint2 hi = *(const uint2*)&BsR[16 * t + fr][kbB + 4];
      uint4 q1; q1.x = lo.x; q1.y = lo.y; q1.z = hi.x; q1.w = hi.y;
      bf16x8 bR = *(const bf16x8*)&q1;
      lo = *(const uint2*)&BsI[16 * t + fr][kbB];
      hi = *(const uint2*)&BsI[16 * t + fr][kbB + 4];
      uint4 q2; q2.x = lo.x; q2.y = lo.y; q2.z = hi.x; q2.w = hi.y;
      bf16x8 bI = *(const bf16x8*)&q2;
#pragma unroll
      for (int mt = 0; mt < 2; ++mt) {
        accr[mt][t] = MFMA(aC[mt], bR, accr[mt][t], 0, 0, 0);
        accr[mt][t] = MFMA(aSn[mt], bI, accr[mt][t], 0, 0, 0);
        acci[mt][t] = MFMA(aC[mt], bI, acci[mt][t], 0, 0, 0);
        acci[mt][t] = MFMA(aS[mt], bR, acci[mt][t], 0, 0, 0);
      }
    }
    __syncthreads();
  }
  const float inv = 1.f / 255.f;
#pragma unroll
  for (int t = 0; t < 4; ++t) {
    int n = n0 + 16 * t + fr;
    if (n < KH) {
#pragma unroll
      for (int mt = 0; mt < 2; ++mt) {
#pragma unroll
        for (int j = 0; j < 4; ++j) {
          int m = mt * 64 + 16 * w + 4 * (lane >> 4) + j;
          size_t idx = ((size_t)bc * 128 + m) * KH + n;
          Hr[idx] = (n < WF) ? f2bf(accr[mt][t][j] * inv) : (us16)0;
          Hi[idx] = (n < WF) ? f2bf(acci[mt][t][j] * inv) : (us16)0;
        }
      }
    }
  }
}

// ------- K6: inverse W-DFT via MFMA (K=160 padded) -> scatter into d_out -------
__global__ __launch_bounds__(TPB) void k_dftw_inv_mfma(
    const us16* __restrict__ Hr, const us16* __restrict__ Hi,
    const us16* __restrict__ Tci, const us16* __restrict__ Tsi,
    float* __restrict__ out, int roff, int b0) {
  __shared__ __align__(16) us16 Ar[64][32];
  __shared__ __align__(16) us16 Ai[64][32];
  __shared__ __align__(16) us16 Bc[64][32];
  __shared__ __align__(16) us16 Bs[64][32];
  const int tid = threadIdx.x, w = tid >> 6, lane = tid & 63;
  const int w0 = blockIdx.x * 64, mf0 = blockIdx.y * 64;
  const int rsel = lane >> 2;
  const int csw = (lane & 3) ^ ((lane >> 3) & 3);
  const us16* gAr = Hr + (size_t)(mf0 + 16 * w + rsel) * KH + csw * 8;
  const us16* gAi = Hi + (size_t)(mf0 + 16 * w + rsel) * KH + csw * 8;
  const us16* gBc = Tci + (size_t)(w0 + 16 * w + rsel) * KH + csw * 8;
  const us16* gBs = Tsi + (size_t)(w0 + 16 * w + rsel) * KH + csw * 8;
  f32x4 acc[4] = {};
  const int fr = lane & 15;
  const int kb = 8 * ((lane >> 4) ^ ((lane >> 1) & 3));
  for (int k0 = 0; k0 < KH; k0 += 32) {
    gload16(gAr + k0, &Ar[16 * w][0]);
    gload16(gAi + k0, &Ai[16 * w][0]);
    gload16(gBc + k0, &Bc[16 * w][0]);
    gload16(gBs + k0, &Bs[16 * w][0]);
    __syncthreads();
    bf16x8 aR = *(const bf16x8*)&Ar[16 * w + fr][kb];
    bf16x8 aI = *(const bf16x8*)&Ai[16 * w + fr][kb];
    uint4 su = *(const uint4*)&aI;
    su.x ^= 0x80008000u; su.y ^= 0x80008000u; su.z ^= 0x80008000u; su.w ^= 0x80008000u;
    bf16x8 aIn = *(const bf16x8*)&su;
#pragma unroll
    for (int t = 0; t < 4; ++t) {
      bf16x8 bC = *(const bf16x8*)&Bc[16 * t + fr][kb];
      bf16x8 bS = *(const bf16x8*)&Bs[16 * t + fr][kb];
      acc[t] = MFMA(aR, bC, acc[t], 0, 0, 0);
      acc[t] = MFMA(aIn, bS, acc[t], 0, 0, 0);
    }
    __syncthreads();
  }
#pragma unroll
  for (int t = 0; t < 4; ++t) {
    int wv = w0 + 16 * t + fr;
#pragma unroll
    for (int j = 0; j < 4; ++j) {
      int mf = mf0 + 16 * w + 4 * (lane >> 4) + j;
      int bcl = mf >> 7, mrow = mf & 127;
      int bb = b0 + (bcl >> 6), cc = bcl & 63;
      out[(((size_t)bb * CH + cc) * HIN + roff + mrow) * WIN + wv] = acc[t][j];
    }
  }
}

// ---------------- host ----------------
extern "C" void kernel_launch(void* const* d_in, const int* in_sizes, int n_in,
                              void* d_out, int out_size, void* d_ws, size_t ws_size,
                              hipStream_t stream) {
  const float* x        = (const float*)d_in[0];
  const float* conv_w   = (const float*)d_in[1];
  const float* conv_b   = (const float*)d_in[2];
  const float* gn_gamma = (const float*)d_in[3];
  const float* gn_beta  = (const float*)d_in[4];
  float* out = (float*)d_out;

  // fixed tables (u16 units)
  const size_t uCbA = 2 * 65536;          // per table
  const size_t uTcb = (size_t)NT * 256;
  const size_t uTci = (size_t)256 * KH;
  const size_t uW   = 128 * 128;
  const size_t fixed_u16 = 2 * uCbA + 2 * uTcb + 2 * uTci + 2 * uW;   // 475136
  // per-batch (u16 units)
  const size_t uXB = (size_t)CH * HIN * WIN;      // 4194304
  const size_t uF  = (size_t)CH * SP;             // 3145728 (each of Frt,Fit)
  const size_t uPQ = (size_t)128 * SP;            // 6291456 (each of P,Q)
  const size_t uY  = (size_t)128 * HWFP;          // 4210688
  const size_t per_u16 = uXB + 2 * uF + 2 * uPQ + uY;   // 27279360

  int nb = 0;
  for (int cand = 4; cand >= 1; cand >>= 1) {
    size_t need = fixed_u16 * 2 + 1152 * 4 + (size_t)cand * per_u16 * 2 + 256;
    if (need <= ws_size) { nb = cand; break; }
  }
  if (nb == 0) {
    k_zero<<<dim3((out_size + TPB - 1) / TPB), dim3(TPB), 0, stream>>>(out, out_size);
    return;
  }

  us16* CbA = (us16*)d_ws;
  us16* SbA = CbA + uCbA;
  us16* Tcb = SbA + uCbA;
  us16* Tsb = Tcb + uTcb;
  us16* Tci = Tsb + uTcb;
  us16* Tsi = Tci + uTci;
  us16* Wpb = Tsi + uTci;
  us16* Wqb = Wpb + uW;
  float* part  = (float*)(Wqb + uW);
  float* stats = part + 1024;
  us16* xb  = (us16*)(stats + 128);
  us16* Frt = xb + (size_t)nb * uXB;
  us16* Fit = Frt + (size_t)nb * uF;
  us16* P   = Fit + (size_t)nb * uF;
  us16* Q   = P + (size_t)nb * uPQ;
  us16* Yb  = Q + (size_t)nb * uPQ;
  us16* Hr  = Frt;                              // alias: F dead after k_mix
  us16* Hi  = Frt + (size_t)nb * CH * 128 * KH;

  k_tables<<<dim3(512), dim3(TPB), 0, stream>>>(CbA, SbA, Tcb, Tsb, Tci, Tsi,
                                                Wpb, Wqb, conv_w);

  for (int b0 = 0; b0 < B_ALL; b0 += nb) {
    k_xcast<<<dim3(nb * 4096), dim3(TPB), 0, stream>>>(
        x + (size_t)b0 * CH * HIN * WIN, xb, nb * 1048576);
    k_dftw_fwd_mfma<<<dim3(nb * 256, 3), dim3(TPB), 0, stream>>>(
        xb, Tcb, Tsb, Frt, Fit);
    k_mix<<<dim3(SPV / 64, 2, nb), dim3(TPB), 0, stream>>>(
        Frt, Fit, Wpb, Wqb, P, Q);
    for (int fu = 0; fu < 2; ++fu) {
      const int hsel = fu ? 127 : 0;
      const int roff = fu ? 128 : 0;
      k_dfth_fwd2<<<dim3(3, 1, nb * 128), dim3(TPB), 0, stream>>>(
          P, Q, CbA, SbA, conv_b, Yb, fu);
      k_gn_part<<<dim3(nb * 128), dim3(TPB), 0, stream>>>(Yb, part);
      k_gn_stats<<<dim3(1), dim3(64), 0, stream>>>(part, stats, nb * 16);
      k_dfth_inv_mfma<<<dim3(3, 1, nb * 64), dim3(TPB), 0, stream>>>(
          Yb, CbA, SbA, stats, gn_gamma, gn_beta, Hr, Hi, hsel);
      k_dftw_inv_mfma<<<dim3(4, nb * 128), dim3(TPB), 0, stream>>>(
          Hr, Hi, Tci, Tsi, out, roff, b0);
    }
  }
}

// Round 7
// 324.549 us; speedup vs baseline: 5.6039x; 1.0424x over previous
//
#include <hip/hip_runtime.h>
#include <math.h>

#define TPB 256

typedef unsigned short us16;
typedef __bf16 bf16x8 __attribute__((ext_vector_type(8)));
typedef float f32x4 __attribute__((ext_vector_type(4)));

static const int B_ALL = 4;
static const int CH   = 64;          // input channels
static const int HIN  = 256, WIN = 256;
static const int HH   = 255;         // cropped height
static const int WF   = 129;         // rfft bins along W
static const int HWF  = HH * WF;     // 32895 (valid GN count per channel)
static const int NT   = 192;         // padded n rows
static const int SP   = NT * 256;    // 49152 padded spatial per channel
static const int SPV  = WF * 256;    // 33024 valid spatial
static const int KH   = 160;         // padded K for inverse W-DFT
static const int YST  = NT * 256;    // Yt channel stride (49152)
#define GN_EPS 1e-5f

__device__ __forceinline__ us16 f2bf(float f) {
  union { float f; unsigned u; } v; v.f = f;
  unsigned r = v.u + 0x7FFFu + ((v.u >> 16) & 1u);
  return (us16)(r >> 16);
}
__device__ __forceinline__ float bf2f(us16 v) {
  union { unsigned u; float f; } t; t.u = ((unsigned)v) << 16; return t.f;
}
__device__ __forceinline__ void gload16(const void* g, void* l) {
  __builtin_amdgcn_global_load_lds(
      (const __attribute__((address_space(1))) unsigned int*)g,
      (__attribute__((address_space(3))) unsigned int*)l, 16, 0, 0);
}
#define MFMA __builtin_amdgcn_mfma_f32_16x16x32_bf16

// ---------------- fallback ----------------
__global__ __launch_bounds__(TPB) void k_zero(float* __restrict__ out, int n) {
  int i = blockIdx.x * TPB + threadIdx.x;
  if (i < n) out[i] = 0.f;
}

// ---------------- cast x f32 -> bf16 ----------------
__global__ __launch_bounds__(TPB) void k_xcast(const float* __restrict__ x,
                                               us16* __restrict__ xb, int n4) {
  int i = blockIdx.x * TPB + threadIdx.x;
  if (i < n4) {
    float4 v = ((const float4*)x)[i];
    ushort4 o;
    o.x = f2bf(v.x); o.y = f2bf(v.y); o.z = f2bf(v.z); o.w = f2bf(v.w);
    ((ushort4*)xb)[i] = o;
  }
}

// ---------------- bf16 tables ----------------
__global__ __launch_bounds__(TPB) void k_tables(
    us16* __restrict__ CbA, us16* __restrict__ SbA,
    us16* __restrict__ Tcb, us16* __restrict__ Tsb,
    us16* __restrict__ Tci, us16* __restrict__ Tsi,
    us16* __restrict__ Wpb, us16* __restrict__ Wqb,
    const float* __restrict__ conv_w) {
  int i = blockIdx.x * TPB + threadIdx.x;
  const double PI2 = 6.283185307179586476925286766559;
  if (i < 2 * 65536) {                      // H-DFT [fu][r][k], k-shift absorbed
    int fu = i >> 16, r = (i >> 8) & 255, k = i & 255;
    float cv = 0.f, sv = 0.f;
    int kk = k - fu;
    if (r < 255 && kk >= 0 && kk < 255) {
      double ang = PI2 * (double)((r * kk) % 255) / 255.0;
      cv = (float)cos(ang); sv = (float)sin(ang);
    }
    CbA[i] = f2bf(cv); SbA[i] = f2bf(sv);
  }
  if (i < NT * 256) {                       // W-DFT fwd transposed [n][w]
    int n = i >> 8, w = i & 255;
    float cv = 0.f, sv = 0.f;
    if (n < WF) {
      double ang = PI2 * (double)((n * w) & 255) / 256.0;
      cv = (float)cos(ang); sv = (float)sin(ang);
    }
    Tcb[i] = f2bf(cv); Tsb[i] = f2bf(sv);
  }
  if (i < 256 * KH) {                       // W-DFT inv [w][k], Hermitian coef
    int w = i / KH, k = i - w * KH;
    float cv = 0.f, sv = 0.f;
    if (k < WF) {
      double coef = (k == 0 || k == 128) ? 1.0 : 2.0;
      double ang = PI2 * (double)((k * w) & 255) / 256.0;
      cv = (float)(coef * cos(ang) / 256.0);
      sv = (float)(coef * sin(ang) / 256.0);
    }
    Tci[i] = f2bf(cv); Tsi[i] = f2bf(sv);
  }
  if (i < 128 * 128) {                      // mix weights
    int o = i >> 7, c = i & 127;
    Wpb[i] = f2bf(conv_w[i]);
    float q = (c < 64) ? -conv_w[o * 128 + 64 + c] : conv_w[o * 128 + c - 64];
    Wqb[i] = f2bf(q);
  }
}

// ------- K1: forward W-DFT via MFMA (2-phase dbuf) -> Frt/Fit[bc][n][h] -------
__global__ __launch_bounds__(TPB) void k_dftw_fwd_mfma(
    const us16* __restrict__ xb, const us16* __restrict__ Tcb,
    const us16* __restrict__ Tsb, us16* __restrict__ Frt, us16* __restrict__ Fit) {
  __shared__ __align__(16) us16 Ac[2][64][32];
  __shared__ __align__(16) us16 As[2][64][32];
  __shared__ __align__(16) us16 Bx[2][64][32];
  const int tid = threadIdx.x, w = tid >> 6, lane = tid & 63;
  const int hb = blockIdx.x;
  const int n0 = blockIdx.y * 64;
  const int rsel = lane >> 2;
  const int csw = (lane & 3) ^ ((lane >> 3) & 3);
  const us16* gAc = Tcb + (size_t)(n0 + 16 * w + rsel) * 256 + csw * 8;
  const us16* gAs = Tsb + (size_t)(n0 + 16 * w + rsel) * 256 + csw * 8;
  const us16* gB  = xb + ((size_t)hb * 64 + 16 * w + rsel) * 256 + csw * 8;
  f32x4 accr[4] = {}, acci[4] = {};
  const int fr = lane & 15;
  const int kb = 8 * ((lane >> 4) ^ ((lane >> 1) & 3));
#define STAGE_K1(pp, k0) do { \
    gload16(gAc + (k0), &Ac[pp][16 * w][0]); \
    gload16(gAs + (k0), &As[pp][16 * w][0]); \
    gload16(gB + (k0), &Bx[pp][16 * w][0]); } while (0)
  STAGE_K1(0, 0);
  __syncthreads();
  int pp = 0;
  for (int k0 = 0; k0 < 256; k0 += 32) {
    if (k0 + 32 < 256) STAGE_K1(pp ^ 1, k0 + 32);
    bf16x8 aC = *(const bf16x8*)&Ac[pp][16 * w + fr][kb];
    bf16x8 aS = *(const bf16x8*)&As[pp][16 * w + fr][kb];
    uint4 su = *(const uint4*)&aS;
    su.x ^= 0x80008000u; su.y ^= 0x80008000u; su.z ^= 0x80008000u; su.w ^= 0x80008000u;
    bf16x8 aSn = *(const bf16x8*)&su;
#pragma unroll
    for (int t = 0; t < 4; ++t) {
      bf16x8 b = *(const bf16x8*)&Bx[pp][16 * t + fr][kb];
      accr[t] = MFMA(aC, b, accr[t], 0, 0, 0);
      acci[t] = MFMA(aSn, b, acci[t], 0, 0, 0);
    }
    __syncthreads();
    pp ^= 1;
  }
  const int bc = hb >> 2, hl = (hb & 3) * 64;
#pragma unroll
  for (int t = 0; t < 4; ++t) {
    int h = hl + 16 * t + fr;
#pragma unroll
    for (int j = 0; j < 4; ++j) {
      int n = n0 + 16 * w + 4 * (lane >> 4) + j;
      if (n < WF) {
        size_t idx = ((size_t)bc * NT + n) * 256 + h;
        Frt[idx] = f2bf(accr[t][j]);
        Fit[idx] = f2bf(acci[t][j]);
      }
    }
  }
}

// ------- K2: channel-mix P = Wp.[Fr;Fi], Q = Wq.[Fr;Fi] (unchanged; ~BW-bound) -------
__global__ __launch_bounds__(TPB) void k_mix(
    const us16* __restrict__ Frt, const us16* __restrict__ Fit,
    const us16* __restrict__ Wpb, const us16* __restrict__ Wqb,
    us16* __restrict__ P, us16* __restrict__ Q) {
  __shared__ __align__(16) us16 Ap[64][32];
  __shared__ __align__(16) us16 Aq[64][32];
  __shared__ __align__(8)  us16 Bs[64][36];
  const int tid = threadIdx.x, w = tid >> 6, lane = tid & 63;
  const int sp0 = blockIdx.x * 64, o0 = blockIdx.y * 64, b = blockIdx.z;
  const int rsel = lane >> 2;
  const int csw = (lane & 3) ^ ((lane >> 3) & 3);
  const us16* gAp = Wpb + (size_t)(o0 + 16 * w + rsel) * 128 + csw * 8;
  const us16* gAq = Wqb + (size_t)(o0 + 16 * w + rsel) * 128 + csw * 8;
  f32x4 accp[4] = {}, accq[4] = {};
  const int fr = lane & 15;
  const int kbA = 8 * ((lane >> 4) ^ ((lane >> 1) & 3));
  const int kbB = 8 * (lane >> 4);
  for (int c0 = 0; c0 < 128; c0 += 32) {
    gload16(gAp + c0, &Ap[16 * w][0]);
    gload16(gAq + c0, &Aq[16 * w][0]);
    for (int f = tid; f < 1024; f += TPB) {
      int cl = f >> 5, spp = f & 31;
      int c = c0 + cl;
      const us16* src = (c < 64) ? Frt : Fit;
      size_t addr = (size_t)(b * 64 + (c & 63)) * SP + sp0 + 2 * spp;
      unsigned v = *(const unsigned*)(src + addr);
      Bs[2 * spp][cl] = (us16)v;
      Bs[2 * spp + 1][cl] = (us16)(v >> 16);
    }
    __syncthreads();
    bf16x8 aP = *(const bf16x8*)&Ap[16 * w + fr][kbA];
    bf16x8 aQ = *(const bf16x8*)&Aq[16 * w + fr][kbA];
#pragma unroll
    for (int t = 0; t < 4; ++t) {
      uint2 lo = *(const uint2*)&Bs[16 * t + fr][kbB];
      uint2 hi = *(const uint2*)&Bs[16 * t + fr][kbB + 4];
      uint4 qq; qq.x = lo.x; qq.y = lo.y; qq.z = hi.x; qq.w = hi.y;
      bf16x8 bb = *(const bf16x8*)&qq;
      accp[t] = MFMA(aP, bb, accp[t], 0, 0, 0);
      accq[t] = MFMA(aQ, bb, accq[t], 0, 0, 0);
    }
    __syncthreads();
  }
#pragma unroll
  for (int t = 0; t < 4; ++t) {
    int sp = sp0 + 16 * t + fr;
#pragma unroll
    for (int j = 0; j < 4; ++j) {
      int o = o0 + 16 * w + 4 * (lane >> 4) + j;
      size_t idx = (size_t)(b * 128 + o) * SP + sp;
      P[idx] = f2bf(accp[t][j]);
      Q[idx] = f2bf(accq[t][j]);
    }
  }
}

// ------- K3: H-DFT fwd (2-phase dbuf) -> Yt[bz][n=192][m=256] bf16 -------
__global__ __launch_bounds__(TPB) void k_dfth_fwd2(
    const us16* __restrict__ P, const us16* __restrict__ Q,
    const us16* __restrict__ CbA, const us16* __restrict__ SbA,
    const float* __restrict__ bias, us16* __restrict__ Yt, int fu) {
  __shared__ __align__(16) us16 Ac[2][4][64][32];
  __shared__ __align__(16) us16 As[2][4][64][32];
  __shared__ __align__(16) us16 Bp[2][64][32];
  __shared__ __align__(16) us16 Bq[2][64][32];
  const int tid = threadIdx.x, w = tid >> 6, lane = tid & 63;
  const int bz = blockIdx.z;
  const int n0 = blockIdx.x * 64;
  const int rsel = lane >> 2;
  const int csw = (lane & 3) ^ ((lane >> 3) & 3);
  const us16* gAc = CbA + (((size_t)fu * 256 + 16 * w + rsel) << 8) + csw * 8;
  const us16* gAs = SbA + (((size_t)fu * 256 + 16 * w + rsel) << 8) + csw * 8;
  const us16* gBp = P + ((size_t)bz * NT + n0 + 16 * w + rsel) * 256 + csw * 8;
  const us16* gBq = Q + ((size_t)bz * NT + n0 + 16 * w + rsel) * 256 + csw * 8;
  f32x4 acc[4][4] = {};
  const int fr = lane & 15;
  const int kb = 8 * ((lane >> 4) ^ ((lane >> 1) & 3));
#define STAGE_K3(pp, k0) do { \
    _Pragma("unroll") \
    for (int mt = 0; mt < 4; ++mt) { \
      gload16(gAc + (mt << 14) + (k0), &Ac[pp][mt][16 * w][0]); \
      gload16(gAs + (mt << 14) + (k0), &As[pp][mt][16 * w][0]); } \
    gload16(gBp + (k0), &Bp[pp][16 * w][0]); \
    gload16(gBq + (k0), &Bq[pp][16 * w][0]); } while (0)
  STAGE_K3(0, 0);
  __syncthreads();
  int pp = 0;
  for (int k0 = 0; k0 < 256; k0 += 32) {
    if (k0 + 32 < 256) STAGE_K3(pp ^ 1, k0 + 32);
    bf16x8 aC[4], aS[4];
#pragma unroll
    for (int mt = 0; mt < 4; ++mt) {
      aC[mt] = *(const bf16x8*)&Ac[pp][mt][16 * w + fr][kb];
      aS[mt] = *(const bf16x8*)&As[pp][mt][16 * w + fr][kb];
    }
#pragma unroll
    for (int t = 0; t < 4; ++t) {
      bf16x8 bP = *(const bf16x8*)&Bp[pp][16 * t + fr][kb];
      bf16x8 bQ = *(const bf16x8*)&Bq[pp][16 * t + fr][kb];
#pragma unroll
      for (int mt = 0; mt < 4; ++mt) {
        acc[mt][t] = MFMA(aC[mt], bP, acc[mt][t], 0, 0, 0);
        acc[mt][t] = MFMA(aS[mt], bQ, acc[mt][t], 0, 0, 0);
      }
    }
    __syncthreads();
    pp ^= 1;
  }
  const float bo = bias[bz & 127];
  us16* yc = Yt + (size_t)bz * YST;
  const int mb_ = 16 * w + 4 * (lane >> 4);
#pragma unroll
  for (int t = 0; t < 4; ++t) {
    int n = n0 + 16 * t + fr;
#pragma unroll
    for (int mt = 0; mt < 4; ++mt) {
      unsigned lo = (unsigned)f2bf(acc[mt][t][0] + bo) |
                    ((unsigned)f2bf(acc[mt][t][1] + bo) << 16);
      unsigned hi = (unsigned)f2bf(acc[mt][t][2] + bo) |
                    ((unsigned)f2bf(acc[mt][t][3] + bo) << 16);
      uint2 pk; pk.x = lo; pk.y = hi;
      *(uint2*)(yc + (size_t)n * 256 + mt * 64 + mb_) = pk;
    }
  }
}

// ---------------- K4: GroupNorm stats on Yt (valid n<129, m<255) ----------------
__global__ __launch_bounds__(TPB) void k_gn_part(const us16* __restrict__ Yt,
                                                 float* __restrict__ part) {
  const int tid = threadIdx.x;
  const int bz = blockIdx.x;
  const us16* p = Yt + (size_t)bz * YST;
  float s = 0.f, ss = 0.f;
  for (int cch = tid; cch < 129 * 32; cch += TPB) {
    int n = cch >> 5, off = (cch & 31) * 8;
    uint4 v = *(const uint4*)(p + (size_t)n * 256 + off);
    unsigned q[4] = {v.x, v.y, v.z, v.w};
#pragma unroll
    for (int u = 0; u < 4; ++u) {
      float f0 = __uint_as_float(q[u] << 16);
      float f1 = __uint_as_float(q[u] & 0xffff0000u);
      s += f0 + f1; ss += f0 * f0 + f1 * f1;
    }
    if ((cch & 31) == 31) {                 // exclude m == 255 (pad row)
      float f = __uint_as_float(v.w & 0xffff0000u);
      s -= f; ss -= f * f;
    }
  }
  __shared__ float rs[TPB], rq[TPB];
  rs[tid] = s; rq[tid] = ss;
  __syncthreads();
  for (int st = TPB / 2; st > 0; st >>= 1) {
    if (tid < st) { rs[tid] += rs[tid + st]; rq[tid] += rq[tid + st]; }
    __syncthreads();
  }
  if (tid == 0) { part[bz * 2] = rs[0]; part[bz * 2 + 1] = rq[0]; }
}

__global__ void k_gn_stats(const float* __restrict__ part,
                           float* __restrict__ stats, int nbg) {
  int bg = blockIdx.x * blockDim.x + threadIdx.x;
  if (bg < nbg) {
    float s = 0.f, ss = 0.f;
    for (int j = 0; j < 8; ++j) {
      s += part[(bg * 8 + j) * 2];
      ss += part[(bg * 8 + j) * 2 + 1];
    }
    const float inv = 1.f / (8.f * (float)HWF);
    float mean = s * inv;
    float var = ss * inv - mean * mean;
    stats[bg * 2] = mean;
    stats[bg * 2 + 1] = rsqrtf(var + GN_EPS);
  }
}

// ---------------- K5: in-place GN+ReLU on Yt valid rows ----------------
__global__ __launch_bounds__(TPB) void k_gnnorm(us16* __restrict__ Yt,
                                                const float* __restrict__ stats,
                                                const float* __restrict__ gamma,
                                                const float* __restrict__ beta) {
  const int bz = blockIdx.x, b = bz >> 7, o = bz & 127;
  const int g = b * 16 + (o >> 3);
  const float sc = gamma[o] * stats[g * 2 + 1];
  const float sh = beta[o] - stats[g * 2] * sc;
  us16* p = Yt + (size_t)bz * YST;
  for (int cch = threadIdx.x; cch < 129 * 32; cch += TPB) {
    int n = cch >> 5, off = (cch & 31) * 8;
    uint4 v = *(const uint4*)(p + (size_t)n * 256 + off);
    unsigned q[4] = {v.x, v.y, v.z, v.w};
    unsigned r[4];
#pragma unroll
    for (int u = 0; u < 4; ++u) {
      float lo = fmaxf(__uint_as_float(q[u] << 16) * sc + sh, 0.f);
      float hi = fmaxf(__uint_as_float(q[u] & 0xffff0000u) * sc + sh, 0.f);
      r[u] = (unsigned)f2bf(lo) | ((unsigned)f2bf(hi) << 16);
    }
    uint4 o4; o4.x = r[0]; o4.y = r[1]; o4.z = r[2]; o4.w = r[3];
    *(uint4*)(p + (size_t)n * 256 + off) = o4;
  }
}

// ------- K6: inverse H-DFT (pure gload, 2-phase dbuf) -> Hr/Hi bf16 [bc*128+m][160] -------
__global__ __launch_bounds__(TPB) void k_dfth_inv_mfma(
    const us16* __restrict__ Yt, const us16* __restrict__ CbA,
    const us16* __restrict__ SbA, us16* __restrict__ Hr, us16* __restrict__ Hi,
    int hsel) {
  __shared__ __align__(16) us16 Ac[2][2][64][32];
  __shared__ __align__(16) us16 As[2][2][64][32];
  __shared__ __align__(16) us16 Br[2][64][32];
  __shared__ __align__(16) us16 Bi[2][64][32];
  const int tid = threadIdx.x, w = tid >> 6, lane = tid & 63;
  const int bc = blockIdx.z, b = bc >> 6, c = bc & 63;
  const int n0 = blockIdx.x * 64;
  const int rsel = lane >> 2;
  const int csw = (lane & 3) ^ ((lane >> 3) & 3);
  const us16* gAc = CbA + (((size_t)hsel + 16 * w + rsel) << 8) + csw * 8;
  const us16* gAs = SbA + (((size_t)hsel + 16 * w + rsel) << 8) + csw * 8;
  const us16* gBr = Yt + (size_t)(b * 128 + c) * YST +
                    (size_t)(n0 + 16 * w + rsel) * 256 + csw * 8;
  const us16* gBi = Yt + (size_t)(b * 128 + 64 + c) * YST +
                    (size_t)(n0 + 16 * w + rsel) * 256 + csw * 8;
  f32x4 accr[2][4] = {}, acci[2][4] = {};
  const int fr = lane & 15;
  const int kb = 8 * ((lane >> 4) ^ ((lane >> 1) & 3));
#define STAGE_K6(pp, k0) do { \
    gload16(gAc + (k0), &Ac[pp][0][16 * w][0]); \
    gload16(gAc + (1 << 14) + (k0), &Ac[pp][1][16 * w][0]); \
    gload16(gAs + (k0), &As[pp][0][16 * w][0]); \
    gload16(gAs + (1 << 14) + (k0), &As[pp][1][16 * w][0]); \
    gload16(gBr + (k0), &Br[pp][16 * w][0]); \
    gload16(gBi + (k0), &Bi[pp][16 * w][0]); } while (0)
  STAGE_K6(0, 0);
  __syncthreads();
  int pp = 0;
  for (int k0 = 0; k0 < 256; k0 += 32) {
    if (k0 + 32 < 256) STAGE_K6(pp ^ 1, k0 + 32);
    bf16x8 aC[2], aS[2], aSn[2];
#pragma unroll
    for (int mt = 0; mt < 2; ++mt) {
      aC[mt] = *(const bf16x8*)&Ac[pp][mt][16 * w + fr][kb];
      aS[mt] = *(const bf16x8*)&As[pp][mt][16 * w + fr][kb];
      uint4 su = *(const uint4*)&aS[mt];
      su.x ^= 0x80008000u; su.y ^= 0x80008000u; su.z ^= 0x80008000u; su.w ^= 0x80008000u;
      aSn[mt] = *(const bf16x8*)&su;
    }
#pragma unroll
    for (int t = 0; t < 4; ++t) {
      bf16x8 bR = *(const bf16x8*)&Br[pp][16 * t + fr][kb];
      bf16x8 bI = *(const bf16x8*)&Bi[pp][16 * t + fr][kb];
#pragma unroll
      for (int mt = 0; mt < 2; ++mt) {
        accr[mt][t] = MFMA(aC[mt], bR, accr[mt][t], 0, 0, 0);
        accr[mt][t] = MFMA(aSn[mt], bI, accr[mt][t], 0, 0, 0);
        acci[mt][t] = MFMA(aC[mt], bI, acci[mt][t], 0, 0, 0);
        acci[mt][t] = MFMA(aS[mt], bR, acci[mt][t], 0, 0, 0);
      }
    }
    __syncthreads();
    pp ^= 1;
  }
  const float inv = 1.f / 255.f;
#pragma unroll
  for (int t = 0; t < 4; ++t) {
    int n = n0 + 16 * t + fr;
    if (n < KH) {
#pragma unroll
      for (int mt = 0; mt < 2; ++mt) {
#pragma unroll
        for (int j = 0; j < 4; ++j) {
          int m = mt * 64 + 16 * w + 4 * (lane >> 4) + j;
          size_t idx = ((size_t)bc * 128 + m) * KH + n;
          Hr[idx] = (n < WF) ? f2bf(accr[mt][t][j] * inv) : (us16)0;
          Hi[idx] = (n < WF) ? f2bf(acci[mt][t][j] * inv) : (us16)0;
        }
      }
    }
  }
}

// ------- K7: inverse W-DFT (2-phase dbuf, K=160) -> scatter into d_out -------
__global__ __launch_bounds__(TPB) void k_dftw_inv_mfma(
    const us16* __restrict__ Hr, const us16* __restrict__ Hi,
    const us16* __restrict__ Tci, const us16* __restrict__ Tsi,
    float* __restrict__ out, int roff, int b0) {
  __shared__ __align__(16) us16 Ar[2][64][32];
  __shared__ __align__(16) us16 Ai[2][64][32];
  __shared__ __align__(16) us16 Bc[2][64][32];
  __shared__ __align__(16) us16 Bs[2][64][32];
  const int tid = threadIdx.x, w = tid >> 6, lane = tid & 63;
  const int w0 = blockIdx.x * 64, mf0 = blockIdx.y * 64;
  const int rsel = lane >> 2;
  const int csw = (lane & 3) ^ ((lane >> 3) & 3);
  const us16* gAr = Hr + (size_t)(mf0 + 16 * w + rsel) * KH + csw * 8;
  const us16* gAi = Hi + (size_t)(mf0 + 16 * w + rsel) * KH + csw * 8;
  const us16* gBc = Tci + (size_t)(w0 + 16 * w + rsel) * KH + csw * 8;
  const us16* gBs = Tsi + (size_t)(w0 + 16 * w + rsel) * KH + csw * 8;
  f32x4 acc[4] = {};
  const int fr = lane & 15;
  const int kb = 8 * ((lane >> 4) ^ ((lane >> 1) & 3));
#define STAGE_K7(pp, k0) do { \
    gload16(gAr + (k0), &Ar[pp][16 * w][0]); \
    gload16(gAi + (k0), &Ai[pp][16 * w][0]); \
    gload16(gBc + (k0), &Bc[pp][16 * w][0]); \
    gload16(gBs + (k0), &Bs[pp][16 * w][0]); } while (0)
  STAGE_K7(0, 0);
  __syncthreads();
  int pp = 0;
  for (int k0 = 0; k0 < KH; k0 += 32) {
    if (k0 + 32 < KH) STAGE_K7(pp ^ 1, k0 + 32);
    bf16x8 aR = *(const bf16x8*)&Ar[pp][16 * w + fr][kb];
    bf16x8 aI = *(const bf16x8*)&Ai[pp][16 * w + fr][kb];
    uint4 su = *(const uint4*)&aI;
    su.x ^= 0x80008000u; su.y ^= 0x80008000u; su.z ^= 0x80008000u; su.w ^= 0x80008000u;
    bf16x8 aIn = *(const bf16x8*)&su;
#pragma unroll
    for (int t = 0; t < 4; ++t) {
      bf16x8 bC = *(const bf16x8*)&Bc[pp][16 * t + fr][kb];
      bf16x8 bS = *(const bf16x8*)&Bs[pp][16 * t + fr][kb];
      acc[t] = MFMA(aR, bC, acc[t], 0, 0, 0);
      acc[t] = MFMA(aIn, bS, acc[t], 0, 0, 0);
    }
    __syncthreads();
    pp ^= 1;
  }
#pragma unroll
  for (int t = 0; t < 4; ++t) {
    int wv = w0 + 16 * t + fr;
#pragma unroll
    for (int j = 0; j < 4; ++j) {
      int mf = mf0 + 16 * w + 4 * (lane >> 4) + j;
      int bcl = mf >> 7, mrow = mf & 127;
      int bb = b0 + (bcl >> 6), cc = bcl & 63;
      out[(((size_t)bb * CH + cc) * HIN + roff + mrow) * WIN + wv] = acc[t][j];
    }
  }
}

// ---------------- host ----------------
extern "C" void kernel_launch(void* const* d_in, const int* in_sizes, int n_in,
                              void* d_out, int out_size, void* d_ws, size_t ws_size,
                              hipStream_t stream) {
  const float* x        = (const float*)d_in[0];
  const float* conv_w   = (const float*)d_in[1];
  const float* conv_b   = (const float*)d_in[2];
  const float* gn_gamma = (const float*)d_in[3];
  const float* gn_beta  = (const float*)d_in[4];
  float* out = (float*)d_out;

  // u16 units
  const size_t uCbA = 2 * 65536;
  const size_t uTcb = (size_t)NT * 256;
  const size_t uTci = (size_t)256 * KH;
  const size_t uW   = 128 * 128;
  const size_t fixed_u16 = 2 * uCbA + 2 * uTcb + 2 * uTci + 2 * uW;
  const size_t uXB = (size_t)CH * HIN * WIN;      // 4194304
  const size_t uF  = (size_t)CH * SP;             // 3145728
  const size_t uPQ = (size_t)128 * SP;            // 6291456
  // Yt (nb*128*YST = nb*6291456) aliases xb+Frt (nb*7340032) -> no extra alloc
  const size_t per_u16 = uXB + 2 * uF + 2 * uPQ;  // 23068672

  int nb = 0;
  for (int cand = 4; cand >= 1; cand >>= 1) {
    size_t need = fixed_u16 * 2 + 1152 * 4 + (size_t)cand * per_u16 * 2 + 256;
    if (need <= ws_size) { nb = cand; break; }
  }
  if (nb == 0) {
    k_zero<<<dim3((out_size + TPB - 1) / TPB), dim3(TPB), 0, stream>>>(out, out_size);
    return;
  }

  us16* CbA = (us16*)d_ws;
  us16* SbA = CbA + uCbA;
  us16* Tcb = SbA + uCbA;
  us16* Tsb = Tcb + uTcb;
  us16* Tci = Tsb + uTcb;
  us16* Tsi = Tci + uTci;
  us16* Wpb = Tsi + uTci;
  us16* Wqb = Wpb + uW;
  float* part  = (float*)(Wqb + uW);
  float* stats = part + 1024;
  us16* xb  = (us16*)(stats + 128);
  us16* Frt = xb + (size_t)nb * uXB;
  us16* Fit = Frt + (size_t)nb * uF;
  us16* P   = Fit + (size_t)nb * uF;
  us16* Q   = P + (size_t)nb * uPQ;
  us16* Yt  = xb;                               // alias: xb+Frt dead after k_mix
  us16* Hr  = Fit;                              // alias: Fit dead after k_mix
  us16* Hi  = Fit + (size_t)nb * CH * 128 * KH; // nb*1310720 (x2 <= nb*uF)

  k_tables<<<dim3(512), dim3(TPB), 0, stream>>>(CbA, SbA, Tcb, Tsb, Tci, Tsi,
                                                Wpb, Wqb, conv_w);

  for (int b0 = 0; b0 < B_ALL; b0 += nb) {
    k_xcast<<<dim3(nb * 4096), dim3(TPB), 0, stream>>>(
        x + (size_t)b0 * CH * HIN * WIN, xb, nb * 1048576);
    k_dftw_fwd_mfma<<<dim3(nb * 256, 3), dim3(TPB), 0, stream>>>(
        xb, Tcb, Tsb, Frt, Fit);
    k_mix<<<dim3(SPV / 64, 2, nb), dim3(TPB), 0, stream>>>(
        Frt, Fit, Wpb, Wqb, P, Q);
    for (int fu = 0; fu < 2; ++fu) {
      const int hsel = fu ? 127 : 0;
      const int roff = fu ? 128 : 0;
      k_dfth_fwd2<<<dim3(3, 1, nb * 128), dim3(TPB), 0, stream>>>(
          P, Q, CbA, SbA, conv_b, Yt, fu);
      k_gn_part<<<dim3(nb * 128), dim3(TPB), 0, stream>>>(Yt, part);
      k_gn_stats<<<dim3(1), dim3(64), 0, stream>>>(part, stats, nb * 16);
      k_gnnorm<<<dim3(nb * 128), dim3(TPB), 0, stream>>>(Yt, stats, gn_gamma, gn_beta);
      k_dfth_inv_mfma<<<dim3(3, 1, nb * 64), dim3(TPB), 0, stream>>>(
          Yt, CbA, SbA, Hr, Hi, hsel);
      k_dftw_inv_mfma<<<dim3(4, nb * 128), dim3(TPB), 0, stream>>>(
          Hr, Hi, Tci, Tsi, out, roff, b0);
    }
  }
}

// Round 8
// 320.295 us; speedup vs baseline: 5.6783x; 1.0133x over previous
//
#include <hip/hip_runtime.h>
#include <math.h>

#define TPB 256

typedef unsigned short us16;
typedef __bf16 bf16x8 __attribute__((ext_vector_type(8)));
typedef float f32x4 __attribute__((ext_vector_type(4)));

static const int B_ALL = 4;
static const int CH   = 64;          // input channels
static const int HIN  = 256, WIN = 256;
static const int HH   = 255;         // cropped height
static const int WF   = 129;         // rfft bins along W
static const int HWF  = HH * WF;     // 32895 (valid GN count per channel)
static const int NT   = 192;         // padded n rows
static const int SP   = NT * 256;    // 49152 padded spatial per channel
static const int SPV  = WF * 256;    // 33024 valid spatial
static const int KH   = 160;         // padded K for inverse W-DFT
static const int YST  = NT * 256;    // Yt channel stride (49152)
#define GN_EPS 1e-5f

__device__ __forceinline__ us16 f2bf(float f) {
  union { float f; unsigned u; } v; v.f = f;
  unsigned r = v.u + 0x7FFFu + ((v.u >> 16) & 1u);
  return (us16)(r >> 16);
}
__device__ __forceinline__ float bf2f(us16 v) {
  union { unsigned u; float f; } t; t.u = ((unsigned)v) << 16; return t.f;
}
__device__ __forceinline__ void gload16(const void* g, void* l) {
  __builtin_amdgcn_global_load_lds(
      (const __attribute__((address_space(1))) unsigned int*)g,
      (__attribute__((address_space(3))) unsigned int*)l, 16, 0, 0);
}
#define MFMA __builtin_amdgcn_mfma_f32_16x16x32_bf16

// counted vmcnt wait (T4): keep N newest loads in flight, wait for all older.
#define WAITVM(N) asm volatile("s_waitcnt vmcnt(" #N ")" ::: "memory")
// consume-side fence: all waves' stages visible; block compiler motion.
#define BAR_ACQ() do { \
    __builtin_amdgcn_s_barrier(); \
    asm volatile("" ::: "memory"); \
    __builtin_amdgcn_sched_barrier(0); } while (0)
// release-side fence: all reads of this buffer done before restage.
#define BAR_REL() do { \
    asm volatile("" ::: "memory"); \
    __builtin_amdgcn_s_barrier(); } while (0)

// ---------------- fallback ----------------
__global__ __launch_bounds__(TPB) void k_zero(float* __restrict__ out, int n) {
  int i = blockIdx.x * TPB + threadIdx.x;
  if (i < n) out[i] = 0.f;
}

// ---------------- cast x f32 -> bf16 ----------------
__global__ __launch_bounds__(TPB) void k_xcast(const float* __restrict__ x,
                                               us16* __restrict__ xb, int n4) {
  int i = blockIdx.x * TPB + threadIdx.x;
  if (i < n4) {
    float4 v = ((const float4*)x)[i];
    ushort4 o;
    o.x = f2bf(v.x); o.y = f2bf(v.y); o.z = f2bf(v.z); o.w = f2bf(v.w);
    ((ushort4*)xb)[i] = o;
  }
}

// ---------------- bf16 tables ----------------
__global__ __launch_bounds__(TPB) void k_tables(
    us16* __restrict__ CbA, us16* __restrict__ SbA,
    us16* __restrict__ Tcb, us16* __restrict__ Tsb,
    us16* __restrict__ Tci, us16* __restrict__ Tsi,
    us16* __restrict__ Wpb, us16* __restrict__ Wqb,
    const float* __restrict__ conv_w) {
  int i = blockIdx.x * TPB + threadIdx.x;
  const double PI2 = 6.283185307179586476925286766559;
  if (i < 2 * 65536) {                      // H-DFT [fu][r][k], k-shift absorbed
    int fu = i >> 16, r = (i >> 8) & 255, k = i & 255;
    float cv = 0.f, sv = 0.f;
    int kk = k - fu;
    if (r < 255 && kk >= 0 && kk < 255) {
      double ang = PI2 * (double)((r * kk) % 255) / 255.0;
      cv = (float)cos(ang); sv = (float)sin(ang);
    }
    CbA[i] = f2bf(cv); SbA[i] = f2bf(sv);
  }
  if (i < NT * 256) {                       // W-DFT fwd transposed [n][w]
    int n = i >> 8, w = i & 255;
    float cv = 0.f, sv = 0.f;
    if (n < WF) {
      double ang = PI2 * (double)((n * w) & 255) / 256.0;
      cv = (float)cos(ang); sv = (float)sin(ang);
    }
    Tcb[i] = f2bf(cv); Tsb[i] = f2bf(sv);
  }
  if (i < 256 * KH) {                       // W-DFT inv [w][k], Hermitian coef
    int w = i / KH, k = i - w * KH;
    float cv = 0.f, sv = 0.f;
    if (k < WF) {
      double coef = (k == 0 || k == 128) ? 1.0 : 2.0;
      double ang = PI2 * (double)((k * w) & 255) / 256.0;
      cv = (float)(coef * cos(ang) / 256.0);
      sv = (float)(coef * sin(ang) / 256.0);
    }
    Tci[i] = f2bf(cv); Tsi[i] = f2bf(sv);
  }
  if (i < 128 * 128) {                      // mix weights
    int o = i >> 7, c = i & 127;
    Wpb[i] = f2bf(conv_w[i]);
    float q = (c < 64) ? -conv_w[o * 128 + 64 + c] : conv_w[o * 128 + c - 64];
    Wqb[i] = f2bf(q);
  }
}

// ------- K1: forward W-DFT via MFMA (counted-vmcnt dbuf) -> Frt/Fit[bc][n][h] -------
__global__ __launch_bounds__(TPB) void k_dftw_fwd_mfma(
    const us16* __restrict__ xb, const us16* __restrict__ Tcb,
    const us16* __restrict__ Tsb, us16* __restrict__ Frt, us16* __restrict__ Fit) {
  __shared__ __align__(16) us16 Ac[2][64][32];
  __shared__ __align__(16) us16 As[2][64][32];
  __shared__ __align__(16) us16 Bx[2][64][32];
  const int tid = threadIdx.x, w = tid >> 6, lane = tid & 63;
  const int hb = blockIdx.x;
  const int n0 = blockIdx.y * 64;
  const int rsel = lane >> 2;
  const int csw = (lane & 3) ^ ((lane >> 3) & 3);
  const us16* gAc = Tcb + (size_t)(n0 + 16 * w + rsel) * 256 + csw * 8;
  const us16* gAs = Tsb + (size_t)(n0 + 16 * w + rsel) * 256 + csw * 8;
  const us16* gB  = xb + ((size_t)hb * 64 + 16 * w + rsel) * 256 + csw * 8;
  f32x4 accr[4] = {}, acci[4] = {};
  const int fr = lane & 15;
  const int kb = 8 * ((lane >> 4) ^ ((lane >> 1) & 3));
#define STAGE_K1(pp, k0) do { \
    gload16(gAc + (k0), &Ac[pp][16 * w][0]); \
    gload16(gAs + (k0), &As[pp][16 * w][0]); \
    gload16(gB + (k0), &Bx[pp][16 * w][0]); } while (0)
  STAGE_K1(0, 0);
  int pp = 0;
  for (int k0 = 0; k0 < 256; k0 += 32) {
    if (k0 + 32 < 256) { STAGE_K1(pp ^ 1, k0 + 32); WAITVM(3); }
    else WAITVM(0);
    BAR_ACQ();
    bf16x8 aC = *(const bf16x8*)&Ac[pp][16 * w + fr][kb];
    bf16x8 aS = *(const bf16x8*)&As[pp][16 * w + fr][kb];
    uint4 su = *(const uint4*)&aS;
    su.x ^= 0x80008000u; su.y ^= 0x80008000u; su.z ^= 0x80008000u; su.w ^= 0x80008000u;
    bf16x8 aSn = *(const bf16x8*)&su;
#pragma unroll
    for (int t = 0; t < 4; ++t) {
      bf16x8 b = *(const bf16x8*)&Bx[pp][16 * t + fr][kb];
      accr[t] = MFMA(aC, b, accr[t], 0, 0, 0);
      acci[t] = MFMA(aSn, b, acci[t], 0, 0, 0);
    }
    BAR_REL();
    pp ^= 1;
  }
  const int bc = hb >> 2, hl = (hb & 3) * 64;
#pragma unroll
  for (int t = 0; t < 4; ++t) {
    int h = hl + 16 * t + fr;
#pragma unroll
    for (int j = 0; j < 4; ++j) {
      int n = n0 + 16 * w + 4 * (lane >> 4) + j;
      if (n < WF) {
        size_t idx = ((size_t)bc * NT + n) * 256 + h;
        Frt[idx] = f2bf(accr[t][j]);
        Fit[idx] = f2bf(acci[t][j]);
      }
    }
  }
}

// ------- K2: channel-mix P = Wp.[Fr;Fi], Q = Wq.[Fr;Fi] (safe __syncthreads) -------
__global__ __launch_bounds__(TPB) void k_mix(
    const us16* __restrict__ Frt, const us16* __restrict__ Fit,
    const us16* __restrict__ Wpb, const us16* __restrict__ Wqb,
    us16* __restrict__ P, us16* __restrict__ Q) {
  __shared__ __align__(16) us16 Ap[64][32];
  __shared__ __align__(16) us16 Aq[64][32];
  __shared__ __align__(8)  us16 Bs[64][36];
  const int tid = threadIdx.x, w = tid >> 6, lane = tid & 63;
  const int sp0 = blockIdx.x * 64, o0 = blockIdx.y * 64, b = blockIdx.z;
  const int rsel = lane >> 2;
  const int csw = (lane & 3) ^ ((lane >> 3) & 3);
  const us16* gAp = Wpb + (size_t)(o0 + 16 * w + rsel) * 128 + csw * 8;
  const us16* gAq = Wqb + (size_t)(o0 + 16 * w + rsel) * 128 + csw * 8;
  f32x4 accp[4] = {}, accq[4] = {};
  const int fr = lane & 15;
  const int kbA = 8 * ((lane >> 4) ^ ((lane >> 1) & 3));
  const int kbB = 8 * (lane >> 4);
  for (int c0 = 0; c0 < 128; c0 += 32) {
    gload16(gAp + c0, &Ap[16 * w][0]);
    gload16(gAq + c0, &Aq[16 * w][0]);
    for (int f = tid; f < 1024; f += TPB) {
      int cl = f >> 5, spp = f & 31;
      int c = c0 + cl;
      const us16* src = (c < 64) ? Frt : Fit;
      size_t addr = (size_t)(b * 64 + (c & 63)) * SP + sp0 + 2 * spp;
      unsigned v = *(const unsigned*)(src + addr);
      Bs[2 * spp][cl] = (us16)v;
      Bs[2 * spp + 1][cl] = (us16)(v >> 16);
    }
    __syncthreads();
    bf16x8 aP = *(const bf16x8*)&Ap[16 * w + fr][kbA];
    bf16x8 aQ = *(const bf16x8*)&Aq[16 * w + fr][kbA];
#pragma unroll
    for (int t = 0; t < 4; ++t) {
      uint2 lo = *(const uint2*)&Bs[16 * t + fr][kbB];
      uint2 hi = *(const uint2*)&Bs[16 * t + fr][kbB + 4];
      uint4 qq; qq.x = lo.x; qq.y = lo.y; qq.z = hi.x; qq.w = hi.y;
      bf16x8 bb = *(const bf16x8*)&qq;
      accp[t] = MFMA(aP, bb, accp[t], 0, 0, 0);
      accq[t] = MFMA(aQ, bb, accq[t], 0, 0, 0);
    }
    __syncthreads();
  }
#pragma unroll
  for (int t = 0; t < 4; ++t) {
    int sp = sp0 + 16 * t + fr;
#pragma unroll
    for (int j = 0; j < 4; ++j) {
      int o = o0 + 16 * w + 4 * (lane >> 4) + j;
      size_t idx = (size_t)(b * 128 + o) * SP + sp;
      P[idx] = f2bf(accp[t][j]);
      Q[idx] = f2bf(accq[t][j]);
    }
  }
}

// ------- K3: H-DFT fwd (counted-vmcnt dbuf) -> Yt[bz][n=192][m=256] bf16 -------
__global__ __launch_bounds__(TPB) void k_dfth_fwd2(
    const us16* __restrict__ P, const us16* __restrict__ Q,
    const us16* __restrict__ CbA, const us16* __restrict__ SbA,
    const float* __restrict__ bias, us16* __restrict__ Yt, int fu) {
  __shared__ __align__(16) us16 Ac[2][4][64][32];
  __shared__ __align__(16) us16 As[2][4][64][32];
  __shared__ __align__(16) us16 Bp[2][64][32];
  __shared__ __align__(16) us16 Bq[2][64][32];
  const int tid = threadIdx.x, w = tid >> 6, lane = tid & 63;
  const int bz = blockIdx.z;
  const int n0 = blockIdx.x * 64;
  const int rsel = lane >> 2;
  const int csw = (lane & 3) ^ ((lane >> 3) & 3);
  const us16* gAc = CbA + (((size_t)fu * 256 + 16 * w + rsel) << 8) + csw * 8;
  const us16* gAs = SbA + (((size_t)fu * 256 + 16 * w + rsel) << 8) + csw * 8;
  const us16* gBp = P + ((size_t)bz * NT + n0 + 16 * w + rsel) * 256 + csw * 8;
  const us16* gBq = Q + ((size_t)bz * NT + n0 + 16 * w + rsel) * 256 + csw * 8;
  f32x4 acc[4][4] = {};
  const int fr = lane & 15;
  const int kb = 8 * ((lane >> 4) ^ ((lane >> 1) & 3));
#define STAGE_K3(pp, k0) do { \
    _Pragma("unroll") \
    for (int mt = 0; mt < 4; ++mt) { \
      gload16(gAc + (mt << 14) + (k0), &Ac[pp][mt][16 * w][0]); \
      gload16(gAs + (mt << 14) + (k0), &As[pp][mt][16 * w][0]); } \
    gload16(gBp + (k0), &Bp[pp][16 * w][0]); \
    gload16(gBq + (k0), &Bq[pp][16 * w][0]); } while (0)
  STAGE_K3(0, 0);
  int pp = 0;
  for (int k0 = 0; k0 < 256; k0 += 32) {
    if (k0 + 32 < 256) { STAGE_K3(pp ^ 1, k0 + 32); WAITVM(10); }
    else WAITVM(0);
    BAR_ACQ();
    bf16x8 aC[4], aS[4];
#pragma unroll
    for (int mt = 0; mt < 4; ++mt) {
      aC[mt] = *(const bf16x8*)&Ac[pp][mt][16 * w + fr][kb];
      aS[mt] = *(const bf16x8*)&As[pp][mt][16 * w + fr][kb];
    }
#pragma unroll
    for (int t = 0; t < 4; ++t) {
      bf16x8 bP = *(const bf16x8*)&Bp[pp][16 * t + fr][kb];
      bf16x8 bQ = *(const bf16x8*)&Bq[pp][16 * t + fr][kb];
#pragma unroll
      for (int mt = 0; mt < 4; ++mt) {
        acc[mt][t] = MFMA(aC[mt], bP, acc[mt][t], 0, 0, 0);
        acc[mt][t] = MFMA(aS[mt], bQ, acc[mt][t], 0, 0, 0);
      }
    }
    BAR_REL();
    pp ^= 1;
  }
  const float bo = bias[bz & 127];
  us16* yc = Yt + (size_t)bz * YST;
  const int mb_ = 16 * w + 4 * (lane >> 4);
#pragma unroll
  for (int t = 0; t < 4; ++t) {
    int n = n0 + 16 * t + fr;
#pragma unroll
    for (int mt = 0; mt < 4; ++mt) {
      unsigned lo = (unsigned)f2bf(acc[mt][t][0] + bo) |
                    ((unsigned)f2bf(acc[mt][t][1] + bo) << 16);
      unsigned hi = (unsigned)f2bf(acc[mt][t][2] + bo) |
                    ((unsigned)f2bf(acc[mt][t][3] + bo) << 16);
      uint2 pk; pk.x = lo; pk.y = hi;
      *(uint2*)(yc + (size_t)n * 256 + mt * 64 + mb_) = pk;
    }
  }
}

// ---------------- K4: GroupNorm stats on Yt (valid n<129, m<255) ----------------
__global__ __launch_bounds__(TPB) void k_gn_part(const us16* __restrict__ Yt,
                                                 float* __restrict__ part) {
  const int tid = threadIdx.x;
  const int bz = blockIdx.x;
  const us16* p = Yt + (size_t)bz * YST;
  float s = 0.f, ss = 0.f;
  for (int cch = tid; cch < 129 * 32; cch += TPB) {
    int n = cch >> 5, off = (cch & 31) * 8;
    uint4 v = *(const uint4*)(p + (size_t)n * 256 + off);
    unsigned q[4] = {v.x, v.y, v.z, v.w};
#pragma unroll
    for (int u = 0; u < 4; ++u) {
      float f0 = __uint_as_float(q[u] << 16);
      float f1 = __uint_as_float(q[u] & 0xffff0000u);
      s += f0 + f1; ss += f0 * f0 + f1 * f1;
    }
    if ((cch & 31) == 31) {                 // exclude m == 255 (pad row)
      float f = __uint_as_float(v.w & 0xffff0000u);
      s -= f; ss -= f * f;
    }
  }
  __shared__ float rs[TPB], rq[TPB];
  rs[tid] = s; rq[tid] = ss;
  __syncthreads();
  for (int st = TPB / 2; st > 0; st >>= 1) {
    if (tid < st) { rs[tid] += rs[tid + st]; rq[tid] += rq[tid + st]; }
    __syncthreads();
  }
  if (tid == 0) { part[bz * 2] = rs[0]; part[bz * 2 + 1] = rq[0]; }
}

__global__ void k_gn_stats(const float* __restrict__ part,
                           float* __restrict__ stats, int nbg) {
  int bg = blockIdx.x * blockDim.x + threadIdx.x;
  if (bg < nbg) {
    float s = 0.f, ss = 0.f;
    for (int j = 0; j < 8; ++j) {
      s += part[(bg * 8 + j) * 2];
      ss += part[(bg * 8 + j) * 2 + 1];
    }
    const float inv = 1.f / (8.f * (float)HWF);
    float mean = s * inv;
    float var = ss * inv - mean * mean;
    stats[bg * 2] = mean;
    stats[bg * 2 + 1] = rsqrtf(var + GN_EPS);
  }
}

// ---------------- K5: in-place GN+ReLU on Yt valid rows ----------------
__global__ __launch_bounds__(TPB) void k_gnnorm(us16* __restrict__ Yt,
                                                const float* __restrict__ stats,
                                                const float* __restrict__ gamma,
                                                const float* __restrict__ beta) {
  const int bz = blockIdx.x, b = bz >> 7, o = bz & 127;
  const int g = b * 16 + (o >> 3);
  const float sc = gamma[o] * stats[g * 2 + 1];
  const float sh = beta[o] - stats[g * 2] * sc;
  us16* p = Yt + (size_t)bz * YST;
  for (int cch = threadIdx.x; cch < 129 * 32; cch += TPB) {
    int n = cch >> 5, off = (cch & 31) * 8;
    uint4 v = *(const uint4*)(p + (size_t)n * 256 + off);
    unsigned q[4] = {v.x, v.y, v.z, v.w};
    unsigned r[4];
#pragma unroll
    for (int u = 0; u < 4; ++u) {
      float lo = fmaxf(__uint_as_float(q[u] << 16) * sc + sh, 0.f);
      float hi = fmaxf(__uint_as_float(q[u] & 0xffff0000u) * sc + sh, 0.f);
      r[u] = (unsigned)f2bf(lo) | ((unsigned)f2bf(hi) << 16);
    }
    uint4 o4; o4.x = r[0]; o4.y = r[1]; o4.z = r[2]; o4.w = r[3];
    *(uint4*)(p + (size_t)n * 256 + off) = o4;
  }
}

// ------- K6: inverse H-DFT (counted-vmcnt dbuf) -> Hr/Hi bf16 [bc*128+m][160] -------
__global__ __launch_bounds__(TPB) void k_dfth_inv_mfma(
    const us16* __restrict__ Yt, const us16* __restrict__ CbA,
    const us16* __restrict__ SbA, us16* __restrict__ Hr, us16* __restrict__ Hi,
    int hsel) {
  __shared__ __align__(16) us16 Ac[2][2][64][32];
  __shared__ __align__(16) us16 As[2][2][64][32];
  __shared__ __align__(16) us16 Br[2][64][32];
  __shared__ __align__(16) us16 Bi[2][64][32];
  const int tid = threadIdx.x, w = tid >> 6, lane = tid & 63;
  const int bc = blockIdx.z, b = bc >> 6, c = bc & 63;
  const int n0 = blockIdx.x * 64;
  const int rsel = lane >> 2;
  const int csw = (lane & 3) ^ ((lane >> 3) & 3);
  const us16* gAc = CbA + (((size_t)hsel + 16 * w + rsel) << 8) + csw * 8;
  const us16* gAs = SbA + (((size_t)hsel + 16 * w + rsel) << 8) + csw * 8;
  const us16* gBr = Yt + (size_t)(b * 128 + c) * YST +
                    (size_t)(n0 + 16 * w + rsel) * 256 + csw * 8;
  const us16* gBi = Yt + (size_t)(b * 128 + 64 + c) * YST +
                    (size_t)(n0 + 16 * w + rsel) * 256 + csw * 8;
  f32x4 accr[2][4] = {}, acci[2][4] = {};
  const int fr = lane & 15;
  const int kb = 8 * ((lane >> 4) ^ ((lane >> 1) & 3));
#define STAGE_K6(pp, k0) do { \
    gload16(gAc + (k0), &Ac[pp][0][16 * w][0]); \
    gload16(gAc + (1 << 14) + (k0), &Ac[pp][1][16 * w][0]); \
    gload16(gAs + (k0), &As[pp][0][16 * w][0]); \
    gload16(gAs + (1 << 14) + (k0), &As[pp][1][16 * w][0]); \
    gload16(gBr + (k0), &Br[pp][16 * w][0]); \
    gload16(gBi + (k0), &Bi[pp][16 * w][0]); } while (0)
  STAGE_K6(0, 0);
  int pp = 0;
  for (int k0 = 0; k0 < 256; k0 += 32) {
    if (k0 + 32 < 256) { STAGE_K6(pp ^ 1, k0 + 32); WAITVM(6); }
    else WAITVM(0);
    BAR_ACQ();
    bf16x8 aC[2], aS[2], aSn[2];
#pragma unroll
    for (int mt = 0; mt < 2; ++mt) {
      aC[mt] = *(const bf16x8*)&Ac[pp][mt][16 * w + fr][kb];
      aS[mt] = *(const bf16x8*)&As[pp][mt][16 * w + fr][kb];
      uint4 su = *(const uint4*)&aS[mt];
      su.x ^= 0x80008000u; su.y ^= 0x80008000u; su.z ^= 0x80008000u; su.w ^= 0x80008000u;
      aSn[mt] = *(const bf16x8*)&su;
    }
#pragma unroll
    for (int t = 0; t < 4; ++t) {
      bf16x8 bR = *(const bf16x8*)&Br[pp][16 * t + fr][kb];
      bf16x8 bI = *(const bf16x8*)&Bi[pp][16 * t + fr][kb];
#pragma unroll
      for (int mt = 0; mt < 2; ++mt) {
        accr[mt][t] = MFMA(aC[mt], bR, accr[mt][t], 0, 0, 0);
        accr[mt][t] = MFMA(aSn[mt], bI, accr[mt][t], 0, 0, 0);
        acci[mt][t] = MFMA(aC[mt], bI, acci[mt][t], 0, 0, 0);
        acci[mt][t] = MFMA(aS[mt], bR, acci[mt][t], 0, 0, 0);
      }
    }
    BAR_REL();
    pp ^= 1;
  }
  const float inv = 1.f / 255.f;
#pragma unroll
  for (int t = 0; t < 4; ++t) {
    int n = n0 + 16 * t + fr;
    if (n < KH) {
#pragma unroll
      for (int mt = 0; mt < 2; ++mt) {
#pragma unroll
        for (int j = 0; j < 4; ++j) {
          int m = mt * 64 + 16 * w + 4 * (lane >> 4) + j;
          size_t idx = ((size_t)bc * 128 + m) * KH + n;
          Hr[idx] = (n < WF) ? f2bf(accr[mt][t][j] * inv) : (us16)0;
          Hi[idx] = (n < WF) ? f2bf(acci[mt][t][j] * inv) : (us16)0;
        }
      }
    }
  }
}

// ------- K7: inverse W-DFT (counted-vmcnt dbuf, K=160) -> scatter into d_out -------
__global__ __launch_bounds__(TPB) void k_dftw_inv_mfma(
    const us16* __restrict__ Hr, const us16* __restrict__ Hi,
    const us16* __restrict__ Tci, const us16* __restrict__ Tsi,
    float* __restrict__ out, int roff, int b0) {
  __shared__ __align__(16) us16 Ar[2][64][32];
  __shared__ __align__(16) us16 Ai[2][64][32];
  __shared__ __align__(16) us16 Bc[2][64][32];
  __shared__ __align__(16) us16 Bs[2][64][32];
  const int tid = threadIdx.x, w = tid >> 6, lane = tid & 63;
  const int w0 = blockIdx.x * 64, mf0 = blockIdx.y * 64;
  const int rsel = lane >> 2;
  const int csw = (lane & 3) ^ ((lane >> 3) & 3);
  const us16* gAr = Hr + (size_t)(mf0 + 16 * w + rsel) * KH + csw * 8;
  const us16* gAi = Hi + (size_t)(mf0 + 16 * w + rsel) * KH + csw * 8;
  const us16* gBc = Tci + (size_t)(w0 + 16 * w + rsel) * KH + csw * 8;
  const us16* gBs = Tsi + (size_t)(w0 + 16 * w + rsel) * KH + csw * 8;
  f32x4 acc[4] = {};
  const int fr = lane & 15;
  const int kb = 8 * ((lane >> 4) ^ ((lane >> 1) & 3));
#define STAGE_K7(pp, k0) do { \
    gload16(gAr + (k0), &Ar[pp][16 * w][0]); \
    gload16(gAi + (k0), &Ai[pp][16 * w][0]); \
    gload16(gBc + (k0), &Bc[pp][16 * w][0]); \
    gload16(gBs + (k0), &Bs[pp][16 * w][0]); } while (0)
  STAGE_K7(0, 0);
  int pp = 0;
  for (int k0 = 0; k0 < KH; k0 += 32) {
    if (k0 + 32 < KH) { STAGE_K7(pp ^ 1, k0 + 32); WAITVM(4); }
    else WAITVM(0);
    BAR_ACQ();
    bf16x8 aR = *(const bf16x8*)&Ar[pp][16 * w + fr][kb];
    bf16x8 aI = *(const bf16x8*)&Ai[pp][16 * w + fr][kb];
    uint4 su = *(const uint4*)&aI;
    su.x ^= 0x80008000u; su.y ^= 0x80008000u; su.z ^= 0x80008000u; su.w ^= 0x80008000u;
    bf16x8 aIn = *(const bf16x8*)&su;
#pragma unroll
    for (int t = 0; t < 4; ++t) {
      bf16x8 bC = *(const bf16x8*)&Bc[pp][16 * t + fr][kb];
      bf16x8 bS = *(const bf16x8*)&Bs[pp][16 * t + fr][kb];
      acc[t] = MFMA(aR, bC, acc[t], 0, 0, 0);
      acc[t] = MFMA(aIn, bS, acc[t], 0, 0, 0);
    }
    BAR_REL();
    pp ^= 1;
  }
#pragma unroll
  for (int t = 0; t < 4; ++t) {
    int wv = w0 + 16 * t + fr;
#pragma unroll
    for (int j = 0; j < 4; ++j) {
      int mf = mf0 + 16 * w + 4 * (lane >> 4) + j;
      int bcl = mf >> 7, mrow = mf & 127;
      int bb = b0 + (bcl >> 6), cc = bcl & 63;
      out[(((size_t)bb * CH + cc) * HIN + roff + mrow) * WIN + wv] = acc[t][j];
    }
  }
}

// ---------------- host ----------------
extern "C" void kernel_launch(void* const* d_in, const int* in_sizes, int n_in,
                              void* d_out, int out_size, void* d_ws, size_t ws_size,
                              hipStream_t stream) {
  const float* x        = (const float*)d_in[0];
  const float* conv_w   = (const float*)d_in[1];
  const float* conv_b   = (const float*)d_in[2];
  const float* gn_gamma = (const float*)d_in[3];
  const float* gn_beta  = (const float*)d_in[4];
  float* out = (float*)d_out;

  // u16 units
  const size_t uCbA = 2 * 65536;
  const size_t uTcb = (size_t)NT * 256;
  const size_t uTci = (size_t)256 * KH;
  const size_t uW   = 128 * 128;
  const size_t fixed_u16 = 2 * uCbA + 2 * uTcb + 2 * uTci + 2 * uW;
  const size_t uXB = (size_t)CH * HIN * WIN;      // 4194304
  const size_t uF  = (size_t)CH * SP;             // 3145728
  const size_t uPQ = (size_t)128 * SP;            // 6291456
  const size_t per_u16 = uXB + 2 * uF + 2 * uPQ;  // 23068672

  int nb = 0;
  for (int cand = 4; cand >= 1; cand >>= 1) {
    size_t need = fixed_u16 * 2 + 1152 * 4 + (size_t)cand * per_u16 * 2 + 256;
    if (need <= ws_size) { nb = cand; break; }
  }
  if (nb == 0) {
    k_zero<<<dim3((out_size + TPB - 1) / TPB), dim3(TPB), 0, stream>>>(out, out_size);
    return;
  }

  us16* CbA = (us16*)d_ws;
  us16* SbA = CbA + uCbA;
  us16* Tcb = SbA + uCbA;
  us16* Tsb = Tcb + uTcb;
  us16* Tci = Tsb + uTcb;
  us16* Tsi = Tci + uTci;
  us16* Wpb = Tsi + uTci;
  us16* Wqb = Wpb + uW;
  float* part  = (float*)(Wqb + uW);
  float* stats = part + 1024;
  us16* xb  = (us16*)(stats + 128);
  us16* Frt = xb + (size_t)nb * uXB;
  us16* Fit = Frt + (size_t)nb * uF;
  us16* P   = Fit + (size_t)nb * uF;
  us16* Q   = P + (size_t)nb * uPQ;
  us16* Yt  = xb;                               // alias: xb+Frt dead after k_mix
  us16* Hr  = Fit;                              // alias: Fit dead after k_mix
  us16* Hi  = Fit + (size_t)nb * CH * 128 * KH; // nb*1310720 (x2 <= nb*uF)

  k_tables<<<dim3(512), dim3(TPB), 0, stream>>>(CbA, SbA, Tcb, Tsb, Tci, Tsi,
                                                Wpb, Wqb, conv_w);

  for (int b0 = 0; b0 < B_ALL; b0 += nb) {
    k_xcast<<<dim3(nb * 4096), dim3(TPB), 0, stream>>>(
        x + (size_t)b0 * CH * HIN * WIN, xb, nb * 1048576);
    k_dftw_fwd_mfma<<<dim3(nb * 256, 3), dim3(TPB), 0, stream>>>(
        xb, Tcb, Tsb, Frt, Fit);
    k_mix<<<dim3(SPV / 64, 2, nb), dim3(TPB), 0, stream>>>(
        Frt, Fit, Wpb, Wqb, P, Q);
    for (int fu = 0; fu < 2; ++fu) {
      const int hsel = fu ? 127 : 0;
      const int roff = fu ? 128 : 0;
      k_dfth_fwd2<<<dim3(3, 1, nb * 128), dim3(TPB), 0, stream>>>(
          P, Q, CbA, SbA, conv_b, Yt, fu);
      k_gn_part<<<dim3(nb * 128), dim3(TPB), 0, stream>>>(Yt, part);
      k_gn_stats<<<dim3(1), dim3(64), 0, stream>>>(part, stats, nb * 16);
      k_gnnorm<<<dim3(nb * 128), dim3(TPB), 0, stream>>>(Yt, stats, gn_gamma, gn_beta);
      k_dfth_inv_mfma<<<dim3(3, 1, nb * 64), dim3(TPB), 0, stream>>>(
          Yt, CbA, SbA, Hr, Hi, hsel);
      k_dftw_inv_mfma<<<dim3(4, nb * 128), dim3(TPB), 0, stream>>>(
          Hr, Hi, Tci, Tsi, out, roff, b0);
    }
  }
}

// Round 11
// 294.759 us; speedup vs baseline: 6.1702x; 1.0866x over previous
//
#include <hip/hip_runtime.h>
#include <math.h>

#define TPB 256

typedef unsigned short us16;
typedef __bf16 bf16x8 __attribute__((ext_vector_type(8)));
typedef float f32x4 __attribute__((ext_vector_type(4)));

static const int B_ALL = 4;
static const int CH   = 64;
static const int HIN  = 256, WIN = 256;
static const int HH   = 255;
static const int WF   = 129;          // valid n per channel
static const int HWF  = HH * WF;      // 32895 valid GN count per channel
static const int SP   = WF * 256;     // 33024 packed spatial per channel
static const int KH   = 160;          // padded K for inverse W-DFT
#define GN_EPS 1e-5f

__device__ __forceinline__ us16 f2bf(float f) {
  union { float f; unsigned u; } v; v.f = f;
  unsigned r = v.u + 0x7FFFu + ((v.u >> 16) & 1u);
  return (us16)(r >> 16);
}
__device__ __forceinline__ void gload16(const void* g, void* l) {
  __builtin_amdgcn_global_load_lds(
      (const __attribute__((address_space(1))) unsigned int*)g,
      (__attribute__((address_space(3))) unsigned int*)l, 16, 0, 0);
}
#define MFMA __builtin_amdgcn_mfma_f32_16x16x32_bf16
#define WAITVM(N) asm volatile("s_waitcnt vmcnt(" #N ")" ::: "memory")
#define BAR_ACQ() do { \
    __builtin_amdgcn_s_barrier(); \
    asm volatile("" ::: "memory"); \
    __builtin_amdgcn_sched_barrier(0); } while (0)
#define BAR_REL() do { \
    asm volatile("" ::: "memory"); \
    __builtin_amdgcn_s_barrier(); } while (0)

// ---------------- fallback ----------------
__global__ __launch_bounds__(TPB) void k_zero(float* __restrict__ out, int n) {
  int i = blockIdx.x * TPB + threadIdx.x;
  if (i < n) out[i] = 0.f;
}

// ---- cast x f32->bf16 (one wave per row) + analytic Nyquist bin n=128 ----
// Fr[128][h] = sum_w (-1)^w x[h][w];  Fi[128][h] = 0
__global__ __launch_bounds__(TPB) void k_xcast2(const float* __restrict__ x,
                                                us16* __restrict__ xb,
                                                us16* __restrict__ Frt,
                                                us16* __restrict__ Fit) {
  const int row = blockIdx.x * 4 + (threadIdx.x >> 6);   // (bc,h) flat row
  const int lane = threadIdx.x & 63;
  float4 v = ((const float4*)(x + (size_t)row * 256))[lane];
  ushort4 o;
  o.x = f2bf(v.x); o.y = f2bf(v.y); o.z = f2bf(v.z); o.w = f2bf(v.w);
  ((ushort4*)(xb + (size_t)row * 256))[lane] = o;
  float alt = v.x - v.y + v.z - v.w;                     // w = 4l..4l+3 signs +-+-
  for (int off = 32; off; off >>= 1) alt += __shfl_down(alt, off);
  if (lane == 0) {
    int bc = row >> 8, h = row & 255;
    size_t idx = ((size_t)bc * WF + 128) * 256 + h;
    Frt[idx] = f2bf(alt);
    Fit[idx] = 0;
  }
}

// ---------------- bf16 tables ----------------
__global__ __launch_bounds__(TPB) void k_tables(
    us16* __restrict__ CbA, us16* __restrict__ SbA,
    us16* __restrict__ Tcb, us16* __restrict__ Tsb,
    us16* __restrict__ Tci, us16* __restrict__ Tsi,
    us16* __restrict__ Wpb, us16* __restrict__ Wqb,
    const float* __restrict__ conv_w) {
  int i = blockIdx.x * TPB + threadIdx.x;
  const double PI2 = 6.283185307179586476925286766559;
  if (i < 2 * 65536) {                      // H-DFT [fu][r][k], k-shift absorbed
    int fu = i >> 16, r = (i >> 8) & 255, k = i & 255;
    float cv = 0.f, sv = 0.f;
    int kk = k - fu;
    if (r < 255 && kk >= 0 && kk < 255) {
      double ang = PI2 * (double)((r * kk) % 255) / 255.0;
      cv = (float)cos(ang); sv = (float)sin(ang);
    }
    CbA[i] = f2bf(cv); SbA[i] = f2bf(sv);
  }
  if (i < 128 * 256) {                      // W-DFT fwd transposed [n<128][w]
    int n = i >> 8, w = i & 255;
    double ang = PI2 * (double)((n * w) & 255) / 256.0;
    Tcb[i] = f2bf((float)cos(ang));
    Tsb[i] = f2bf((float)sin(ang));
  }
  if (i < 256 * KH) {                       // W-DFT inv [w][k], Hermitian coef
    int w = i / KH, k = i - w * KH;
    float cv = 0.f, sv = 0.f;
    if (k < WF) {
      double coef = (k == 0 || k == 128) ? 1.0 : 2.0;
      double ang = PI2 * (double)((k * w) & 255) / 256.0;
      cv = (float)(coef * cos(ang) / 256.0);
      sv = (float)(coef * sin(ang) / 256.0);
    }
    Tci[i] = f2bf(cv); Tsi[i] = f2bf(sv);
  }
  if (i < 128 * 128) {                      // mix weights
    int o = i >> 7, c = i & 127;
    Wpb[i] = f2bf(conv_w[i]);
    float q = (c < 64) ? -conv_w[o * 128 + 64 + c] : conv_w[o * 128 + c - 64];
    Wqb[i] = f2bf(q);
  }
}

// ------- K1: forward W-DFT (counted-vmcnt dbuf), n<128 only -> Frt/Fit packed -------
__global__ __launch_bounds__(TPB) void k_dftw_fwd_mfma(
    const us16* __restrict__ xb, const us16* __restrict__ Tcb,
    const us16* __restrict__ Tsb, us16* __restrict__ Frt, us16* __restrict__ Fit) {
  __shared__ __align__(16) us16 Ac[2][64][32];
  __shared__ __align__(16) us16 As[2][64][32];
  __shared__ __align__(16) us16 Bx[2][64][32];
  const int tid = threadIdx.x, w = tid >> 6, lane = tid & 63;
  const int hb = blockIdx.x;
  const int n0 = blockIdx.y * 64;
  const int rsel = lane >> 2;
  const int csw = (lane & 3) ^ ((lane >> 3) & 3);
  const us16* gAc = Tcb + (size_t)(n0 + 16 * w + rsel) * 256 + csw * 8;
  const us16* gAs = Tsb + (size_t)(n0 + 16 * w + rsel) * 256 + csw * 8;
  const us16* gB  = xb + ((size_t)hb * 64 + 16 * w + rsel) * 256 + csw * 8;
  f32x4 accr[4] = {}, acci[4] = {};
  const int fr = lane & 15;
  const int kb = 8 * ((lane >> 4) ^ ((lane >> 1) & 3));
#define STAGE_K1(pp, k0) do { \
    gload16(gAc + (k0), &Ac[pp][16 * w][0]); \
    gload16(gAs + (k0), &As[pp][16 * w][0]); \
    gload16(gB + (k0), &Bx[pp][16 * w][0]); } while (0)
  STAGE_K1(0, 0);
  int pp = 0;
  for (int k0 = 0; k0 < 256; k0 += 32) {
    if (k0 + 32 < 256) { STAGE_K1(pp ^ 1, k0 + 32); WAITVM(3); }
    else WAITVM(0);
    BAR_ACQ();
    bf16x8 aC = *(const bf16x8*)&Ac[pp][16 * w + fr][kb];
    bf16x8 aS = *(const bf16x8*)&As[pp][16 * w + fr][kb];
    uint4 su = *(const uint4*)&aS;
    su.x ^= 0x80008000u; su.y ^= 0x80008000u; su.z ^= 0x80008000u; su.w ^= 0x80008000u;
    bf16x8 aSn = *(const bf16x8*)&su;
#pragma unroll
    for (int t = 0; t < 4; ++t) {
      bf16x8 b = *(const bf16x8*)&Bx[pp][16 * t + fr][kb];
      accr[t] = MFMA(aC, b, accr[t], 0, 0, 0);
      acci[t] = MFMA(aSn, b, acci[t], 0, 0, 0);
    }
    BAR_REL();
    pp ^= 1;
  }
  const int bc = hb >> 2, hl = (hb & 3) * 64;
#pragma unroll
  for (int t = 0; t < 4; ++t) {
    int h = hl + 16 * t + fr;
#pragma unroll
    for (int j = 0; j < 4; ++j) {
      int n = n0 + 16 * w + 4 * (lane >> 4) + j;     // always < 128
      size_t idx = ((size_t)bc * WF + n) * 256 + h;
      Frt[idx] = f2bf(accr[t][j]);
      Fit[idx] = f2bf(acci[t][j]);
    }
  }
}

// ------- K2: channel-mix P = Wp.[Fr;Fi], Q = Wq.[Fr;Fi] -------
__global__ __launch_bounds__(TPB) void k_mix(
    const us16* __restrict__ Frt, const us16* __restrict__ Fit,
    const us16* __restrict__ Wpb, const us16* __restrict__ Wqb,
    us16* __restrict__ P, us16* __restrict__ Q) {
  __shared__ __align__(16) us16 Ap[64][32];
  __shared__ __align__(16) us16 Aq[64][32];
  __shared__ __align__(8)  us16 Bs[64][36];
  const int tid = threadIdx.x, w = tid >> 6, lane = tid & 63;
  const int sp0 = blockIdx.x * 64, o0 = blockIdx.y * 64, b = blockIdx.z;
  const int rsel = lane >> 2;
  const int csw = (lane & 3) ^ ((lane >> 3) & 3);
  const us16* gAp = Wpb + (size_t)(o0 + 16 * w + rsel) * 128 + csw * 8;
  const us16* gAq = Wqb + (size_t)(o0 + 16 * w + rsel) * 128 + csw * 8;
  f32x4 accp[4] = {}, accq[4] = {};
  const int fr = lane & 15;
  const int kbA = 8 * ((lane >> 4) ^ ((lane >> 1) & 3));
  const int kbB = 8 * (lane >> 4);
  for (int c0 = 0; c0 < 128; c0 += 32) {
    gload16(gAp + c0, &Ap[16 * w][0]);
    gload16(gAq + c0, &Aq[16 * w][0]);
    for (int f = tid; f < 1024; f += TPB) {
      int cl = f >> 5, spp = f & 31;
      int c = c0 + cl;
      const us16* src = (c < 64) ? Frt : Fit;
      size_t addr = (size_t)(b * 64 + (c & 63)) * SP + sp0 + 2 * spp;
      unsigned v = *(const unsigned*)(src + addr);
      Bs[2 * spp][cl] = (us16)v;
      Bs[2 * spp + 1][cl] = (us16)(v >> 16);
    }
    __syncthreads();
    bf16x8 aP = *(const bf16x8*)&Ap[16 * w + fr][kbA];
    bf16x8 aQ = *(const bf16x8*)&Aq[16 * w + fr][kbA];
#pragma unroll
    for (int t = 0; t < 4; ++t) {
      uint2 lo = *(const uint2*)&Bs[16 * t + fr][kbB];
      uint2 hi = *(const uint2*)&Bs[16 * t + fr][kbB + 4];
      uint4 qq; qq.x = lo.x; qq.y = lo.y; qq.z = hi.x; qq.w = hi.y;
      bf16x8 bb = *(const bf16x8*)&qq;
      accp[t] = MFMA(aP, bb, accp[t], 0, 0, 0);
      accq[t] = MFMA(aQ, bb, accq[t], 0, 0, 0);
    }
    __syncthreads();
  }
#pragma unroll
  for (int t = 0; t < 4; ++t) {
    int sp = sp0 + 16 * t + fr;
#pragma unroll
    for (int j = 0; j < 4; ++j) {
      int o = o0 + 16 * w + 4 * (lane >> 4) + j;
      size_t idx = (size_t)(b * 128 + o) * SP + sp;
      P[idx] = f2bf(accp[t][j]);
      Q[idx] = f2bf(accq[t][j]);
    }
  }
}

// ------- K3: H-DFT fwd, N packed over u=ch*129+n -> Yt[b][u][m] bf16 -------
__global__ __launch_bounds__(TPB) void k_dfth_fwd2(
    const us16* __restrict__ P, const us16* __restrict__ Q,
    const us16* __restrict__ CbA, const us16* __restrict__ SbA,
    const float* __restrict__ bias, us16* __restrict__ Yt, int fu) {
  __shared__ __align__(16) us16 Ac[2][4][64][32];
  __shared__ __align__(16) us16 As[2][4][64][32];
  __shared__ __align__(16) us16 Bp[2][64][32];
  __shared__ __align__(16) us16 Bq[2][64][32];
  const int tid = threadIdx.x, w = tid >> 6, lane = tid & 63;
  const int b = blockIdx.z;
  const int u0 = blockIdx.x * 64;            // packed (ch,n) row base within b
  const int rsel = lane >> 2;
  const int csw = (lane & 3) ^ ((lane >> 3) & 3);
  const us16* gAc = CbA + (((size_t)fu * 256 + 16 * w + rsel) << 8) + csw * 8;
  const us16* gAs = SbA + (((size_t)fu * 256 + 16 * w + rsel) << 8) + csw * 8;
  const us16* gBp = P + (size_t)b * 128 * SP + (size_t)(u0 + 16 * w + rsel) * 256 + csw * 8;
  const us16* gBq = Q + (size_t)b * 128 * SP + (size_t)(u0 + 16 * w + rsel) * 256 + csw * 8;
  f32x4 acc[4][4] = {};
  const int fr = lane & 15;
  const int kb = 8 * ((lane >> 4) ^ ((lane >> 1) & 3));
#define STAGE_K3(pp, k0) do { \
    _Pragma("unroll") \
    for (int mt = 0; mt < 4; ++mt) { \
      gload16(gAc + (mt << 14) + (k0), &Ac[pp][mt][16 * w][0]); \
      gload16(gAs + (mt << 14) + (k0), &As[pp][mt][16 * w][0]); } \
    gload16(gBp + (k0), &Bp[pp][16 * w][0]); \
    gload16(gBq + (k0), &Bq[pp][16 * w][0]); } while (0)
  STAGE_K3(0, 0);
  int pp = 0;
  for (int k0 = 0; k0 < 256; k0 += 32) {
    if (k0 + 32 < 256) { STAGE_K3(pp ^ 1, k0 + 32); WAITVM(10); }
    else WAITVM(0);
    BAR_ACQ();
    bf16x8 aC[4], aS[4];
#pragma unroll
    for (int mt = 0; mt < 4; ++mt) {
      aC[mt] = *(const bf16x8*)&Ac[pp][mt][16 * w + fr][kb];
      aS[mt] = *(const bf16x8*)&As[pp][mt][16 * w + fr][kb];
    }
#pragma unroll
    for (int t = 0; t < 4; ++t) {
      bf16x8 bP = *(const bf16x8*)&Bp[pp][16 * t + fr][kb];
      bf16x8 bQ = *(const bf16x8*)&Bq[pp][16 * t + fr][kb];
#pragma unroll
      for (int mt = 0; mt < 4; ++mt) {
        acc[mt][t] = MFMA(aC[mt], bP, acc[mt][t], 0, 0, 0);
        acc[mt][t] = MFMA(aS[mt], bQ, acc[mt][t], 0, 0, 0);
      }
    }
    BAR_REL();
    pp ^= 1;
  }
  us16* yb = Yt + (size_t)b * 128 * SP;
  const int mb_ = 16 * w + 4 * (lane >> 4);
#pragma unroll
  for (int t = 0; t < 4; ++t) {
    int u = u0 + 16 * t + fr;
    float bo = bias[u / WF];                  // channel of this column
#pragma unroll
    for (int mt = 0; mt < 4; ++mt) {
      unsigned lo = (unsigned)f2bf(acc[mt][t][0] + bo) |
                    ((unsigned)f2bf(acc[mt][t][1] + bo) << 16);
      unsigned hi = (unsigned)f2bf(acc[mt][t][2] + bo) |
                    ((unsigned)f2bf(acc[mt][t][3] + bo) << 16);
      uint2 pk; pk.x = lo; pk.y = hi;
      *(uint2*)(yb + (size_t)u * 256 + mt * 64 + mb_) = pk;
    }
  }
}

// ---------------- K4: GroupNorm stats on Yt (all n valid, exclude m=255) ----------------
__global__ __launch_bounds__(TPB) void k_gn_part(const us16* __restrict__ Yt,
                                                 float* __restrict__ part) {
  const int tid = threadIdx.x;
  const int bz = blockIdx.x, b = bz >> 7, ch = bz & 127;
  const us16* p = Yt + (size_t)b * 128 * SP + (size_t)ch * SP;
  float s = 0.f, ss = 0.f;
  for (int cch = tid; cch < 129 * 32; cch += TPB) {
    int n = cch >> 5, off = (cch & 31) * 8;
    uint4 v = *(const uint4*)(p + (size_t)n * 256 + off);
    unsigned q[4] = {v.x, v.y, v.z, v.w};
#pragma unroll
    for (int u = 0; u < 4; ++u) {
      float f0 = __uint_as_float(q[u] << 16);
      float f1 = __uint_as_float(q[u] & 0xffff0000u);
      s += f0 + f1; ss += f0 * f0 + f1 * f1;
    }
    if ((cch & 31) == 31) {                 // exclude m == 255 (pad row of H-DFT)
      float f = __uint_as_float(v.w & 0xffff0000u);
      s -= f; ss -= f * f;
    }
  }
  __shared__ float rs[TPB], rq[TPB];
  rs[tid] = s; rq[tid] = ss;
  __syncthreads();
  for (int st = TPB / 2; st > 0; st >>= 1) {
    if (tid < st) { rs[tid] += rs[tid + st]; rq[tid] += rq[tid + st]; }
    __syncthreads();
  }
  if (tid == 0) { part[bz * 2] = rs[0]; part[bz * 2 + 1] = rq[0]; }
}

__global__ void k_gn_stats(const float* __restrict__ part,
                           float* __restrict__ stats, int nbg) {
  int bg = blockIdx.x * blockDim.x + threadIdx.x;
  if (bg < nbg) {
    float s = 0.f, ss = 0.f;
    for (int j = 0; j < 8; ++j) {
      s += part[(bg * 8 + j) * 2];
      ss += part[(bg * 8 + j) * 2 + 1];
    }
    const float inv = 1.f / (8.f * (float)HWF);
    float mean = s * inv;
    float var = ss * inv - mean * mean;
    stats[bg * 2] = mean;
    stats[bg * 2 + 1] = rsqrtf(var + GN_EPS);
  }
}

// ---------------- K5: in-place GN+ReLU on Yt ----------------
__global__ __launch_bounds__(TPB) void k_gnnorm(us16* __restrict__ Yt,
                                                const float* __restrict__ stats,
                                                const float* __restrict__ gamma,
                                                const float* __restrict__ beta) {
  const int bz = blockIdx.x, b = bz >> 7, o = bz & 127;
  const int g = b * 16 + (o >> 3);
  const float sc = gamma[o] * stats[g * 2 + 1];
  const float sh = beta[o] - stats[g * 2] * sc;
  us16* p = Yt + (size_t)b * 128 * SP + (size_t)o * SP;
  for (int cch = threadIdx.x; cch < 129 * 32; cch += TPB) {
    int n = cch >> 5, off = (cch & 31) * 8;
    uint4 v = *(const uint4*)(p + (size_t)n * 256 + off);
    unsigned q[4] = {v.x, v.y, v.z, v.w};
    unsigned r[4];
#pragma unroll
    for (int u = 0; u < 4; ++u) {
      float lo = fmaxf(__uint_as_float(q[u] << 16) * sc + sh, 0.f);
      float hi = fmaxf(__uint_as_float(q[u] & 0xffff0000u) * sc + sh, 0.f);
      r[u] = (unsigned)f2bf(lo) | ((unsigned)f2bf(hi) << 16);
    }
    uint4 o4; o4.x = r[0]; o4.y = r[1]; o4.z = r[2]; o4.w = r[3];
    *(uint4*)(p + (size_t)n * 256 + off) = o4;
  }
}

// ------- K6: inverse H-DFT, N packed over u=c*129+n -> Hr/Hi bf16 [bc*128+m][160] -------
__global__ __launch_bounds__(TPB) void k_dfth_inv_mfma(
    const us16* __restrict__ Yt, const us16* __restrict__ CbA,
    const us16* __restrict__ SbA, us16* __restrict__ Hr, us16* __restrict__ Hi,
    int hsel) {
  __shared__ __align__(16) us16 Ac[2][2][64][32];
  __shared__ __align__(16) us16 As[2][2][64][32];
  __shared__ __align__(16) us16 Br[2][64][32];
  __shared__ __align__(16) us16 Bi[2][64][32];
  const int tid = threadIdx.x, w = tid >> 6, lane = tid & 63;
  const int b = blockIdx.z;
  const int u0 = blockIdx.x * 64;            // packed (c,n) over c<64
  const int rsel = lane >> 2;
  const int csw = (lane & 3) ^ ((lane >> 3) & 3);
  const us16* gAc = CbA + (((size_t)hsel + 16 * w + rsel) << 8) + csw * 8;
  const us16* gAs = SbA + (((size_t)hsel + 16 * w + rsel) << 8) + csw * 8;
  const us16* yb = Yt + (size_t)b * 128 * SP;
  const us16* gBr = yb + (size_t)(u0 + 16 * w + rsel) * 256 + csw * 8;
  const us16* gBi = gBr + (size_t)64 * SP;   // imag channels are 64..127
  f32x4 accr[2][4] = {}, acci[2][4] = {};
  const int fr = lane & 15;
  const int kb = 8 * ((lane >> 4) ^ ((lane >> 1) & 3));
#define STAGE_K6(pp, k0) do { \
    gload16(gAc + (k0), &Ac[pp][0][16 * w][0]); \
    gload16(gAc + (1 << 14) + (k0), &Ac[pp][1][16 * w][0]); \
    gload16(gAs + (k0), &As[pp][0][16 * w][0]); \
    gload16(gAs + (1 << 14) + (k0), &As[pp][1][16 * w][0]); \
    gload16(gBr + (k0), &Br[pp][16 * w][0]); \
    gload16(gBi + (k0), &Bi[pp][16 * w][0]); } while (0)
  STAGE_K6(0, 0);
  int pp = 0;
  for (int k0 = 0; k0 < 256; k0 += 32) {
    if (k0 + 32 < 256) { STAGE_K6(pp ^ 1, k0 + 32); WAITVM(6); }
    else WAITVM(0);
    BAR_ACQ();
    bf16x8 aC[2], aS[2], aSn[2];
#pragma unroll
    for (int mt = 0; mt < 2; ++mt) {
      aC[mt] = *(const bf16x8*)&Ac[pp][mt][16 * w + fr][kb];
      aS[mt] = *(const bf16x8*)&As[pp][mt][16 * w + fr][kb];
      uint4 su = *(const uint4*)&aS[mt];
      su.x ^= 0x80008000u; su.y ^= 0x80008000u; su.z ^= 0x80008000u; su.w ^= 0x80008000u;
      aSn[mt] = *(const bf16x8*)&su;
    }
#pragma unroll
    for (int t = 0; t < 4; ++t) {
      bf16x8 bR = *(const bf16x8*)&Br[pp][16 * t + fr][kb];
      bf16x8 bI = *(const bf16x8*)&Bi[pp][16 * t + fr][kb];
#pragma unroll
      for (int mt = 0; mt < 2; ++mt) {
        accr[mt][t] = MFMA(aC[mt], bR, accr[mt][t], 0, 0, 0);
        accr[mt][t] = MFMA(aSn[mt], bI, accr[mt][t], 0, 0, 0);
        acci[mt][t] = MFMA(aC[mt], bI, acci[mt][t], 0, 0, 0);
        acci[mt][t] = MFMA(aS[mt], bR, acci[mt][t], 0, 0, 0);
      }
    }
    BAR_REL();
    pp ^= 1;
  }
  const float inv = 1.f / 255.f;
#pragma unroll
  for (int t = 0; t < 4; ++t) {
    int u = u0 + 16 * t + fr;
    int c = u / WF, n = u - c * WF;
#pragma unroll
    for (int mt = 0; mt < 2; ++mt) {
#pragma unroll
      for (int j = 0; j < 4; ++j) {
        int m = mt * 64 + 16 * w + 4 * (lane >> 4) + j;
        size_t idx = (((size_t)(b * 64 + c)) * 128 + m) * KH + n;
        Hr[idx] = f2bf(accr[mt][t][j] * inv);
        Hi[idx] = f2bf(acci[mt][t][j] * inv);
      }
    }
  }
}

// ------- K7: inverse W-DFT (counted-vmcnt dbuf, K=160) -> scatter into d_out -------
// Hr pad columns [129,160) are stale garbage but multiply zero Tci/Tsi entries.
__global__ __launch_bounds__(TPB) void k_dftw_inv_mfma(
    const us16* __restrict__ Hr, const us16* __restrict__ Hi,
    const us16* __restrict__ Tci, const us16* __restrict__ Tsi,
    float* __restrict__ out, int roff, int b0) {
  __shared__ __align__(16) us16 Ar[2][64][32];
  __shared__ __align__(16) us16 Ai[2][64][32];
  __shared__ __align__(16) us16 Bc[2][64][32];
  __shared__ __align__(16) us16 Bs[2][64][32];
  const int tid = threadIdx.x, w = tid >> 6, lane = tid & 63;
  const int w0 = blockIdx.x * 64, mf0 = blockIdx.y * 64;
  const int rsel = lane >> 2;
  const int csw = (lane & 3) ^ ((lane >> 3) & 3);
  const us16* gAr = Hr + (size_t)(mf0 + 16 * w + rsel) * KH + csw * 8;
  const us16* gAi = Hi + (size_t)(mf0 + 16 * w + rsel) * KH + csw * 8;
  const us16* gBc = Tci + (size_t)(w0 + 16 * w + rsel) * KH + csw * 8;
  const us16* gBs = Tsi + (size_t)(w0 + 16 * w + rsel) * KH + csw * 8;
  f32x4 acc[4] = {};
  const int fr = lane & 15;
  const int kb = 8 * ((lane >> 4) ^ ((lane >> 1) & 3));
#define STAGE_K7(pp, k0) do { \
    gload16(gAr + (k0), &Ar[pp][16 * w][0]); \
    gload16(gAi + (k0), &Ai[pp][16 * w][0]); \
    gload16(gBc + (k0), &Bc[pp][16 * w][0]); \
    gload16(gBs + (k0), &Bs[pp][16 * w][0]); } while (0)
  STAGE_K7(0, 0);
  int pp = 0;
  for (int k0 = 0; k0 < KH; k0 += 32) {
    if (k0 + 32 < KH) { STAGE_K7(pp ^ 1, k0 + 32); WAITVM(4); }
    else WAITVM(0);
    BAR_ACQ();
    bf16x8 aR = *(const bf16x8*)&Ar[pp][16 * w + fr][kb];
    bf16x8 aI = *(const bf16x8*)&Ai[pp][16 * w + fr][kb];
    uint4 su = *(const uint4*)&aI;
    su.x ^= 0x80008000u; su.y ^= 0x80008000u; su.z ^= 0x80008000u; su.w ^= 0x80008000u;
    bf16x8 aIn = *(const bf16x8*)&su;
#pragma unroll
    for (int t = 0; t < 4; ++t) {
      bf16x8 bC = *(const bf16x8*)&Bc[pp][16 * t + fr][kb];
      bf16x8 bS = *(const bf16x8*)&Bs[pp][16 * t + fr][kb];
      acc[t] = MFMA(aR, bC, acc[t], 0, 0, 0);
      acc[t] = MFMA(aIn, bS, acc[t], 0, 0, 0);
    }
    BAR_REL();
    pp ^= 1;
  }
#pragma unroll
  for (int t = 0; t < 4; ++t) {
    int wv = w0 + 16 * t + fr;
#pragma unroll
    for (int j = 0; j < 4; ++j) {
      int mf = mf0 + 16 * w + 4 * (lane >> 4) + j;
      int bcl = mf >> 7, mrow = mf & 127;
      int bb = b0 + (bcl >> 6), cc = bcl & 63;
      out[(((size_t)bb * CH + cc) * HIN + roff + mrow) * WIN + wv] = acc[t][j];
    }
  }
}

// ---------------- host ----------------
extern "C" void kernel_launch(void* const* d_in, const int* in_sizes, int n_in,
                              void* d_out, int out_size, void* d_ws, size_t ws_size,
                              hipStream_t stream) {
  const float* x        = (const float*)d_in[0];
  const float* conv_w   = (const float*)d_in[1];
  const float* conv_b   = (const float*)d_in[2];
  const float* gn_gamma = (const float*)d_in[3];
  const float* gn_beta  = (const float*)d_in[4];
  float* out = (float*)d_out;

  // u16 units
  const size_t uCbA = 2 * 65536;
  const size_t uTcb = 128 * 256;
  const size_t uTci = (size_t)256 * KH;
  const size_t uW   = 128 * 128;
  const size_t fixed_u16 = 2 * uCbA + 2 * uTcb + 2 * uTci + 2 * uW;
  const size_t uXB = (size_t)CH * HIN * WIN;      // 4194304
  const size_t uF  = (size_t)CH * SP;             // 2113536
  const size_t uPQ = (size_t)128 * SP;            // 4227072
  const size_t uYT = (size_t)128 * SP;            // 4227072 (aliases xb/Frt)
  const size_t uH  = (size_t)CH * 128 * KH;       // 1310720
  const size_t per_u16 = uXB + 2 * uF + 2 * uPQ;  // 16875520

  int nb = 0;
  for (int cand = 4; cand >= 1; cand >>= 1) {
    size_t need = fixed_u16 * 2 + 1152 * 4 + (size_t)cand * per_u16 * 2 + 256;
    if (need <= ws_size) { nb = cand; break; }
  }
  if (nb == 0) {
    k_zero<<<dim3((out_size + TPB - 1) / TPB), dim3(TPB), 0, stream>>>(out, out_size);
    return;
  }

  us16* CbA = (us16*)d_ws;
  us16* SbA = CbA + uCbA;
  us16* Tcb = SbA + uCbA;
  us16* Tsb = Tcb + uTcb;
  us16* Tci = Tsb + uTcb;
  us16* Tsi = Tci + uTci;
  us16* Wpb = Tsi + uTci;
  us16* Wqb = Wpb + uW;
  float* part  = (float*)(Wqb + uW);
  float* stats = part + 1024;
  us16* xb  = (us16*)(stats + 128);
  us16* Frt = xb + (size_t)nb * uXB;
  us16* Fit = Frt + (size_t)nb * uF;
  us16* P   = Fit + (size_t)nb * uF;
  us16* Q   = P + (size_t)nb * uPQ;
  // aliases into [xb | Frt | Fit] (dead after k_mix): Yt then Hr/Hi
  us16* Yt  = xb;                               // nb*uYT <= nb*(uXB+uF)
  us16* Hr  = xb + (size_t)nb * uYT;
  us16* Hi  = Hr + (size_t)nb * uH;             // total nb*(uYT+2uH) <= nb*(uXB+2uF)

  k_tables<<<dim3(512), dim3(TPB), 0, stream>>>(CbA, SbA, Tcb, Tsb, Tci, Tsi,
                                                Wpb, Wqb, conv_w);

  for (int b0 = 0; b0 < B_ALL; b0 += nb) {
    k_xcast2<<<dim3(nb * 4096), dim3(TPB), 0, stream>>>(
        x + (size_t)b0 * CH * HIN * WIN, xb, Frt, Fit);
    k_dftw_fwd_mfma<<<dim3(nb * 256, 2), dim3(TPB), 0, stream>>>(
        xb, Tcb, Tsb, Frt, Fit);
    k_mix<<<dim3(SP / 64, 2, nb), dim3(TPB), 0, stream>>>(
        Frt, Fit, Wpb, Wqb, P, Q);
    for (int fu = 0; fu < 2; ++fu) {
      const int hsel = fu ? 127 : 0;
      const int roff = fu ? 128 : 0;
      k_dfth_fwd2<<<dim3(128 * WF / 64, 1, nb), dim3(TPB), 0, stream>>>(
          P, Q, CbA, SbA, conv_b, Yt, fu);
      k_gn_part<<<dim3(nb * 128), dim3(TPB), 0, stream>>>(Yt, part);
      k_gn_stats<<<dim3(1), dim3(64), 0, stream>>>(part, stats, nb * 16);
      k_gnnorm<<<dim3(nb * 128), dim3(TPB), 0, stream>>>(Yt, stats, gn_gamma, gn_beta);
      k_dfth_inv_mfma<<<dim3(64 * WF / 64, 1, nb), dim3(TPB), 0, stream>>>(
          Yt, CbA, SbA, Hr, Hi, hsel);
      k_dftw_inv_mfma<<<dim3(4, nb * 128), dim3(TPB), 0, stream>>>(
          Hr, Hi, Tci, Tsi, out, roff, b0);
    }
  }
}

// Round 14
// 267.264 us; speedup vs baseline: 6.8050x; 1.1029x over previous
//
#include <hip/hip_runtime.h>
#include <math.h>

#define TPB 256

typedef unsigned short us16;
typedef __bf16 bf16x8 __attribute__((ext_vector_type(8)));
typedef float f32x4 __attribute__((ext_vector_type(4)));

static const int B_ALL = 4;
static const int CH   = 64;
static const int HIN  = 256, WIN = 256;
static const int HH   = 255;
static const int WF   = 129;          // valid n per channel
static const int HWF  = HH * WF;      // 32895 valid GN count per channel
static const int SP   = WF * 256;     // 33024 packed spatial per channel
static const int KH   = 160;          // padded K for inverse W-DFT
static const int UZ   = 64 * WF;      // 8256 packed (c,n) rows per batch (inv side)
#define GN_EPS 1e-5f

__device__ __forceinline__ us16 f2bf(float f) {
  union { float f; unsigned u; } v; v.f = f;
  unsigned r = v.u + 0x7FFFu + ((v.u >> 16) & 1u);
  return (us16)(r >> 16);
}
__device__ __forceinline__ float bf2f(us16 v) {
  union { unsigned u; float f; } t; t.u = ((unsigned)v) << 16; return t.f;
}
__device__ __forceinline__ void gload16(const void* g, void* l) {
  __builtin_amdgcn_global_load_lds(
      (const __attribute__((address_space(1))) unsigned int*)g,
      (__attribute__((address_space(3))) unsigned int*)l, 16, 0, 0);
}
#define MFMA __builtin_amdgcn_mfma_f32_16x16x32_bf16
#define WAITVM(N) asm volatile("s_waitcnt vmcnt(" #N ")" ::: "memory")
#define BAR_ACQ() do { \
    __builtin_amdgcn_s_barrier(); \
    asm volatile("" ::: "memory"); \
    __builtin_amdgcn_sched_barrier(0); } while (0)
#define BAR_REL() do { \
    asm volatile("" ::: "memory"); \
    __builtin_amdgcn_s_barrier(); } while (0)

// ---------------- fallback ----------------
__global__ __launch_bounds__(TPB) void k_zero(float* __restrict__ out, int n) {
  int i = blockIdx.x * TPB + threadIdx.x;
  if (i < n) out[i] = 0.f;
}

// ---- cast x f32->bf16 (one wave per row) + analytic Nyquist bin n=128 ----
__global__ __launch_bounds__(TPB) void k_xcast2(const float* __restrict__ x,
                                                us16* __restrict__ xb,
                                                us16* __restrict__ Frt,
                                                us16* __restrict__ Fit) {
  const int row = blockIdx.x * 4 + (threadIdx.x >> 6);
  const int lane = threadIdx.x & 63;
  float4 v = ((const float4*)(x + (size_t)row * 256))[lane];
  ushort4 o;
  o.x = f2bf(v.x); o.y = f2bf(v.y); o.z = f2bf(v.z); o.w = f2bf(v.w);
  ((ushort4*)(xb + (size_t)row * 256))[lane] = o;
  float alt = v.x - v.y + v.z - v.w;
  for (int off = 32; off; off >>= 1) alt += __shfl_down(alt, off);
  if (lane == 0) {
    int bc = row >> 8, h = row & 255;
    size_t idx = ((size_t)bc * WF + 128) * 256 + h;
    Frt[idx] = f2bf(alt);
    Fit[idx] = 0;
  }
}

// ---------------- bf16 tables ----------------
__global__ __launch_bounds__(TPB) void k_tables(
    us16* __restrict__ CbA, us16* __restrict__ SbA,
    us16* __restrict__ Tcb, us16* __restrict__ Tsb,
    us16* __restrict__ Tci, us16* __restrict__ Tsi,
    us16* __restrict__ Wpb, us16* __restrict__ Wqb,
    const float* __restrict__ conv_w) {
  int i = blockIdx.x * TPB + threadIdx.x;
  const double PI2 = 6.283185307179586476925286766559;
  if (i < 2 * 65536) {                      // H-DFT [fu][r][k], k-shift absorbed
    int fu = i >> 16, r = (i >> 8) & 255, k = i & 255;
    float cv = 0.f, sv = 0.f;
    int kk = k - fu;
    if (r < 255 && kk >= 0 && kk < 255) {
      double ang = PI2 * (double)((r * kk) % 255) / 255.0;
      cv = (float)cos(ang); sv = (float)sin(ang);
    }
    CbA[i] = f2bf(cv); SbA[i] = f2bf(sv);
  }
  if (i < 128 * 256) {                      // W-DFT fwd transposed [n<128][w]
    int n = i >> 8, w = i & 255;
    double ang = PI2 * (double)((n * w) & 255) / 256.0;
    Tcb[i] = f2bf((float)cos(ang));
    Tsb[i] = f2bf((float)sin(ang));
  }
  if (i < 256 * KH) {                       // W-DFT inv [w][k], Hermitian coef
    int w = i / KH, k = i - w * KH;
    float cv = 0.f, sv = 0.f;
    if (k < WF) {
      double coef = (k == 0 || k == 128) ? 1.0 : 2.0;
      double ang = PI2 * (double)((k * w) & 255) / 256.0;
      cv = (float)(coef * cos(ang) / 256.0);
      sv = (float)(coef * sin(ang) / 256.0);
    }
    Tci[i] = f2bf(cv); Tsi[i] = f2bf(sv);
  }
  if (i < 128 * 128) {                      // mix weights
    int o = i >> 7, c = i & 127;
    Wpb[i] = f2bf(conv_w[i]);
    float q = (c < 64) ? -conv_w[o * 128 + 64 + c] : conv_w[o * 128 + c - 64];
    Wqb[i] = f2bf(q);
  }
}

// ------- K1: forward W-DFT (counted-vmcnt dbuf), n<128 -> Frt/Fit packed -------
__global__ __launch_bounds__(TPB) void k_dftw_fwd_mfma(
    const us16* __restrict__ xb, const us16* __restrict__ Tcb,
    const us16* __restrict__ Tsb, us16* __restrict__ Frt, us16* __restrict__ Fit) {
  __shared__ __align__(16) us16 Ac[2][64][32];
  __shared__ __align__(16) us16 As[2][64][32];
  __shared__ __align__(16) us16 Bx[2][64][32];
  const int tid = threadIdx.x, w = tid >> 6, lane = tid & 63;
  const int hb = blockIdx.x;
  const int n0 = blockIdx.y * 64;
  const int rsel = lane >> 2;
  const int csw = (lane & 3) ^ ((lane >> 3) & 3);
  const us16* gAc = Tcb + (size_t)(n0 + 16 * w + rsel) * 256 + csw * 8;
  const us16* gAs = Tsb + (size_t)(n0 + 16 * w + rsel) * 256 + csw * 8;
  const us16* gB  = xb + ((size_t)hb * 64 + 16 * w + rsel) * 256 + csw * 8;
  f32x4 accr[4] = {}, acci[4] = {};
  const int fr = lane & 15;
  const int kb = 8 * ((lane >> 4) ^ ((lane >> 1) & 3));
#define STAGE_K1(pp, k0) do { \
    gload16(gAc + (k0), &Ac[pp][16 * w][0]); \
    gload16(gAs + (k0), &As[pp][16 * w][0]); \
    gload16(gB + (k0), &Bx[pp][16 * w][0]); } while (0)
  STAGE_K1(0, 0);
  int pp = 0;
  for (int k0 = 0; k0 < 256; k0 += 32) {
    if (k0 + 32 < 256) { STAGE_K1(pp ^ 1, k0 + 32); WAITVM(3); }
    else WAITVM(0);
    BAR_ACQ();
    bf16x8 aC = *(const bf16x8*)&Ac[pp][16 * w + fr][kb];
    bf16x8 aS = *(const bf16x8*)&As[pp][16 * w + fr][kb];
    uint4 su = *(const uint4*)&aS;
    su.x ^= 0x80008000u; su.y ^= 0x80008000u; su.z ^= 0x80008000u; su.w ^= 0x80008000u;
    bf16x8 aSn = *(const bf16x8*)&su;
#pragma unroll
    for (int t = 0; t < 4; ++t) {
      bf16x8 b = *(const bf16x8*)&Bx[pp][16 * t + fr][kb];
      accr[t] = MFMA(aC, b, accr[t], 0, 0, 0);
      acci[t] = MFMA(aSn, b, acci[t], 0, 0, 0);
    }
    BAR_REL();
    pp ^= 1;
  }
  const int bc = hb >> 2, hl = (hb & 3) * 64;
#pragma unroll
  for (int t = 0; t < 4; ++t) {
    int h = hl + 16 * t + fr;
#pragma unroll
    for (int j = 0; j < 4; ++j) {
      int n = n0 + 16 * w + 4 * (lane >> 4) + j;
      size_t idx = ((size_t)bc * WF + n) * 256 + h;
      Frt[idx] = f2bf(accr[t][j]);
      Fit[idx] = f2bf(acci[t][j]);
    }
  }
}

// ------- K2: channel-mix P = Wp.[Fr;Fi], Q = Wq.[Fr;Fi] -------
__global__ __launch_bounds__(TPB) void k_mix(
    const us16* __restrict__ Frt, const us16* __restrict__ Fit,
    const us16* __restrict__ Wpb, const us16* __restrict__ Wqb,
    us16* __restrict__ P, us16* __restrict__ Q) {
  __shared__ __align__(16) us16 Ap[64][32];
  __shared__ __align__(16) us16 Aq[64][32];
  __shared__ __align__(8)  us16 Bs[64][36];
  const int tid = threadIdx.x, w = tid >> 6, lane = tid & 63;
  const int sp0 = blockIdx.x * 64, o0 = blockIdx.y * 64, b = blockIdx.z;
  const int rsel = lane >> 2;
  const int csw = (lane & 3) ^ ((lane >> 3) & 3);
  const us16* gAp = Wpb + (size_t)(o0 + 16 * w + rsel) * 128 + csw * 8;
  const us16* gAq = Wqb + (size_t)(o0 + 16 * w + rsel) * 128 + csw * 8;
  f32x4 accp[4] = {}, accq[4] = {};
  const int fr = lane & 15;
  const int kbA = 8 * ((lane >> 4) ^ ((lane >> 1) & 3));
  const int kbB = 8 * (lane >> 4);
  for (int c0 = 0; c0 < 128; c0 += 32) {
    gload16(gAp + c0, &Ap[16 * w][0]);
    gload16(gAq + c0, &Aq[16 * w][0]);
    for (int f = tid; f < 1024; f += TPB) {
      int cl = f >> 5, spp = f & 31;
      int c = c0 + cl;
      const us16* src = (c < 64) ? Frt : Fit;
      size_t addr = (size_t)(b * 64 + (c & 63)) * SP + sp0 + 2 * spp;
      unsigned v = *(const unsigned*)(src + addr);
      Bs[2 * spp][cl] = (us16)v;
      Bs[2 * spp + 1][cl] = (us16)(v >> 16);
    }
    __syncthreads();
    bf16x8 aP = *(const bf16x8*)&Ap[16 * w + fr][kbA];
    bf16x8 aQ = *(const bf16x8*)&Aq[16 * w + fr][kbA];
#pragma unroll
    for (int t = 0; t < 4; ++t) {
      uint2 lo = *(const uint2*)&Bs[16 * t + fr][kbB];
      uint2 hi = *(const uint2*)&Bs[16 * t + fr][kbB + 4];
      uint4 qq; qq.x = lo.x; qq.y = lo.y; qq.z = hi.x; qq.w = hi.y;
      bf16x8 bb = *(const bf16x8*)&qq;
      accp[t] = MFMA(aP, bb, accp[t], 0, 0, 0);
      accq[t] = MFMA(aQ, bb, accq[t], 0, 0, 0);
    }
    __syncthreads();
  }
#pragma unroll
  for (int t = 0; t < 4; ++t) {
    int sp = sp0 + 16 * t + fr;
#pragma unroll
    for (int j = 0; j < 4; ++j) {
      int o = o0 + 16 * w + 4 * (lane >> 4) + j;
      size_t idx = (size_t)(b * 128 + o) * SP + sp;
      P[idx] = f2bf(accp[t][j]);
      Q[idx] = f2bf(accq[t][j]);
    }
  }
}

// ------- K3: H-DFT fwd, M-symmetric: compute r=0..127, emit rows r and 255-r -------
// CP = sum C[r][k] P[u][k]; SQ = sum S[r][k] Q[u][k]; Y[r]=CP+SQ+b, Y[255-r]=CP-SQ+b
__global__ __launch_bounds__(TPB) void k_dfth_fwd2(
    const us16* __restrict__ P, const us16* __restrict__ Q,
    const us16* __restrict__ CbA, const us16* __restrict__ SbA,
    const float* __restrict__ bias, us16* __restrict__ Yt, int fu) {
  __shared__ __align__(16) us16 Ac[2][2][64][32];
  __shared__ __align__(16) us16 As[2][2][64][32];
  __shared__ __align__(16) us16 Bp[2][64][32];
  __shared__ __align__(16) us16 Bq[2][64][32];
  const int tid = threadIdx.x, w = tid >> 6, lane = tid & 63;
  const int b = blockIdx.z;
  const int u0 = blockIdx.x * 64;
  const int rsel = lane >> 2;
  const int csw = (lane & 3) ^ ((lane >> 3) & 3);
  const us16* gAc = CbA + (((size_t)fu * 256 + 16 * w + rsel) << 8) + csw * 8;
  const us16* gAs = SbA + (((size_t)fu * 256 + 16 * w + rsel) << 8) + csw * 8;
  const us16* gBp = P + (size_t)b * 128 * SP + (size_t)(u0 + 16 * w + rsel) * 256 + csw * 8;
  const us16* gBq = Q + (size_t)b * 128 * SP + (size_t)(u0 + 16 * w + rsel) * 256 + csw * 8;
  f32x4 cp[2][4] = {}, sq[2][4] = {};
  const int fr = lane & 15;
  const int kb = 8 * ((lane >> 4) ^ ((lane >> 1) & 3));
#define STAGE_K3(pp, k0) do { \
    _Pragma("unroll") \
    for (int mt = 0; mt < 2; ++mt) { \
      gload16(gAc + (mt << 14) + (k0), &Ac[pp][mt][16 * w][0]); \
      gload16(gAs + (mt << 14) + (k0), &As[pp][mt][16 * w][0]); } \
    gload16(gBp + (k0), &Bp[pp][16 * w][0]); \
    gload16(gBq + (k0), &Bq[pp][16 * w][0]); } while (0)
  STAGE_K3(0, 0);
  int pp = 0;
  for (int k0 = 0; k0 < 256; k0 += 32) {
    if (k0 + 32 < 256) { STAGE_K3(pp ^ 1, k0 + 32); WAITVM(6); }
    else WAITVM(0);
    BAR_ACQ();
    bf16x8 aC[2], aS[2];
#pragma unroll
    for (int mt = 0; mt < 2; ++mt) {
      aC[mt] = *(const bf16x8*)&Ac[pp][mt][16 * w + fr][kb];
      aS[mt] = *(const bf16x8*)&As[pp][mt][16 * w + fr][kb];
    }
#pragma unroll
    for (int t = 0; t < 4; ++t) {
      bf16x8 bP = *(const bf16x8*)&Bp[pp][16 * t + fr][kb];
      bf16x8 bQ = *(const bf16x8*)&Bq[pp][16 * t + fr][kb];
#pragma unroll
      for (int mt = 0; mt < 2; ++mt) {
        cp[mt][t] = MFMA(aC[mt], bP, cp[mt][t], 0, 0, 0);
        sq[mt][t] = MFMA(aS[mt], bQ, sq[mt][t], 0, 0, 0);
      }
    }
    BAR_REL();
    pp ^= 1;
  }
  us16* yb = Yt + (size_t)b * 128 * SP;
  const int mb_ = 16 * w + 4 * (lane >> 4);
#pragma unroll
  for (int t = 0; t < 4; ++t) {
    int u = u0 + 16 * t + fr;
    float bo = bias[u / WF];
#pragma unroll
    for (int mt = 0; mt < 2; ++mt) {
      int base = mt * 64 + mb_;                  // r = base + j, 0..127
      float y[4], z[4];
#pragma unroll
      for (int j = 0; j < 4; ++j) {
        y[j] = cp[mt][t][j] + sq[mt][t][j] + bo; // row r
        z[j] = cp[mt][t][j] - sq[mt][t][j] + bo; // row 255-r
      }
      uint2 pk;
      pk.x = (unsigned)f2bf(y[0]) | ((unsigned)f2bf(y[1]) << 16);
      pk.y = (unsigned)f2bf(y[2]) | ((unsigned)f2bf(y[3]) << 16);
      *(uint2*)(yb + (size_t)u * 256 + base) = pk;
      uint2 pk2;                                 // reversed: m' = 252-base .. 255-base
      pk2.x = (unsigned)f2bf(z[3]) | ((unsigned)f2bf(z[2]) << 16);
      pk2.y = (unsigned)f2bf(z[1]) | ((unsigned)f2bf(z[0]) << 16);
      *(uint2*)(yb + (size_t)u * 256 + 252 - base) = pk2;
    }
  }
}

// ---------------- K4: GroupNorm stats on Yt (exclude m=255 pad) ----------------
__global__ __launch_bounds__(TPB) void k_gn_part(const us16* __restrict__ Yt,
                                                 float* __restrict__ part) {
  const int tid = threadIdx.x;
  const int bz = blockIdx.x, b = bz >> 7, ch = bz & 127;
  const us16* p = Yt + (size_t)b * 128 * SP + (size_t)ch * SP;
  float s = 0.f, ss = 0.f;
  for (int cch = tid; cch < 129 * 32; cch += TPB) {
    int n = cch >> 5, off = (cch & 31) * 8;
    uint4 v = *(const uint4*)(p + (size_t)n * 256 + off);
    unsigned q[4] = {v.x, v.y, v.z, v.w};
#pragma unroll
    for (int u = 0; u < 4; ++u) {
      float f0 = __uint_as_float(q[u] << 16);
      float f1 = __uint_as_float(q[u] & 0xffff0000u);
      s += f0 + f1; ss += f0 * f0 + f1 * f1;
    }
    if ((cch & 31) == 31) {
      float f = __uint_as_float(v.w & 0xffff0000u);
      s -= f; ss -= f * f;
    }
  }
  __shared__ float rs[TPB], rq[TPB];
  rs[tid] = s; rq[tid] = ss;
  __syncthreads();
  for (int st = TPB / 2; st > 0; st >>= 1) {
    if (tid < st) { rs[tid] += rs[tid + st]; rq[tid] += rq[tid + st]; }
    __syncthreads();
  }
  if (tid == 0) { part[bz * 2] = rs[0]; part[bz * 2 + 1] = rq[0]; }
}

__global__ void k_gn_stats(const float* __restrict__ part,
                           float* __restrict__ stats, int nbg) {
  int bg = blockIdx.x * blockDim.x + threadIdx.x;
  if (bg < nbg) {
    float s = 0.f, ss = 0.f;
    for (int j = 0; j < 8; ++j) {
      s += part[(bg * 8 + j) * 2];
      ss += part[(bg * 8 + j) * 2 + 1];
    }
    const float inv = 1.f / (8.f * (float)HWF);
    float mean = s * inv;
    float var = ss * inv - mean * mean;
    stats[bg * 2] = mean;
    stats[bg * 2 + 1] = rsqrtf(var + GN_EPS);
  }
}

// ------- K5: GN+ReLU + k-fold: Z+/- [b][u'][k=0..127] (u' over 64 real/imag pairs) -------
// zr = relu(gn(Yt[c])), zi = relu(gn(Yt[64+c])); pair for k>=1 is m=255-k; k=0 unpaired.
__global__ __launch_bounds__(TPB) void k_gnfold(
    const us16* __restrict__ Yt, const float* __restrict__ stats,
    const float* __restrict__ gamma, const float* __restrict__ beta,
    us16* __restrict__ Zrp, us16* __restrict__ Zrm,
    us16* __restrict__ Zip, us16* __restrict__ Zim) {
  const int b = blockIdx.y;
  const int up = blockIdx.x * 8 + (threadIdx.x >> 5);   // 0..8255
  const int l32 = threadIdx.x & 31;
  const int c = up / WF;
  const int g1 = b * 16 + (c >> 3), g2 = g1 + 8;
  const float sc1 = gamma[c] * stats[g1 * 2 + 1];
  const float sh1 = beta[c] - stats[g1 * 2] * sc1;
  const float sc2 = gamma[64 + c] * stats[g2 * 2 + 1];
  const float sh2 = beta[64 + c] - stats[g2 * 2] * sc2;
  const us16* ybase = Yt + (size_t)b * 128 * SP;
  const us16* yr = ybase + (size_t)up * 256;
  const us16* yi = ybase + (size_t)(64 * WF + up) * 256;
  const int k0 = l32 * 4;
  uint2 ar = *(const uint2*)(yr + k0);
  uint2 mr = *(const uint2*)(yr + 252 - k0);
  uint2 ai = *(const uint2*)(yi + k0);
  uint2 mi = *(const uint2*)(yi + 252 - k0);
  us16 arv[4] = {(us16)ar.x, (us16)(ar.x >> 16), (us16)ar.y, (us16)(ar.y >> 16)};
  us16 mrv[4] = {(us16)mr.x, (us16)(mr.x >> 16), (us16)mr.y, (us16)(mr.y >> 16)};
  us16 aiv[4] = {(us16)ai.x, (us16)(ai.x >> 16), (us16)ai.y, (us16)(ai.y >> 16)};
  us16 miv[4] = {(us16)mi.x, (us16)(mi.x >> 16), (us16)mi.y, (us16)(mi.y >> 16)};
  us16 rp[4], rm[4], ip[4], im[4];
#pragma unroll
  for (int d = 0; d < 4; ++d) {
    float zr = fmaxf(bf2f(arv[d]) * sc1 + sh1, 0.f);
    float zi = fmaxf(bf2f(aiv[d]) * sc2 + sh2, 0.f);
    float pr = 0.f, pi = 0.f;
    if (k0 + d > 0) {                           // pair m = 255-(k0+d) = element 3-d of mirror
      pr = fmaxf(bf2f(mrv[3 - d]) * sc1 + sh1, 0.f);
      pi = fmaxf(bf2f(miv[3 - d]) * sc2 + sh2, 0.f);
    }
    rp[d] = f2bf(zr + pr); rm[d] = f2bf(zr - pr);
    ip[d] = f2bf(zi + pi); im[d] = f2bf(zi - pi);
  }
  const size_t zo = ((size_t)b * UZ + up) * 128 + k0;
  uint2 o1; o1.x = (unsigned)rp[0] | ((unsigned)rp[1] << 16);
  o1.y = (unsigned)rp[2] | ((unsigned)rp[3] << 16);
  *(uint2*)(Zrp + zo) = o1;
  uint2 o2; o2.x = (unsigned)rm[0] | ((unsigned)rm[1] << 16);
  o2.y = (unsigned)rm[2] | ((unsigned)rm[3] << 16);
  *(uint2*)(Zrm + zo) = o2;
  uint2 o3; o3.x = (unsigned)ip[0] | ((unsigned)ip[1] << 16);
  o3.y = (unsigned)ip[2] | ((unsigned)ip[3] << 16);
  *(uint2*)(Zip + zo) = o3;
  uint2 o4; o4.x = (unsigned)im[0] | ((unsigned)im[1] << 16);
  o4.y = (unsigned)im[2] | ((unsigned)im[3] << 16);
  *(uint2*)(Zim + zo) = o4;
}

// ------- K6: inverse H-DFT, K folded to 128 -> Hr/Hi bf16 [bc*128+m][160] -------
// accr = sum_k C[hsel+m][k] Zrp - S Zim ; acci = sum_k C Zip + S Zrm  (k=0..127)
__global__ __launch_bounds__(TPB) void k_dfth_inv_mfma(
    const us16* __restrict__ Zrp, const us16* __restrict__ Zrm,
    const us16* __restrict__ Zip, const us16* __restrict__ Zim,
    const us16* __restrict__ CbA, const us16* __restrict__ SbA,
    us16* __restrict__ Hr, us16* __restrict__ Hi, int hsel) {
  __shared__ __align__(16) us16 Ac[2][2][64][32];
  __shared__ __align__(16) us16 As[2][2][64][32];
  __shared__ __align__(16) us16 Brp[2][64][32];
  __shared__ __align__(16) us16 Brm[2][64][32];
  __shared__ __align__(16) us16 Bip[2][64][32];
  __shared__ __align__(16) us16 Bim[2][64][32];
  const int tid = threadIdx.x, w = tid >> 6, lane = tid & 63;
  const int b = blockIdx.z;
  const int u0 = blockIdx.x * 64;
  const int rsel = lane >> 2;
  const int csw = (lane & 3) ^ ((lane >> 3) & 3);
  const us16* gAc = CbA + (((size_t)hsel + 16 * w + rsel) << 8) + csw * 8;
  const us16* gAs = SbA + (((size_t)hsel + 16 * w + rsel) << 8) + csw * 8;
  const size_t zoff = ((size_t)b * UZ + u0 + 16 * w + rsel) * 128 + csw * 8;
  const us16* gZrp = Zrp + zoff;
  const us16* gZrm = Zrm + zoff;
  const us16* gZip = Zip + zoff;
  const us16* gZim = Zim + zoff;
  f32x4 accr[2][4] = {}, acci[2][4] = {};
  const int fr = lane & 15;
  const int kb = 8 * ((lane >> 4) ^ ((lane >> 1) & 3));
#define STAGE_K6(pp, k0) do { \
    gload16(gAc + (k0), &Ac[pp][0][16 * w][0]); \
    gload16(gAc + (1 << 14) + (k0), &Ac[pp][1][16 * w][0]); \
    gload16(gAs + (k0), &As[pp][0][16 * w][0]); \
    gload16(gAs + (1 << 14) + (k0), &As[pp][1][16 * w][0]); \
    gload16(gZrp + (k0), &Brp[pp][16 * w][0]); \
    gload16(gZrm + (k0), &Brm[pp][16 * w][0]); \
    gload16(gZip + (k0), &Bip[pp][16 * w][0]); \
    gload16(gZim + (k0), &Bim[pp][16 * w][0]); } while (0)
  STAGE_K6(0, 0);
  int pp = 0;
  for (int k0 = 0; k0 < 128; k0 += 32) {
    if (k0 + 32 < 128) { STAGE_K6(pp ^ 1, k0 + 32); WAITVM(8); }
    else WAITVM(0);
    BAR_ACQ();
    bf16x8 aC[2], aS[2], aSn[2];
#pragma unroll
    for (int mt = 0; mt < 2; ++mt) {
      aC[mt] = *(const bf16x8*)&Ac[pp][mt][16 * w + fr][kb];
      aS[mt] = *(const bf16x8*)&As[pp][mt][16 * w + fr][kb];
      uint4 su = *(const uint4*)&aS[mt];
      su.x ^= 0x80008000u; su.y ^= 0x80008000u; su.z ^= 0x80008000u; su.w ^= 0x80008000u;
      aSn[mt] = *(const bf16x8*)&su;
    }
#pragma unroll
    for (int t = 0; t < 4; ++t) {
      bf16x8 bRp = *(const bf16x8*)&Brp[pp][16 * t + fr][kb];
      bf16x8 bRm = *(const bf16x8*)&Brm[pp][16 * t + fr][kb];
      bf16x8 bIp = *(const bf16x8*)&Bip[pp][16 * t + fr][kb];
      bf16x8 bIm = *(const bf16x8*)&Bim[pp][16 * t + fr][kb];
#pragma unroll
      for (int mt = 0; mt < 2; ++mt) {
        accr[mt][t] = MFMA(aC[mt], bRp, accr[mt][t], 0, 0, 0);
        accr[mt][t] = MFMA(aSn[mt], bIm, accr[mt][t], 0, 0, 0);
        acci[mt][t] = MFMA(aC[mt], bIp, acci[mt][t], 0, 0, 0);
        acci[mt][t] = MFMA(aS[mt], bRm, acci[mt][t], 0, 0, 0);
      }
    }
    BAR_REL();
    pp ^= 1;
  }
  const float inv = 1.f / 255.f;
#pragma unroll
  for (int t = 0; t < 4; ++t) {
    int u = u0 + 16 * t + fr;
    int c = u / WF, n = u - c * WF;
#pragma unroll
    for (int mt = 0; mt < 2; ++mt) {
#pragma unroll
      for (int j = 0; j < 4; ++j) {
        int m = mt * 64 + 16 * w + 4 * (lane >> 4) + j;
        size_t idx = (((size_t)(b * 64 + c)) * 128 + m) * KH + n;
        Hr[idx] = f2bf(accr[mt][t][j] * inv);
        Hi[idx] = f2bf(acci[mt][t][j] * inv);
      }
    }
  }
}

// ------- K7: inverse W-DFT, W-symmetric (w=0..127 -> cols w and 256-w) -------
// U = sum Hr.Tci ; V = sum (-Hi).Tsi ; out[w]=U+V, out[256-w]=U-V (w>=1)
__global__ __launch_bounds__(TPB) void k_dftw_inv_mfma(
    const us16* __restrict__ Hr, const us16* __restrict__ Hi,
    const us16* __restrict__ Tci, const us16* __restrict__ Tsi,
    float* __restrict__ out, int roff, int b0) {
  __shared__ __align__(16) us16 Ar[2][64][32];
  __shared__ __align__(16) us16 Ai[2][64][32];
  __shared__ __align__(16) us16 Bc[2][64][32];
  __shared__ __align__(16) us16 Bs[2][64][32];
  const int tid = threadIdx.x, w = tid >> 6, lane = tid & 63;
  const int w0 = blockIdx.x * 64, mf0 = blockIdx.y * 64;
  const int rsel = lane >> 2;
  const int csw = (lane & 3) ^ ((lane >> 3) & 3);
  const us16* gAr = Hr + (size_t)(mf0 + 16 * w + rsel) * KH + csw * 8;
  const us16* gAi = Hi + (size_t)(mf0 + 16 * w + rsel) * KH + csw * 8;
  const us16* gBc = Tci + (size_t)(w0 + 16 * w + rsel) * KH + csw * 8;
  const us16* gBs = Tsi + (size_t)(w0 + 16 * w + rsel) * KH + csw * 8;
  f32x4 accU[4] = {}, accV[4] = {};
  const int fr = lane & 15;
  const int kb = 8 * ((lane >> 4) ^ ((lane >> 1) & 3));
#define STAGE_K7(pp, k0) do { \
    gload16(gAr + (k0), &Ar[pp][16 * w][0]); \
    gload16(gAi + (k0), &Ai[pp][16 * w][0]); \
    gload16(gBc + (k0), &Bc[pp][16 * w][0]); \
    gload16(gBs + (k0), &Bs[pp][16 * w][0]); } while (0)
  STAGE_K7(0, 0);
  int pp = 0;
  for (int k0 = 0; k0 < KH; k0 += 32) {
    if (k0 + 32 < KH) { STAGE_K7(pp ^ 1, k0 + 32); WAITVM(4); }
    else WAITVM(0);
    BAR_ACQ();
    bf16x8 aR = *(const bf16x8*)&Ar[pp][16 * w + fr][kb];
    bf16x8 aI = *(const bf16x8*)&Ai[pp][16 * w + fr][kb];
    uint4 su = *(const uint4*)&aI;
    su.x ^= 0x80008000u; su.y ^= 0x80008000u; su.z ^= 0x80008000u; su.w ^= 0x80008000u;
    bf16x8 aIn = *(const bf16x8*)&su;
#pragma unroll
    for (int t = 0; t < 4; ++t) {
      bf16x8 bC = *(const bf16x8*)&Bc[pp][16 * t + fr][kb];
      bf16x8 bS = *(const bf16x8*)&Bs[pp][16 * t + fr][kb];
      accU[t] = MFMA(aR, bC, accU[t], 0, 0, 0);
      accV[t] = MFMA(aIn, bS, accV[t], 0, 0, 0);
    }
    BAR_REL();
    pp ^= 1;
  }
#pragma unroll
  for (int t = 0; t < 4; ++t) {
    int wv = w0 + 16 * t + fr;                 // 0..127
#pragma unroll
    for (int j = 0; j < 4; ++j) {
      int mf = mf0 + 16 * w + 4 * (lane >> 4) + j;
      int bcl = mf >> 7, mrow = mf & 127;
      int bb = b0 + (bcl >> 6), cc = bcl & 63;
      size_t obase = (((size_t)bb * CH + cc) * HIN + roff + mrow) * WIN;
      float U = accU[t][j], V = accV[t][j];
      out[obase + wv] = U + V;
      if (wv > 0) out[obase + 256 - wv] = U - V;
    }
  }
}

// ------- K8: missing column w=128 (sin==0): alternating sum of Hr -------
__global__ __launch_bounds__(TPB) void k_w128(const us16* __restrict__ Hr,
                                              float* __restrict__ out,
                                              int roff, int b0) {
  const int mf = blockIdx.x * TPB + threadIdx.x;
  const us16* hr = Hr + (size_t)mf * KH;
  float s = bf2f(hr[0]) + bf2f(hr[128]);
  for (int k = 1; k < 128; k += 2)
    s += -2.f * bf2f(hr[k]) + 2.f * bf2f(hr[k + 1]);
  s -= 2.f * bf2f(hr[128]);   // loop added +2*hr[128] at k=127 pair; keep coef 1
  s *= (1.f / 256.f);
  int bcl = mf >> 7, mrow = mf & 127;
  int bb = b0 + (bcl >> 6), cc = bcl & 63;
  out[(((size_t)bb * CH + cc) * HIN + roff + mrow) * WIN + 128] = s;
}

// ---------------- host ----------------
extern "C" void kernel_launch(void* const* d_in, const int* in_sizes, int n_in,
                              void* d_out, int out_size, void* d_ws, size_t ws_size,
                              hipStream_t stream) {
  const float* x        = (const float*)d_in[0];
  const float* conv_w   = (const float*)d_in[1];
  const float* conv_b   = (const float*)d_in[2];
  const float* gn_gamma = (const float*)d_in[3];
  const float* gn_beta  = (const float*)d_in[4];
  float* out = (float*)d_out;

  // u16 units
  const size_t uCbA = 2 * 65536;
  const size_t uTcb = 128 * 256;
  const size_t uTci = (size_t)256 * KH;
  const size_t uW   = 128 * 128;
  const size_t fixed_u16 = 2 * uCbA + 2 * uTcb + 2 * uTci + 2 * uW;
  const size_t uXB = (size_t)CH * HIN * WIN;      // 4194304
  const size_t uF  = (size_t)CH * SP;             // 2113536
  const size_t uPQ = (size_t)128 * SP;            // 4227072
  const size_t uYT = (size_t)128 * SP;            // 4227072 (aliases xb/Frt)
  const size_t uH  = (size_t)CH * 128 * KH;       // 1310720
  const size_t uZ1 = (size_t)UZ * 128;            // 1056768 per Z array
  const size_t per_u16 = uXB + 2 * uF + 2 * uPQ + 4 * uZ1;  // 21102592

  int nb = 0;
  for (int cand = 4; cand >= 1; cand >>= 1) {
    size_t need = fixed_u16 * 2 + 1152 * 4 + (size_t)cand * per_u16 * 2 + 256;
    if (need <= ws_size) { nb = cand; break; }
  }
  if (nb == 0) {
    k_zero<<<dim3((out_size + TPB - 1) / TPB), dim3(TPB), 0, stream>>>(out, out_size);
    return;
  }

  us16* CbA = (us16*)d_ws;
  us16* SbA = CbA + uCbA;
  us16* Tcb = SbA + uCbA;
  us16* Tsb = Tcb + uTcb;
  us16* Tci = Tsb + uTcb;
  us16* Tsi = Tci + uTci;
  us16* Wpb = Tsi + uTci;
  us16* Wqb = Wpb + uW;
  float* part  = (float*)(Wqb + uW);
  float* stats = part + 1024;
  us16* xb  = (us16*)(stats + 128);
  us16* Frt = xb + (size_t)nb * uXB;
  us16* Fit = Frt + (size_t)nb * uF;
  us16* P   = Fit + (size_t)nb * uF;
  us16* Q   = P + (size_t)nb * uPQ;
  us16* Zrp = Q + (size_t)nb * uPQ;
  us16* Zrm = Zrp + (size_t)nb * uZ1;
  us16* Zip = Zrm + (size_t)nb * uZ1;
  us16* Zim = Zip + (size_t)nb * uZ1;
  // aliases into [xb | Frt | Fit] (dead after k_mix): Yt then Hr/Hi
  us16* Yt  = xb;                               // nb*uYT <= nb*(uXB+uF)
  us16* Hr  = xb + (size_t)nb * uYT;
  us16* Hi  = Hr + (size_t)nb * uH;             // uYT+2uH <= uXB+2uF

  k_tables<<<dim3(512), dim3(TPB), 0, stream>>>(CbA, SbA, Tcb, Tsb, Tci, Tsi,
                                                Wpb, Wqb, conv_w);

  for (int b0 = 0; b0 < B_ALL; b0 += nb) {
    k_xcast2<<<dim3(nb * 4096), dim3(TPB), 0, stream>>>(
        x + (size_t)b0 * CH * HIN * WIN, xb, Frt, Fit);
    k_dftw_fwd_mfma<<<dim3(nb * 256, 2), dim3(TPB), 0, stream>>>(
        xb, Tcb, Tsb, Frt, Fit);
    k_mix<<<dim3(SP / 64, 2, nb), dim3(TPB), 0, stream>>>(
        Frt, Fit, Wpb, Wqb, P, Q);
    for (int fu = 0; fu < 2; ++fu) {
      const int hsel = fu ? 127 : 0;
      const int roff = fu ? 128 : 0;
      k_dfth_fwd2<<<dim3(128 * WF / 64, 1, nb), dim3(TPB), 0, stream>>>(
          P, Q, CbA, SbA, conv_b, Yt, fu);
      k_gn_part<<<dim3(nb * 128), dim3(TPB), 0, stream>>>(Yt, part);
      k_gn_stats<<<dim3(1), dim3(64), 0, stream>>>(part, stats, nb * 16);
      k_gnfold<<<dim3(UZ / 8, nb), dim3(TPB), 0, stream>>>(
          Yt, stats, gn_gamma, gn_beta, Zrp, Zrm, Zip, Zim);
      k_dfth_inv_mfma<<<dim3(UZ / 64, 1, nb), dim3(TPB), 0, stream>>>(
          Zrp, Zrm, Zip, Zim, CbA, SbA, Hr, Hi, hsel);
      k_dftw_inv_mfma<<<dim3(2, nb * 128), dim3(TPB), 0, stream>>>(
          Hr, Hi, Tci, Tsi, out, roff, b0);
      k_w128<<<dim3(nb * 32), dim3(TPB), 0, stream>>>(Hr, out, roff, b0);
    }
  }
}